// Round 12
// baseline (1182.333 us; speedup 1.0000x reference)
//
#include <hip/hip_runtime.h>
#include <math.h>

typedef _Float16 f16x8 __attribute__((ext_vector_type(8)));
typedef _Float16 f16x4 __attribute__((ext_vector_type(4)));
typedef float f32x4 __attribute__((ext_vector_type(4)));

#define TBM 256
#define TBN 128
#define TBK 32

#define AS1 __attribute__((address_space(1)))
#define AS3 __attribute__((address_space(3)))

__device__ __forceinline__ void gll16(const _Float16* g, _Float16* l)
{
    __builtin_amdgcn_global_load_lds((const AS1 unsigned int*)g,
                                     (AS3 unsigned int*)l, 16, 0, 0);
}

// bijective XCD chunking (m204): dispatch d (round-robin XCD = d%8) -> contiguous tile chunk
__device__ __forceinline__ int xcd_swz(int d, int nwg)
{
    int q = nwg >> 3, r = nwg & 7;
    int x = d & 7, idx = d >> 3;
    int base = x < r ? x * (q + 1) : r * (q + 1) + (x - r) * q;
    return base + idx;
}

// ---- fast transcendentals ----
__device__ __forceinline__ float fsigmoid(float x)
{
    return __builtin_amdgcn_rcpf(1.f + __expf(-x));
}
__device__ __forceinline__ float ftanh(float x)
{
    float ax = fabsf(x);
    float e = __expf(-2.f * ax);
    float t = (1.f - e) * __builtin_amdgcn_rcpf(1.f + e);
    return copysignf(t, x);
}

// ---------------- wave-per-output dot kernel (small-M fp32 GEMMs) ----------------
// ACT: 1 leaky, 2 relu ; F16OUT selects output dtype; EMITC also emits f16 C set (Kin=128)
template<int ACT, bool F16OUT, bool EMITC>
__global__ __launch_bounds__(256)
void dot_k(const float* __restrict__ X, const float* __restrict__ W,
           const float* __restrict__ bias, void* __restrict__ Yv,
           _Float16* __restrict__ Ch, _Float16* __restrict__ CTh,
           float* __restrict__ Csq, int M, int K)
{
    int gw = (blockIdx.x * 256 + threadIdx.x) >> 6;
    int lane = threadIdx.x & 63;
    if (gw >= M * 512) return;
    int r = gw >> 9, n = gw & 511;
    const float* xr = X + (size_t)r * K;
    const float* wr = W + (size_t)n * K;
    float d = 0.f;
    for (int t = 0; t < K; t += 256) {
        float4 a = *(const float4*)(xr + t + lane * 4);
        float4 b = *(const float4*)(wr + t + lane * 4);
        d += a.x * b.x + a.y * b.y + a.z * b.z + a.w * b.w;
    }
#pragma unroll
    for (int o = 32; o; o >>= 1) d += __shfl_xor(d, o);
    if (lane == 0) {
        float v = d + bias[n];
        if (ACT == 1) v = v > 0.f ? v : 0.01f * v;
        else if (ACT == 2) v = fmaxf(v, 0.f);
        if (F16OUT) ((_Float16*)Yv)[(size_t)r * 512 + n] = (_Float16)v;
        else        ((float*)Yv)[(size_t)r * 512 + n] = v;
        if (EMITC) {
            _Float16 h = (_Float16)v;
            Ch[(size_t)r * 512 + n] = h;
            CTh[(size_t)n * 128 + r] = h;
            float f = (float)h;
            atomicAdd(&Csq[r], f * f);
        }
    }
}

// ---------------- f16 MFMA GEMM: 256x128 tile, 8 waves, LDS dbuf, repacked epilogue ----------------
// MODE 0: out = act(v) -> Yh f16; MODE 1: out = Yh + v (coalesced RMW)
// ACT: 0 none, 1 leaky, 2 relu ; SQ: atomicAdd row sum-of-squares of final f16 into Psq
template<int MODE, int ACT, bool SQ>
__global__ __launch_bounds__(512)
void mgemm(const _Float16* __restrict__ A, const _Float16* __restrict__ B,
           const float* __restrict__ bias, _Float16* __restrict__ Yh,
           float* __restrict__ Psq, int M, int K, int Nout)
{
    __shared__ _Float16 As[2][TBM * TBK];
    __shared__ _Float16 Bs[2][TBN * TBK];
    const int tid = threadIdx.x;
    const int lane = tid & 63;
    const int wid = tid >> 6;
    const int wr = wid >> 1, wc = wid & 1;

    int bid = xcd_swz(blockIdx.y * gridDim.x + blockIdx.x, gridDim.x * gridDim.y);
    const int m0 = (bid / gridDim.x) * TBM;
    const int n0 = (bid % gridDim.x) * TBN;

    f32x4 acc[4][4] = {};
    const int nt = K / TBK;

    const int lrow = lane >> 2;
    const int lk = (lane & 3) * 8;

    auto stage = [&](int t, int buf) {
        const int k0 = t * TBK;
#pragma unroll
        for (int q = 0; q < 2; q++) {
            int c = wid * 2 + q;
            int r = c * 16 + lrow;
            int am = min(m0 + r, M - 1);
            gll16(A + (size_t)am * K + k0 + lk, &As[buf][c * 512]);
        }
        {
            int c = wid;
            int r = c * 16 + lrow;
            int bn = min(n0 + r, Nout - 1);
            gll16(B + (size_t)bn * K + k0 + lk, &Bs[buf][c * 512]);
        }
    };

    stage(0, 0);
    __syncthreads();
    for (int t = 0; t < nt; ++t) {
        const int cur = t & 1;
        if (t + 1 < nt) stage(t + 1, cur ^ 1);
        f16x8 af[4], bf[4];
#pragma unroll
        for (int mi = 0; mi < 4; mi++)
            af[mi] = *(const f16x8*)(&As[cur][(wr * 64 + mi * 16 + (lane & 15)) * TBK + (lane >> 4) * 8]);
#pragma unroll
        for (int nj = 0; nj < 4; nj++)
            bf[nj] = *(const f16x8*)(&Bs[cur][(wc * 64 + nj * 16 + (lane & 15)) * TBK + (lane >> 4) * 8]);
#pragma unroll
        for (int mi = 0; mi < 4; mi++)
#pragma unroll
            for (int nj = 0; nj < 4; nj++)
                acc[mi][nj] = __builtin_amdgcn_mfma_f32_16x16x32_f16(af[mi], bf[nj], acc[mi][nj], 0, 0, 0);
        __syncthreads();
    }

    // ---- epilogue: repack 256x128 tile via LDS in two 128-row phases ----
    _Float16* eb = &As[0][0];
    const int g = lane >> 4;
#pragma unroll
    for (int p = 0; p < 2; p++) {
        if (p) __syncthreads();
        if ((wr >> 1) == p) {
#pragma unroll
            for (int nj = 0; nj < 4; nj++) {
                int col = wc * 64 + nj * 16 + (lane & 15);
                float bv = bias ? bias[n0 + col] : 0.f;
#pragma unroll
                for (int mi = 0; mi < 4; mi++)
#pragma unroll
                    for (int r = 0; r < 4; r++) {
                        int lr = (wr & 1) * 64 + mi * 16 + g * 4 + r;
                        float v = acc[mi][nj][r] + bv;
                        if (MODE == 0) {
                            if (ACT == 1) v = v > 0.f ? v : 0.01f * v;
                            else if (ACT == 2) v = fmaxf(v, 0.f);
                        }
                        eb[lr * 128 + col] = (_Float16)v;
                    }
            }
        }
        __syncthreads();
        int t4 = tid * 4;
        int lr = t4 >> 4;
        int cbase = (t4 & 15) * 8;
        int m = m0 + p * 128 + lr;
        float sq = 0.f;
        if (m < M) {
#pragma unroll
            for (int q = 0; q < 4; q++) {
                int c0 = cbase + q * 8;
                f16x8 hv = *(f16x8*)(eb + lr * 128 + c0);
                size_t gidx = (size_t)m * Nout + n0 + c0;
                if (MODE == 1) {
                    f16x8 old = *(f16x8*)(Yh + gidx);
                    f16x8 nw;
#pragma unroll
                    for (int e = 0; e < 8; e++) {
                        float s = (float)old[e] + (float)hv[e];
                        nw[e] = (_Float16)s;
                    }
                    *(f16x8*)(Yh + gidx) = nw;
                    hv = nw;
                } else {
                    *(f16x8*)(Yh + gidx) = hv;
                }
                if (SQ) {
#pragma unroll
                    for (int e = 0; e < 8; e++) { float f = (float)hv[e]; sq += f * f; }
                }
            }
        }
        if (SQ) {
            sq += __shfl_xor(sq, 1);
            sq += __shfl_xor(sq, 2);
            if ((lane & 3) == 0 && m < M) atomicAdd(&Psq[m], sq);
        }
    }
}

// ---------------- fused gate + attention-score GEMM ----------------
// scr[m] += sum_n tanh(A@B1^T+c1)[m,n] * sigmoid(A@B2^T+c2)[m,n] * Ws[n]
// (b_s dropped: softmax over scores is shift-invariant). No TG materialization.
__global__ __launch_bounds__(512)
void gatgemm(const _Float16* __restrict__ A, const _Float16* __restrict__ B1,
             const _Float16* __restrict__ B2, const float* __restrict__ c1,
             const float* __restrict__ c2, const float* __restrict__ Ws,
             float* __restrict__ scr, int M, int K, int Nout)
{
    __shared__ _Float16 As[2][TBM * TBK];
    __shared__ _Float16 B1s[2][TBN * TBK];
    __shared__ _Float16 B2s[2][TBN * TBK];
    const int tid = threadIdx.x;
    const int lane = tid & 63;
    const int wid = tid >> 6;
    const int wr = wid >> 1, wc = wid & 1;

    int bid = xcd_swz(blockIdx.y * gridDim.x + blockIdx.x, gridDim.x * gridDim.y);
    const int m0 = (bid / gridDim.x) * TBM;
    const int n0 = (bid % gridDim.x) * TBN;

    f32x4 acc1[4][4] = {};
    f32x4 acc2[4][4] = {};
    const int nt = K / TBK;

    const int lrow = lane >> 2;
    const int lk = (lane & 3) * 8;

    auto stage = [&](int t, int buf) {
        const int k0 = t * TBK;
#pragma unroll
        for (int q = 0; q < 2; q++) {
            int c = wid * 2 + q;
            int r = c * 16 + lrow;
            int am = min(m0 + r, M - 1);
            gll16(A + (size_t)am * K + k0 + lk, &As[buf][c * 512]);
        }
        {
            int c = wid;
            int r = c * 16 + lrow;
            int bn = min(n0 + r, Nout - 1);
            gll16(B1 + (size_t)bn * K + k0 + lk, &B1s[buf][c * 512]);
            gll16(B2 + (size_t)bn * K + k0 + lk, &B2s[buf][c * 512]);
        }
    };

    stage(0, 0);
    __syncthreads();
    for (int t = 0; t < nt; ++t) {
        const int cur = t & 1;
        if (t + 1 < nt) stage(t + 1, cur ^ 1);
        f16x8 af[4], bf1[4], bf2[4];
#pragma unroll
        for (int mi = 0; mi < 4; mi++)
            af[mi] = *(const f16x8*)(&As[cur][(wr * 64 + mi * 16 + (lane & 15)) * TBK + (lane >> 4) * 8]);
#pragma unroll
        for (int nj = 0; nj < 4; nj++) {
            int ro = (wc * 64 + nj * 16 + (lane & 15)) * TBK + (lane >> 4) * 8;
            bf1[nj] = *(const f16x8*)(&B1s[cur][ro]);
            bf2[nj] = *(const f16x8*)(&B2s[cur][ro]);
        }
#pragma unroll
        for (int mi = 0; mi < 4; mi++)
#pragma unroll
            for (int nj = 0; nj < 4; nj++) {
                acc1[mi][nj] = __builtin_amdgcn_mfma_f32_16x16x32_f16(af[mi], bf1[nj], acc1[mi][nj], 0, 0, 0);
                acc2[mi][nj] = __builtin_amdgcn_mfma_f32_16x16x32_f16(af[mi], bf2[nj], acc2[mi][nj], 0, 0, 0);
            }
        __syncthreads();
    }

    // ---- epilogue: gate + per-row partial dot with Ws, atomic accumulate ----
    const int g = lane >> 4;
    float wsv[4];
#pragma unroll
    for (int nj = 0; nj < 4; nj++)
        wsv[nj] = Ws[n0 + wc * 64 + nj * 16 + (lane & 15)];
#pragma unroll
    for (int mi = 0; mi < 4; mi++) {
#pragma unroll
        for (int r = 0; r < 4; r++) {
            float bv1, bv2, p = 0.f;
#pragma unroll
            for (int nj = 0; nj < 4; nj++) {
                int col = n0 + wc * 64 + nj * 16 + (lane & 15);
                bv1 = c1[col]; bv2 = c2[col];
                float t1 = ftanh(acc1[mi][nj][r] + bv1);
                float g1 = fsigmoid(acc2[mi][nj][r] + bv2);
                p += t1 * g1 * wsv[nj];
            }
#pragma unroll
            for (int o = 1; o < 16; o <<= 1) p += __shfl_xor(p, o);
            if ((lane & 15) == 0) {
                int m = m0 + wr * 64 + mi * 16 + g * 4 + r;
                if (m < M) atomicAdd(&scr[m], p);
            }
        }
    }
}

// ---------------- fused sim GEMM + row softmax: 128-row blocks, 4 waves ----------------
#define SBM 128
__global__ __launch_bounds__(256)
void simgemm(const _Float16* __restrict__ A, const _Float16* __restrict__ B,
             const float* __restrict__ Psq, const float* __restrict__ Csq,
             const float* __restrict__ sscale, _Float16* __restrict__ Ah,
             int M, int K, int Kin)
{
    __shared__ _Float16 As[2][SBM * TBK];
    __shared__ _Float16 Bs[2][SBM * TBK];
    __shared__ float redmx[2][SBM];
    __shared__ float redsm[2][SBM];
    const int tid = threadIdx.x;
    const int lane = tid & 63;
    const int wid = tid >> 6;
    const int wr = wid >> 1, wc = wid & 1;
    const int m0 = blockIdx.y * SBM;

    f32x4 acc[4][4] = {};
    const int nt = K / TBK;
    const int lrow = lane >> 2;
    const int lk = (lane & 3) * 8;

    auto stage = [&](int t, int buf) {
        const int k0 = t * TBK;
#pragma unroll
        for (int q = 0; q < 2; q++) {
            int c = wid * 2 + q;
            int r = c * 16 + lrow;
            int am = min(m0 + r, M - 1);
            int bn = min(r, Kin - 1);
            gll16(A + (size_t)am * K + k0 + lk, &As[buf][c * 512]);
            gll16(B + (size_t)bn * K + k0 + lk, &Bs[buf][c * 512]);
        }
    };

    stage(0, 0);
    __syncthreads();
    for (int t = 0; t < nt; ++t) {
        const int cur = t & 1;
        if (t + 1 < nt) stage(t + 1, cur ^ 1);
        f16x8 af[4], bf[4];
#pragma unroll
        for (int mi = 0; mi < 4; mi++)
            af[mi] = *(const f16x8*)(&As[cur][(wr * 64 + mi * 16 + (lane & 15)) * TBK + (lane >> 4) * 8]);
#pragma unroll
        for (int nj = 0; nj < 4; nj++)
            bf[nj] = *(const f16x8*)(&Bs[cur][(wc * 64 + nj * 16 + (lane & 15)) * TBK + (lane >> 4) * 8]);
#pragma unroll
        for (int mi = 0; mi < 4; mi++)
#pragma unroll
            for (int nj = 0; nj < 4; nj++)
                acc[mi][nj] = __builtin_amdgcn_mfma_f32_16x16x32_f16(af[mi], bf[nj], acc[mi][nj], 0, 0, 0);
        __syncthreads();
    }

    const float denom = fmaxf(1e-6f, sscale[0]);
    const int colbase = wc * 64 + (lane & 15);
    const int g = lane >> 4;
    float cc[4];
#pragma unroll
    for (int nj = 0; nj < 4; nj++) {
        int n = colbase + nj * 16;
        cc[nj] = (n < Kin) ? Csq[n] : 0.f;
    }

#pragma unroll
    for (int mi = 0; mi < 4; mi++) {
#pragma unroll
        for (int r = 0; r < 4; r++) {
            int row = wr * 64 + mi * 16 + g * 4 + r;
            float pp = Psq[m0 + row];
            float mx = -INFINITY;
#pragma unroll
            for (int nj = 0; nj < 4; nj++) {
                int n = colbase + nj * 16;
                float v = -INFINITY;
                if (n < Kin)
                    v = -sqrtf(fmaxf(pp + cc[nj] - 2.f * acc[mi][nj][r], 1e-12f)) / denom;
                acc[mi][nj][r] = v;
                mx = fmaxf(mx, v);
            }
#pragma unroll
            for (int o = 1; o < 16; o <<= 1) mx = fmaxf(mx, __shfl_xor(mx, o));
            if ((lane & 15) == 0) redmx[wc][row] = mx;
        }
    }
    __syncthreads();

#pragma unroll
    for (int mi = 0; mi < 4; mi++) {
#pragma unroll
        for (int r = 0; r < 4; r++) {
            int row = wr * 64 + mi * 16 + g * 4 + r;
            float mx = fmaxf(redmx[0][row], redmx[1][row]);
            float s = 0.f;
#pragma unroll
            for (int nj = 0; nj < 4; nj++) {
                int n = colbase + nj * 16;
                float e = (n < Kin) ? __expf(acc[mi][nj][r] - mx) : 0.f;
                acc[mi][nj][r] = e;
                s += e;
            }
#pragma unroll
            for (int o = 1; o < 16; o <<= 1) s += __shfl_xor(s, o);
            if ((lane & 15) == 0) redsm[wc][row] = s;
        }
    }
    __syncthreads();

#pragma unroll
    for (int mi = 0; mi < 4; mi++) {
#pragma unroll
        for (int r = 0; r < 4; r++) {
            int row = wr * 64 + mi * 16 + g * 4 + r;
            float inv = __builtin_amdgcn_rcpf(redsm[0][row] + redsm[1][row]);
            int m = m0 + row;
#pragma unroll
            for (int nj = 0; nj < 4; nj++) {
                int n = colbase + nj * 16;
                if (n < Kin)
                    Ah[(size_t)m * Kin + n] = (_Float16)(acc[mi][nj][r] * inv);
            }
        }
    }
}

// ---------------- converters ----------------
__global__ __launch_bounds__(256)
void cvt_k(const float* __restrict__ x, _Float16* __restrict__ y, int n)
{
    int i = (blockIdx.x * 256 + threadIdx.x) * 4;
    if (i < n) {
        float4 v = *(const float4*)(x + i);
        f16x4 h = { (_Float16)v.x, (_Float16)v.y, (_Float16)v.z, (_Float16)v.w };
        *(f16x4*)(y + i) = h;
    }
}

// ---------------- small kernels (f16 activations) ----------------
__global__ __launch_bounds__(256)
void ln_k(const _Float16* __restrict__ X, const _Float16* __restrict__ R,
          const float* __restrict__ g, const float* __restrict__ b,
          _Float16* __restrict__ Yh, int M)
{
    int wid = threadIdx.x >> 6, lane = threadIdx.x & 63;
    int row = blockIdx.x * 4 + wid;
    if (row >= M) return;
    f16x8 a = *(const f16x8*)(X + (size_t)row * 512 + lane * 8);
    float v[8];
#pragma unroll
    for (int q = 0; q < 8; q++) v[q] = (float)a[q];
    if (R) {
        f16x8 c = *(const f16x8*)(R + (size_t)row * 512 + lane * 8);
#pragma unroll
        for (int q = 0; q < 8; q++) v[q] += (float)c[q];
    }
    float s = 0.f, ss = 0.f;
#pragma unroll
    for (int q = 0; q < 8; q++) { s += v[q]; ss += v[q] * v[q]; }
#pragma unroll
    for (int o = 32; o; o >>= 1) { s += __shfl_xor(s, o); ss += __shfl_xor(ss, o); }
    float mean = s * (1.f / 512.f);
    float var = ss * (1.f / 512.f) - mean * mean;
    float inv = 1.f / sqrtf(var + 1e-5f);
    int d0 = lane * 8;
    f16x8 o8;
#pragma unroll
    for (int q = 0; q < 8; q++)
        o8[q] = (_Float16)((v[q] - mean) * inv * g[d0 + q] + b[d0 + q]);
    *(f16x8*)(Yh + (size_t)row * 512 + d0) = o8;
}

__global__ __launch_bounds__(256)
void red1_k(const float* __restrict__ C, const float* __restrict__ w1,
            const float* __restrict__ b1, float* __restrict__ H1, int Kin)
{
    int d = blockIdx.x * 256 + threadIdx.x;
    int j = blockIdx.y;
    float acc = b1[j];
    for (int k = 0; k < Kin; k++) acc = fmaf(C[(size_t)k * 512 + d], w1[(size_t)j * Kin + k], acc);
    H1[(size_t)j * 512 + d] = fmaxf(acc, 0.f);
}

// red2 + fused f16 conversion/transpose/Csq emission for the NEXT iteration
__global__ __launch_bounds__(256)
void red2_k(const float* __restrict__ H1, const float* __restrict__ w2,
            const float* __restrict__ b2, float* __restrict__ Cn,
            _Float16* __restrict__ Chn, _Float16* __restrict__ CThn,
            float* __restrict__ Csqn, int Kin, int Kout)
{
    int d = blockIdx.x * 256 + threadIdx.x;
    int j2 = blockIdx.y;
    float acc = b2[j2];
    for (int j = 0; j < Kin; j++) acc = fmaf(H1[(size_t)j * 512 + d], w2[(size_t)j2 * Kin + j], acc);
    Cn[(size_t)j2 * 512 + d] = acc;
    _Float16 h = (_Float16)acc;
    Chn[(size_t)j2 * 512 + d] = h;
    CThn[(size_t)d * Kout + j2] = h;
    float f = (float)h;
    float sq = f * f;
#pragma unroll
    for (int o = 32; o; o >>= 1) sq += __shfl_xor(sq, o);
    if ((threadIdx.x & 63) == 0) atomicAdd(&Csqn[j2], sq);
}

__global__ __launch_bounds__(1024)
void pool_k(float* __restrict__ s, float* __restrict__ scal, int M)
{
    __shared__ float sm[16];
    int tid = threadIdx.x, lane = tid & 63, wid = tid >> 6;
    float mx = -INFINITY;
    for (int i = tid * 4; i < M; i += 4096) {
        float4 a = *(const float4*)(s + i);
        mx = fmaxf(fmaxf(fmaxf(mx, a.x), fmaxf(a.y, a.z)), a.w);
    }
#pragma unroll
    for (int o = 32; o; o >>= 1) mx = fmaxf(mx, __shfl_xor(mx, o));
    if (lane == 0) sm[wid] = mx;
    __syncthreads();
    if (wid == 0) {
        float v = (lane < 16) ? sm[lane] : -INFINITY;
#pragma unroll
        for (int o = 8; o; o >>= 1) v = fmaxf(v, __shfl_xor(v, o));
        if (lane == 0) sm[0] = v;
    }
    __syncthreads();
    float gmax = sm[0];
    __syncthreads();
    float sum = 0.f;
    for (int i = tid * 4; i < M; i += 4096) {
        float4 a = *(const float4*)(s + i);
        float4 e;
        e.x = __expf(a.x - gmax); e.y = __expf(a.y - gmax);
        e.z = __expf(a.z - gmax); e.w = __expf(a.w - gmax);
        *(float4*)(s + i) = e;
        sum += e.x + e.y + e.z + e.w;
    }
#pragma unroll
    for (int o = 32; o; o >>= 1) sum += __shfl_xor(sum, o);
    if (lane == 0) sm[wid] = sum;
    __syncthreads();
    if (tid == 0) {
        float t = 0.f;
        for (int w = 0; w < 16; w++) t += sm[w];
        scal[0] = t;
    }
}

__global__ __launch_bounds__(256)
void bagp_k(const _Float16* __restrict__ Z, const float* __restrict__ w,
            float* __restrict__ PB, int M, int cs)
{
    int d = blockIdx.x * 256 + threadIdx.x;
    int chunk = blockIdx.y;
    int i0 = chunk * cs;
    int i1 = min(M, i0 + cs);
    float acc = 0.f;
    for (int i = i0; i < i1; i++) acc = fmaf(w[i], (float)Z[(size_t)i * 512 + d], acc);
    PB[(size_t)chunk * 512 + d] = acc;
}

__global__ __launch_bounds__(256)
void bagf_k(const float* __restrict__ PB, const float* __restrict__ scal,
            float* __restrict__ bag, int nchunk)
{
    int d = blockIdx.x * 256 + threadIdx.x;
    float acc = 0.f;
    for (int c = 0; c < nchunk; c++) acc += PB[(size_t)c * 512 + d];
    bag[d] = acc / scal[0];
}

__global__ __launch_bounds__(256)
void h_k(const float* __restrict__ bag, const float* __restrict__ Wh,
         const float* __restrict__ bh, float* __restrict__ h)
{
    int wid = threadIdx.x >> 6, lane = threadIdx.x & 63;
    int j = blockIdx.x * 4 + wid;
    const float* wr = Wh + (size_t)j * 512;
    float d = 0.f;
#pragma unroll
    for (int t = 0; t < 2; t++) {
        float4 a = *(const float4*)(wr + t * 256 + lane * 4);
        float4 bv = *(const float4*)(bag + t * 256 + lane * 4);
        d += a.x * bv.x + a.y * bv.y + a.z * bv.z + a.w * bv.w;
    }
#pragma unroll
    for (int o = 32; o; o >>= 1) d += __shfl_xor(d, o);
    if (lane == 0) h[j] = fmaxf(d + bh[j], 0.f);
}

__global__ __launch_bounds__(128)
void logit_k(const float* __restrict__ h, const float* __restrict__ Wc,
             const float* __restrict__ bc, float* __restrict__ out)
{
    int wid = threadIdx.x >> 6, lane = threadIdx.x & 63;
    const float* wr = Wc + (size_t)wid * 512;
    float d = 0.f;
#pragma unroll
    for (int t = 0; t < 2; t++) {
        float4 a = *(const float4*)(wr + t * 256 + lane * 4);
        float4 hv = *(const float4*)(h + t * 256 + lane * 4);
        d += a.x * hv.x + a.y * hv.y + a.z * hv.z + a.w * hv.w;
    }
#pragma unroll
    for (int o = 32; o; o >>= 1) d += __shfl_xor(d, o);
    if (lane == 0) out[wid] = d + bc[wid];
}

extern "C" void kernel_launch(void* const* d_in, const int* in_sizes, int n_in,
                              void* d_out, int out_size, void* d_ws, size_t ws_size,
                              hipStream_t stream)
{
    const float* data    = (const float*)d_in[0];
    const float* protos  = (const float*)d_in[1];
    const float* W_pp    = (const float*)d_in[2];
    const float* b_pp    = (const float*)d_in[3];
    const float* W_cp    = (const float*)d_in[4];
    const float* b_cp    = (const float*)d_in[5];
    const float* sscale  = (const float*)d_in[6];
    const float* enh_w1  = (const float*)d_in[7];
    const float* enh_b1  = (const float*)d_in[8];
    const float* enh_w2  = (const float*)d_in[9];
    const float* enh_b2  = (const float*)d_in[10];
    const float* ln_g    = (const float*)d_in[11];
    const float* ln_b    = (const float*)d_in[12];
    const float* red_w1[3] = {(const float*)d_in[13], (const float*)d_in[17], (const float*)d_in[21]};
    const float* red_b1[3] = {(const float*)d_in[14], (const float*)d_in[18], (const float*)d_in[22]};
    const float* red_w2[3] = {(const float*)d_in[15], (const float*)d_in[19], (const float*)d_in[23]};
    const float* red_b2[3] = {(const float*)d_in[16], (const float*)d_in[20], (const float*)d_in[24]};
    const float* W_proc  = (const float*)d_in[25];
    const float* b_proc  = (const float*)d_in[26];
    const float* g_an    = (const float*)d_in[27];
    const float* b_an    = (const float*)d_in[28];
    const float* W_t     = (const float*)d_in[29];
    const float* b_t     = (const float*)d_in[30];
    const float* W_g     = (const float*)d_in[31];
    const float* b_g     = (const float*)d_in[32];
    const float* W_s     = (const float*)d_in[33];
    const float* b_s     = (const float*)d_in[34];  // unused: softmax shift-invariant
    const float* W_h     = (const float*)d_in[35];
    const float* b_h     = (const float*)d_in[36];
    const float* W_c     = (const float*)d_in[37];
    const float* b_c     = (const float*)d_in[38];
    float* out = (float*)d_out;
    (void)b_s;

    constexpr int N = 32768, DIN = 768, D = 512;
    constexpr int NCHUNK = 256;
    char* w = (char*)d_ws;
    auto alloc = [&](size_t bytes) -> char* {
        char* p = w; w += (bytes + 255) & ~(size_t)255; return p;
    };
    _Float16* Ph     = (_Float16*)alloc((size_t)N * D * 2);
    _Float16* CTXh   = (_Float16*)alloc((size_t)N * D * 2);
    _Float16* TMPh   = (_Float16*)alloc((size_t)N * D * 2);
    _Float16* Zrawh  = (_Float16*)alloc((size_t)(N + 16) * D * 2);
    _Float16* Zh     = (_Float16*)alloc((size_t)(N + 16) * D * 2);
    _Float16* datah  = (_Float16*)alloc((size_t)N * DIN * 2);
    _Float16* Ah     = (_Float16*)alloc((size_t)N * 128 * 2);
    _Float16* Ch     = (_Float16*)alloc(128 * D * 2);
    _Float16* CTh    = (_Float16*)alloc(128 * D * 2);
    _Float16* Wpph   = (_Float16*)alloc((size_t)D * DIN * 2);
    _Float16* w1h    = (_Float16*)alloc((size_t)3 * D * D * 2);
    _Float16* w2h    = (_Float16*)alloc((size_t)3 * D * D * 2);
    _Float16* Wproch = (_Float16*)alloc((size_t)D * D * 2);
    _Float16* Wth    = (_Float16*)alloc((size_t)D * D * 2);
    _Float16* Wgh    = (_Float16*)alloc((size_t)D * D * 2);
    float*    Psq    = (float*)alloc((size_t)N * 4);
    float*    Csq    = (float*)alloc(128 * 4);
    float*    Ca     = (float*)alloc(128 * D * 4);
    float*    Cb     = (float*)alloc(128 * D * 4);
    float*    H1     = (float*)alloc(128 * D * 4);
    float*    scr    = (float*)alloc((size_t)(N + 16) * 4);
    float*    PB     = (float*)alloc((size_t)NCHUNK * D * 4);
    float*    bag    = (float*)alloc(D * 4);
    float*    hb     = (float*)alloc(D * 4);
    float*    scal   = (float*)alloc(8 * 4);

    dim3 blk(256);
    dim3 blk512(512);
    auto cgrid = [](size_t n) { return dim3((unsigned)((n / 4 + 255) / 256)); };
    auto mgrid = [](int M_, int Nout_) { return dim3((Nout_ + TBN - 1) / TBN, (M_ + TBM - 1) / TBM); };

    // --- convert weights + data to f16 ---
    cvt_k<<<cgrid((size_t)N * DIN), blk, 0, stream>>>(data, datah, N * DIN);
    cvt_k<<<cgrid((size_t)D * DIN), blk, 0, stream>>>(W_pp, Wpph, D * DIN);
    cvt_k<<<cgrid((size_t)3 * D * D), blk, 0, stream>>>(enh_w1, w1h, 3 * D * D);
    cvt_k<<<cgrid((size_t)3 * D * D), blk, 0, stream>>>(enh_w2, w2h, 3 * D * D);
    cvt_k<<<cgrid((size_t)D * D), blk, 0, stream>>>(W_proc, Wproch, D * D);
    cvt_k<<<cgrid((size_t)D * D), blk, 0, stream>>>(W_t, Wth, D * D);
    cvt_k<<<cgrid((size_t)D * D), blk, 0, stream>>>(W_g, Wgh, D * D);

    // P = leaky(data @ W_pp^T + b_pp) -> f16, with fused Psq accumulation
    hipMemsetAsync(Psq, 0, (size_t)N * 4, stream);
    mgemm<0, 1, true><<<mgrid(N, D), blk512, 0, stream>>>(datah, Wpph, b_pp, Ph, Psq, N, DIN, D);
    // C0 = leaky(protos @ W_cp^T + b_cp) -> fp32 + f16 set (Ch/CTh/Csq)
    hipMemsetAsync(Csq, 0, 128 * 4, stream);
    dot_k<1, false, true><<<dim3(128 * 512 / 4), blk, 0, stream>>>(protos, W_cp, b_cp, Ca, Ch, CTh, Csq, 128, DIN);

    float* C = Ca;
    float* Cn = Cb;
    int Kin = 128;
    for (int i = 0; i < 3; i++) {
        int Kout = Kin >> 1;
        // A = softmax(-dist/denom) fused with S = P@C^T
        simgemm<<<dim3(1, N / SBM), blk, 0, stream>>>(Ph, Ch, Psq, Csq, sscale, Ah, N, D, Kin);
        if (i < 2) hipMemsetAsync(Psq, 0, (size_t)N * 4, stream);
        // ctx = A @ C -> f16
        mgemm<0, 0, false><<<mgrid(N, D), blk512, 0, stream>>>(Ah, CTh, nullptr, CTXh, nullptr, N, Kin, D);
        // P = LN(P + ctx) -> f16
        ln_k<<<dim3((N + 3) / 4), blk, 0, stream>>>(Ph, CTXh, ln_g + (size_t)i * D, ln_b + (size_t)i * D, Ph, N);
        // enhancer MLP: P += w2 @ relu(w1 @ P + b1) + b2   (enh2 fuses Psq for next iter)
        mgemm<0, 2, false><<<mgrid(N, D), blk512, 0, stream>>>(Ph, w1h + (size_t)i * D * D, enh_b1 + (size_t)i * D, TMPh, nullptr, N, D, D);
        if (i < 2)
            mgemm<1, 0, true><<<mgrid(N, D), blk512, 0, stream>>>(TMPh, w2h + (size_t)i * D * D, enh_b2 + (size_t)i * D, Ph, Psq, N, D, D);
        else
            mgemm<1, 0, false><<<mgrid(N, D), blk512, 0, stream>>>(TMPh, w2h + (size_t)i * D * D, enh_b2 + (size_t)i * D, Ph, nullptr, N, D, D);
        // ProtoReducer; red2 emits next iteration's f16 C set
        hipMemsetAsync(Csq, 0, 128 * 4, stream);
        red1_k<<<dim3(2, Kin), blk, 0, stream>>>(C, red_w1[i], red_b1[i], H1, Kin);
        red2_k<<<dim3(2, Kout), blk, 0, stream>>>(H1, red_w2[i], red_b2[i], Cn, Ch, CTh, Csq, Kin, Kout);
        float* t = C; C = Cn; Cn = t;
        Kin = Kout;
    }

    // Zraw = relu(proc([P; C]))
    mgemm<0, 2, false><<<mgrid(N, D), blk512, 0, stream>>>(Ph, Wproch, b_proc, Zrawh, nullptr, N, D, D);
    dot_k<2, true, false><<<dim3(16 * 512 / 4), blk, 0, stream>>>(C, W_proc, b_proc, Zrawh + (size_t)N * D, nullptr, nullptr, nullptr, 16, D);
    // Z = LN(Zraw)
    ln_k<<<dim3((N + 16 + 3) / 4), blk, 0, stream>>>(Zrawh, nullptr, g_an, b_an, Zh, N + 16);

    // scores = (tanh(Z@W_t^T+b_t) * sigmoid(Z@W_g^T+b_g)) @ W_s  (fused; b_s shift-invariant)
    hipMemsetAsync(scr, 0, (size_t)(N + 16) * 4, stream);
    gatgemm<<<mgrid(N + 16, D), blk512, 0, stream>>>(Zh, Wth, Wgh, b_t, b_g, W_s, scr, N + 16, D, D);

    // attention pooling
    pool_k<<<dim3(1), dim3(1024), 0, stream>>>(scr, scal, N + 16);
    int cs = (N + 16 + NCHUNK - 1) / NCHUNK;
    bagp_k<<<dim3(2, NCHUNK), blk, 0, stream>>>(Zh, scr, PB, N + 16, cs);
    bagf_k<<<dim3(2), blk, 0, stream>>>(PB, scal, bag, NCHUNK);

    // classifier head
    h_k<<<dim3(128), blk, 0, stream>>>(bag, W_h, b_h, hb);
    logit_k<<<dim3(1), dim3(128), 0, stream>>>(hb, W_c, b_c, out);
}

// Round 13
// 858.021 us; speedup vs baseline: 1.3780x; 1.3780x over previous
//
#include <hip/hip_runtime.h>
#include <math.h>

typedef _Float16 f16x8 __attribute__((ext_vector_type(8)));
typedef _Float16 f16x4 __attribute__((ext_vector_type(4)));
typedef float f32x4 __attribute__((ext_vector_type(4)));

#define TBM 256
#define TBN 128
#define TBK 32

#define AS1 __attribute__((address_space(1)))
#define AS3 __attribute__((address_space(3)))

__device__ __forceinline__ void gll16(const _Float16* g, _Float16* l)
{
    __builtin_amdgcn_global_load_lds((const AS1 unsigned int*)g,
                                     (AS3 unsigned int*)l, 16, 0, 0);
}

// bijective XCD chunking (m204)
__device__ __forceinline__ int xcd_swz(int d, int nwg)
{
    int q = nwg >> 3, r = nwg & 7;
    int x = d & 7, idx = d >> 3;
    int base = x < r ? x * (q + 1) : r * (q + 1) + (x - r) * q;
    return base + idx;
}

// ---- fast transcendentals ----
__device__ __forceinline__ float fsigmoid(float x)
{
    return __builtin_amdgcn_rcpf(1.f + __expf(-x));
}
__device__ __forceinline__ float ftanh(float x)
{
    float ax = fabsf(x);
    float e = __expf(-2.f * ax);
    float t = (1.f - e) * __builtin_amdgcn_rcpf(1.f + e);
    return copysignf(t, x);
}

// ---------------- wave-per-output dot kernel (small-M fp32 GEMMs) ----------------
// ACT: 1 leaky, 2 relu ; F16OUT selects output dtype
template<int ACT, bool F16OUT>
__global__ __launch_bounds__(256)
void dot_k(const float* __restrict__ X, const float* __restrict__ W,
           const float* __restrict__ bias, void* __restrict__ Yv,
           int M, int K)
{
    int gw = (blockIdx.x * 256 + threadIdx.x) >> 6;
    int lane = threadIdx.x & 63;
    if (gw >= M * 512) return;
    int r = gw >> 9, n = gw & 511;
    const float* xr = X + (size_t)r * K;
    const float* wr = W + (size_t)n * K;
    float d = 0.f;
    for (int t = 0; t < K; t += 256) {
        float4 a = *(const float4*)(xr + t + lane * 4);
        float4 b = *(const float4*)(wr + t + lane * 4);
        d += a.x * b.x + a.y * b.y + a.z * b.z + a.w * b.w;
    }
#pragma unroll
    for (int o = 32; o; o >>= 1) d += __shfl_xor(d, o);
    if (lane == 0) {
        float v = d + bias[n];
        if (ACT == 1) v = v > 0.f ? v : 0.01f * v;
        else if (ACT == 2) v = fmaxf(v, 0.f);
        if (F16OUT) ((_Float16*)Yv)[(size_t)r * 512 + n] = (_Float16)v;
        else        ((float*)Yv)[(size_t)r * 512 + n] = v;
    }
}

// C [Kin,512] fp32 -> Ch, CTh f16 + Csq row sum-of-squares; one wave per row (no atomics)
__global__ __launch_bounds__(256)
void cvtC2_k(const float* __restrict__ C, _Float16* __restrict__ Ch,
             _Float16* __restrict__ CTh, float* __restrict__ Csq, int Kin)
{
    int w = threadIdx.x >> 6, lane = threadIdx.x & 63;
    int row = blockIdx.x * 4 + w;
    if (row >= Kin) return;
    float4 a = *(const float4*)(C + (size_t)row * 512 + lane * 8);
    float4 b = *(const float4*)(C + (size_t)row * 512 + lane * 8 + 4);
    f16x8 h;
    h[0] = (_Float16)a.x; h[1] = (_Float16)a.y; h[2] = (_Float16)a.z; h[3] = (_Float16)a.w;
    h[4] = (_Float16)b.x; h[5] = (_Float16)b.y; h[6] = (_Float16)b.z; h[7] = (_Float16)b.w;
    *(f16x8*)(Ch + (size_t)row * 512 + lane * 8) = h;
    float s = 0.f;
#pragma unroll
    for (int q = 0; q < 8; q++) {
        float f = (float)h[q];
        s += f * f;
        CTh[(size_t)(lane * 8 + q) * Kin + row] = h[q];
    }
#pragma unroll
    for (int o = 32; o; o >>= 1) s += __shfl_xor(s, o);
    if (lane == 0) Csq[row] = s;
}

// ---------------- f16 MFMA GEMM: 256x128 tile, 8 waves, LDS dbuf, repacked epilogue ----------------
// MODE 0: out = act(v) -> Yh f16; MODE 1: out = Yh + v (coalesced RMW)
// ACT: 0 none, 1 leaky, 2 relu ; SQ: atomicAdd row sum-of-squares of final f16 into Psq
template<int MODE, int ACT, bool SQ>
__global__ __launch_bounds__(512)
void mgemm(const _Float16* __restrict__ A, const _Float16* __restrict__ B,
           const float* __restrict__ bias, _Float16* __restrict__ Yh,
           float* __restrict__ Psq, int M, int K, int Nout)
{
    __shared__ _Float16 As[2][TBM * TBK];
    __shared__ _Float16 Bs[2][TBN * TBK];
    const int tid = threadIdx.x;
    const int lane = tid & 63;
    const int wid = tid >> 6;
    const int wr = wid >> 1, wc = wid & 1;

    int bid = xcd_swz(blockIdx.y * gridDim.x + blockIdx.x, gridDim.x * gridDim.y);
    const int m0 = (bid / gridDim.x) * TBM;
    const int n0 = (bid % gridDim.x) * TBN;

    f32x4 acc[4][4] = {};
    const int nt = K / TBK;

    const int lrow = lane >> 2;
    const int lk = (lane & 3) * 8;

    auto stage = [&](int t, int buf) {
        const int k0 = t * TBK;
#pragma unroll
        for (int q = 0; q < 2; q++) {
            int c = wid * 2 + q;
            int r = c * 16 + lrow;
            int am = min(m0 + r, M - 1);
            gll16(A + (size_t)am * K + k0 + lk, &As[buf][c * 512]);
        }
        {
            int c = wid;
            int r = c * 16 + lrow;
            int bn = min(n0 + r, Nout - 1);
            gll16(B + (size_t)bn * K + k0 + lk, &Bs[buf][c * 512]);
        }
    };

    stage(0, 0);
    __syncthreads();
    for (int t = 0; t < nt; ++t) {
        const int cur = t & 1;
        if (t + 1 < nt) stage(t + 1, cur ^ 1);
        f16x8 af[4], bf[4];
#pragma unroll
        for (int mi = 0; mi < 4; mi++)
            af[mi] = *(const f16x8*)(&As[cur][(wr * 64 + mi * 16 + (lane & 15)) * TBK + (lane >> 4) * 8]);
#pragma unroll
        for (int nj = 0; nj < 4; nj++)
            bf[nj] = *(const f16x8*)(&Bs[cur][(wc * 64 + nj * 16 + (lane & 15)) * TBK + (lane >> 4) * 8]);
#pragma unroll
        for (int mi = 0; mi < 4; mi++)
#pragma unroll
            for (int nj = 0; nj < 4; nj++)
                acc[mi][nj] = __builtin_amdgcn_mfma_f32_16x16x32_f16(af[mi], bf[nj], acc[mi][nj], 0, 0, 0);
        __syncthreads();
    }

    // ---- epilogue: repack 256x128 tile via LDS in two 128-row phases ----
    _Float16* eb = &As[0][0];
    const int g = lane >> 4;
#pragma unroll
    for (int p = 0; p < 2; p++) {
        if (p) __syncthreads();
        if ((wr >> 1) == p) {
#pragma unroll
            for (int nj = 0; nj < 4; nj++) {
                int col = wc * 64 + nj * 16 + (lane & 15);
                float bv = bias ? bias[n0 + col] : 0.f;
#pragma unroll
                for (int mi = 0; mi < 4; mi++)
#pragma unroll
                    for (int r = 0; r < 4; r++) {
                        int lr = (wr & 1) * 64 + mi * 16 + g * 4 + r;
                        float v = acc[mi][nj][r] + bv;
                        if (MODE == 0) {
                            if (ACT == 1) v = v > 0.f ? v : 0.01f * v;
                            else if (ACT == 2) v = fmaxf(v, 0.f);
                        }
                        eb[lr * 128 + col] = (_Float16)v;
                    }
            }
        }
        __syncthreads();
        int t4 = tid * 4;
        int lr = t4 >> 4;
        int cbase = (t4 & 15) * 8;
        int m = m0 + p * 128 + lr;
        float sq = 0.f;
        if (m < M) {
#pragma unroll
            for (int q = 0; q < 4; q++) {
                int c0 = cbase + q * 8;
                f16x8 hv = *(f16x8*)(eb + lr * 128 + c0);
                size_t gidx = (size_t)m * Nout + n0 + c0;
                if (MODE == 1) {
                    f16x8 old = *(f16x8*)(Yh + gidx);
                    f16x8 nw;
#pragma unroll
                    for (int e = 0; e < 8; e++) {
                        float s = (float)old[e] + (float)hv[e];
                        nw[e] = (_Float16)s;
                    }
                    *(f16x8*)(Yh + gidx) = nw;
                    hv = nw;
                } else {
                    *(f16x8*)(Yh + gidx) = hv;
                }
                if (SQ) {
#pragma unroll
                    for (int e = 0; e < 8; e++) { float f = (float)hv[e]; sq += f * f; }
                }
            }
        }
        if (SQ) {
            sq += __shfl_xor(sq, 1);
            sq += __shfl_xor(sq, 2);
            if ((lane & 3) == 0 && m < M) atomicAdd(&Psq[m], sq);
        }
    }
}

// ---------------- fused gate + attention-score GEMM ----------------
// scr[m] += sum_n tanh(A@B1^T+c1)[m,n] * sigmoid(A@B2^T+c2)[m,n] * Ws[n]
__global__ __launch_bounds__(512)
void gatgemm(const _Float16* __restrict__ A, const _Float16* __restrict__ B1,
             const _Float16* __restrict__ B2, const float* __restrict__ c1,
             const float* __restrict__ c2, const float* __restrict__ Ws,
             float* __restrict__ scr, int M, int K, int Nout)
{
    __shared__ _Float16 As[2][TBM * TBK];
    __shared__ _Float16 B1s[2][TBN * TBK];
    __shared__ _Float16 B2s[2][TBN * TBK];
    const int tid = threadIdx.x;
    const int lane = tid & 63;
    const int wid = tid >> 6;
    const int wr = wid >> 1, wc = wid & 1;

    int bid = xcd_swz(blockIdx.y * gridDim.x + blockIdx.x, gridDim.x * gridDim.y);
    const int m0 = (bid / gridDim.x) * TBM;
    const int n0 = (bid % gridDim.x) * TBN;

    f32x4 acc1[4][4] = {};
    f32x4 acc2[4][4] = {};
    const int nt = K / TBK;

    const int lrow = lane >> 2;
    const int lk = (lane & 3) * 8;

    auto stage = [&](int t, int buf) {
        const int k0 = t * TBK;
#pragma unroll
        for (int q = 0; q < 2; q++) {
            int c = wid * 2 + q;
            int r = c * 16 + lrow;
            int am = min(m0 + r, M - 1);
            gll16(A + (size_t)am * K + k0 + lk, &As[buf][c * 512]);
        }
        {
            int c = wid;
            int r = c * 16 + lrow;
            int bn = min(n0 + r, Nout - 1);
            gll16(B1 + (size_t)bn * K + k0 + lk, &B1s[buf][c * 512]);
            gll16(B2 + (size_t)bn * K + k0 + lk, &B2s[buf][c * 512]);
        }
    };

    stage(0, 0);
    __syncthreads();
    for (int t = 0; t < nt; ++t) {
        const int cur = t & 1;
        if (t + 1 < nt) stage(t + 1, cur ^ 1);
        f16x8 af[4], bf1[4], bf2[4];
#pragma unroll
        for (int mi = 0; mi < 4; mi++)
            af[mi] = *(const f16x8*)(&As[cur][(wr * 64 + mi * 16 + (lane & 15)) * TBK + (lane >> 4) * 8]);
#pragma unroll
        for (int nj = 0; nj < 4; nj++) {
            int ro = (wc * 64 + nj * 16 + (lane & 15)) * TBK + (lane >> 4) * 8;
            bf1[nj] = *(const f16x8*)(&B1s[cur][ro]);
            bf2[nj] = *(const f16x8*)(&B2s[cur][ro]);
        }
#pragma unroll
        for (int mi = 0; mi < 4; mi++)
#pragma unroll
            for (int nj = 0; nj < 4; nj++) {
                acc1[mi][nj] = __builtin_amdgcn_mfma_f32_16x16x32_f16(af[mi], bf1[nj], acc1[mi][nj], 0, 0, 0);
                acc2[mi][nj] = __builtin_amdgcn_mfma_f32_16x16x32_f16(af[mi], bf2[nj], acc2[mi][nj], 0, 0, 0);
            }
        __syncthreads();
    }

    // ---- epilogue: gate + per-row partial dot with Ws, atomic accumulate ----
    const int g = lane >> 4;
    float wsv[4];
#pragma unroll
    for (int nj = 0; nj < 4; nj++)
        wsv[nj] = Ws[n0 + wc * 64 + nj * 16 + (lane & 15)];
#pragma unroll
    for (int mi = 0; mi < 4; mi++) {
#pragma unroll
        for (int r = 0; r < 4; r++) {
            float p = 0.f;
#pragma unroll
            for (int nj = 0; nj < 4; nj++) {
                int col = n0 + wc * 64 + nj * 16 + (lane & 15);
                float t1 = ftanh(acc1[mi][nj][r] + c1[col]);
                float g1 = fsigmoid(acc2[mi][nj][r] + c2[col]);
                p += t1 * g1 * wsv[nj];
            }
#pragma unroll
            for (int o = 1; o < 16; o <<= 1) p += __shfl_xor(p, o);
            if ((lane & 15) == 0) {
                int m = m0 + wr * 64 + mi * 16 + g * 4 + r;
                if (m < M) atomicAdd(&scr[m], p);
            }
        }
    }
}

// ---------------- fused sim GEMM + row softmax: 128-row blocks, 4 waves ----------------
#define SBM 128
__global__ __launch_bounds__(256)
void simgemm(const _Float16* __restrict__ A, const _Float16* __restrict__ B,
             const float* __restrict__ Psq, const float* __restrict__ Csq,
             const float* __restrict__ sscale, _Float16* __restrict__ Ah,
             int M, int K, int Kin)
{
    __shared__ _Float16 As[2][SBM * TBK];
    __shared__ _Float16 Bs[2][SBM * TBK];
    __shared__ float redmx[2][SBM];
    __shared__ float redsm[2][SBM];
    const int tid = threadIdx.x;
    const int lane = tid & 63;
    const int wid = tid >> 6;
    const int wr = wid >> 1, wc = wid & 1;
    const int m0 = blockIdx.y * SBM;

    f32x4 acc[4][4] = {};
    const int nt = K / TBK;
    const int lrow = lane >> 2;
    const int lk = (lane & 3) * 8;

    auto stage = [&](int t, int buf) {
        const int k0 = t * TBK;
#pragma unroll
        for (int q = 0; q < 2; q++) {
            int c = wid * 2 + q;
            int r = c * 16 + lrow;
            int am = min(m0 + r, M - 1);
            int bn = min(r, Kin - 1);
            gll16(A + (size_t)am * K + k0 + lk, &As[buf][c * 512]);
            gll16(B + (size_t)bn * K + k0 + lk, &Bs[buf][c * 512]);
        }
    };

    stage(0, 0);
    __syncthreads();
    for (int t = 0; t < nt; ++t) {
        const int cur = t & 1;
        if (t + 1 < nt) stage(t + 1, cur ^ 1);
        f16x8 af[4], bf[4];
#pragma unroll
        for (int mi = 0; mi < 4; mi++)
            af[mi] = *(const f16x8*)(&As[cur][(wr * 64 + mi * 16 + (lane & 15)) * TBK + (lane >> 4) * 8]);
#pragma unroll
        for (int nj = 0; nj < 4; nj++)
            bf[nj] = *(const f16x8*)(&Bs[cur][(wc * 64 + nj * 16 + (lane & 15)) * TBK + (lane >> 4) * 8]);
#pragma unroll
        for (int mi = 0; mi < 4; mi++)
#pragma unroll
            for (int nj = 0; nj < 4; nj++)
                acc[mi][nj] = __builtin_amdgcn_mfma_f32_16x16x32_f16(af[mi], bf[nj], acc[mi][nj], 0, 0, 0);
        __syncthreads();
    }

    const float denom = fmaxf(1e-6f, sscale[0]);
    const int colbase = wc * 64 + (lane & 15);
    const int g = lane >> 4;
    float cc[4];
#pragma unroll
    for (int nj = 0; nj < 4; nj++) {
        int n = colbase + nj * 16;
        cc[nj] = (n < Kin) ? Csq[n] : 0.f;
    }

#pragma unroll
    for (int mi = 0; mi < 4; mi++) {
#pragma unroll
        for (int r = 0; r < 4; r++) {
            int row = wr * 64 + mi * 16 + g * 4 + r;
            float pp = Psq[m0 + row];
            float mx = -INFINITY;
#pragma unroll
            for (int nj = 0; nj < 4; nj++) {
                int n = colbase + nj * 16;
                float v = -INFINITY;
                if (n < Kin)
                    v = -sqrtf(fmaxf(pp + cc[nj] - 2.f * acc[mi][nj][r], 1e-12f)) / denom;
                acc[mi][nj][r] = v;
                mx = fmaxf(mx, v);
            }
#pragma unroll
            for (int o = 1; o < 16; o <<= 1) mx = fmaxf(mx, __shfl_xor(mx, o));
            if ((lane & 15) == 0) redmx[wc][row] = mx;
        }
    }
    __syncthreads();

#pragma unroll
    for (int mi = 0; mi < 4; mi++) {
#pragma unroll
        for (int r = 0; r < 4; r++) {
            int row = wr * 64 + mi * 16 + g * 4 + r;
            float mx = fmaxf(redmx[0][row], redmx[1][row]);
            float s = 0.f;
#pragma unroll
            for (int nj = 0; nj < 4; nj++) {
                int n = colbase + nj * 16;
                float e = (n < Kin) ? __expf(acc[mi][nj][r] - mx) : 0.f;
                acc[mi][nj][r] = e;
                s += e;
            }
#pragma unroll
            for (int o = 1; o < 16; o <<= 1) s += __shfl_xor(s, o);
            if ((lane & 15) == 0) redsm[wc][row] = s;
        }
    }
    __syncthreads();

#pragma unroll
    for (int mi = 0; mi < 4; mi++) {
#pragma unroll
        for (int r = 0; r < 4; r++) {
            int row = wr * 64 + mi * 16 + g * 4 + r;
            float inv = __builtin_amdgcn_rcpf(redsm[0][row] + redsm[1][row]);
            int m = m0 + row;
#pragma unroll
            for (int nj = 0; nj < 4; nj++) {
                int n = colbase + nj * 16;
                if (n < Kin)
                    Ah[(size_t)m * Kin + n] = (_Float16)(acc[mi][nj][r] * inv);
            }
        }
    }
}

// ---------------- converters ----------------
__global__ __launch_bounds__(256)
void cvt_k(const float* __restrict__ x, _Float16* __restrict__ y, int n)
{
    int i = (blockIdx.x * 256 + threadIdx.x) * 4;
    if (i < n) {
        float4 v = *(const float4*)(x + i);
        f16x4 h = { (_Float16)v.x, (_Float16)v.y, (_Float16)v.z, (_Float16)v.w };
        *(f16x4*)(y + i) = h;
    }
}

// ---------------- small kernels (f16 activations) ----------------
__global__ __launch_bounds__(256)
void ln_k(const _Float16* __restrict__ X, const _Float16* __restrict__ R,
          const float* __restrict__ g, const float* __restrict__ b,
          _Float16* __restrict__ Yh, int M)
{
    int wid = threadIdx.x >> 6, lane = threadIdx.x & 63;
    int row = blockIdx.x * 4 + wid;
    if (row >= M) return;
    f16x8 a = *(const f16x8*)(X + (size_t)row * 512 + lane * 8);
    float v[8];
#pragma unroll
    for (int q = 0; q < 8; q++) v[q] = (float)a[q];
    if (R) {
        f16x8 c = *(const f16x8*)(R + (size_t)row * 512 + lane * 8);
#pragma unroll
        for (int q = 0; q < 8; q++) v[q] += (float)c[q];
    }
    float s = 0.f, ss = 0.f;
#pragma unroll
    for (int q = 0; q < 8; q++) { s += v[q]; ss += v[q] * v[q]; }
#pragma unroll
    for (int o = 32; o; o >>= 1) { s += __shfl_xor(s, o); ss += __shfl_xor(ss, o); }
    float mean = s * (1.f / 512.f);
    float var = ss * (1.f / 512.f) - mean * mean;
    float inv = 1.f / sqrtf(var + 1e-5f);
    int d0 = lane * 8;
    f16x8 o8;
#pragma unroll
    for (int q = 0; q < 8; q++)
        o8[q] = (_Float16)((v[q] - mean) * inv * g[d0 + q] + b[d0 + q]);
    *(f16x8*)(Yh + (size_t)row * 512 + d0) = o8;
}

__global__ __launch_bounds__(256)
void red1_k(const float* __restrict__ C, const float* __restrict__ w1,
            const float* __restrict__ b1, float* __restrict__ H1, int Kin)
{
    int d = blockIdx.x * 256 + threadIdx.x;
    int j = blockIdx.y;
    float acc = b1[j];
    for (int k = 0; k < Kin; k++) acc = fmaf(C[(size_t)k * 512 + d], w1[(size_t)j * Kin + k], acc);
    H1[(size_t)j * 512 + d] = fmaxf(acc, 0.f);
}

// red2 + fused f16 conversion/transpose/Csq emission for the NEXT iteration
__global__ __launch_bounds__(256)
void red2_k(const float* __restrict__ H1, const float* __restrict__ w2,
            const float* __restrict__ b2, float* __restrict__ Cn,
            _Float16* __restrict__ Chn, _Float16* __restrict__ CThn,
            float* __restrict__ Csqn, int Kin, int Kout)
{
    int d = blockIdx.x * 256 + threadIdx.x;
    int j2 = blockIdx.y;
    float acc = b2[j2];
    for (int j = 0; j < Kin; j++) acc = fmaf(H1[(size_t)j * 512 + d], w2[(size_t)j2 * Kin + j], acc);
    Cn[(size_t)j2 * 512 + d] = acc;
    _Float16 h = (_Float16)acc;
    Chn[(size_t)j2 * 512 + d] = h;
    CThn[(size_t)d * Kout + j2] = h;
    float f = (float)h;
    float sq = f * f;
#pragma unroll
    for (int o = 32; o; o >>= 1) sq += __shfl_xor(sq, o);
    if ((threadIdx.x & 63) == 0) atomicAdd(&Csqn[j2], sq);
}

__global__ __launch_bounds__(1024)
void pool_k(float* __restrict__ s, float* __restrict__ scal, int M)
{
    __shared__ float sm[16];
    int tid = threadIdx.x, lane = tid & 63, wid = tid >> 6;
    float mx = -INFINITY;
    for (int i = tid * 4; i < M; i += 4096) {
        float4 a = *(const float4*)(s + i);
        mx = fmaxf(fmaxf(fmaxf(mx, a.x), fmaxf(a.y, a.z)), a.w);
    }
#pragma unroll
    for (int o = 32; o; o >>= 1) mx = fmaxf(mx, __shfl_xor(mx, o));
    if (lane == 0) sm[wid] = mx;
    __syncthreads();
    if (wid == 0) {
        float v = (lane < 16) ? sm[lane] : -INFINITY;
#pragma unroll
        for (int o = 8; o; o >>= 1) v = fmaxf(v, __shfl_xor(v, o));
        if (lane == 0) sm[0] = v;
    }
    __syncthreads();
    float gmax = sm[0];
    __syncthreads();
    float sum = 0.f;
    for (int i = tid * 4; i < M; i += 4096) {
        float4 a = *(const float4*)(s + i);
        float4 e;
        e.x = __expf(a.x - gmax); e.y = __expf(a.y - gmax);
        e.z = __expf(a.z - gmax); e.w = __expf(a.w - gmax);
        *(float4*)(s + i) = e;
        sum += e.x + e.y + e.z + e.w;
    }
#pragma unroll
    for (int o = 32; o; o >>= 1) sum += __shfl_xor(sum, o);
    if (lane == 0) sm[wid] = sum;
    __syncthreads();
    if (tid == 0) {
        float t = 0.f;
        for (int w = 0; w < 16; w++) t += sm[w];
        scal[0] = t;
    }
}

__global__ __launch_bounds__(256)
void bagp_k(const _Float16* __restrict__ Z, const float* __restrict__ w,
            float* __restrict__ PB, int M, int cs)
{
    int d = blockIdx.x * 256 + threadIdx.x;
    int chunk = blockIdx.y;
    int i0 = chunk * cs;
    int i1 = min(M, i0 + cs);
    float acc = 0.f;
    for (int i = i0; i < i1; i++) acc = fmaf(w[i], (float)Z[(size_t)i * 512 + d], acc);
    PB[(size_t)chunk * 512 + d] = acc;
}

__global__ __launch_bounds__(256)
void bagf_k(const float* __restrict__ PB, const float* __restrict__ scal,
            float* __restrict__ bag, int nchunk)
{
    int d = blockIdx.x * 256 + threadIdx.x;
    float acc = 0.f;
    for (int c = 0; c < nchunk; c++) acc += PB[(size_t)c * 512 + d];
    bag[d] = acc / scal[0];
}

__global__ __launch_bounds__(256)
void h_k(const float* __restrict__ bag, const float* __restrict__ Wh,
         const float* __restrict__ bh, float* __restrict__ h)
{
    int wid = threadIdx.x >> 6, lane = threadIdx.x & 63;
    int j = blockIdx.x * 4 + wid;
    const float* wr = Wh + (size_t)j * 512;
    float d = 0.f;
#pragma unroll
    for (int t = 0; t < 2; t++) {
        float4 a = *(const float4*)(wr + t * 256 + lane * 4);
        float4 bv = *(const float4*)(bag + t * 256 + lane * 4);
        d += a.x * bv.x + a.y * bv.y + a.z * bv.z + a.w * bv.w;
    }
#pragma unroll
    for (int o = 32; o; o >>= 1) d += __shfl_xor(d, o);
    if (lane == 0) h[j] = fmaxf(d + bh[j], 0.f);
}

__global__ __launch_bounds__(128)
void logit_k(const float* __restrict__ h, const float* __restrict__ Wc,
             const float* __restrict__ bc, float* __restrict__ out)
{
    int wid = threadIdx.x >> 6, lane = threadIdx.x & 63;
    const float* wr = Wc + (size_t)wid * 512;
    float d = 0.f;
#pragma unroll
    for (int t = 0; t < 2; t++) {
        float4 a = *(const float4*)(wr + t * 256 + lane * 4);
        float4 hv = *(const float4*)(h + t * 256 + lane * 4);
        d += a.x * hv.x + a.y * hv.y + a.z * hv.z + a.w * hv.w;
    }
#pragma unroll
    for (int o = 32; o; o >>= 1) d += __shfl_xor(d, o);
    if (lane == 0) out[wid] = d + bc[wid];
}

extern "C" void kernel_launch(void* const* d_in, const int* in_sizes, int n_in,
                              void* d_out, int out_size, void* d_ws, size_t ws_size,
                              hipStream_t stream)
{
    const float* data    = (const float*)d_in[0];
    const float* protos  = (const float*)d_in[1];
    const float* W_pp    = (const float*)d_in[2];
    const float* b_pp    = (const float*)d_in[3];
    const float* W_cp    = (const float*)d_in[4];
    const float* b_cp    = (const float*)d_in[5];
    const float* sscale  = (const float*)d_in[6];
    const float* enh_w1  = (const float*)d_in[7];
    const float* enh_b1  = (const float*)d_in[8];
    const float* enh_w2  = (const float*)d_in[9];
    const float* enh_b2  = (const float*)d_in[10];
    const float* ln_g    = (const float*)d_in[11];
    const float* ln_b    = (const float*)d_in[12];
    const float* red_w1[3] = {(const float*)d_in[13], (const float*)d_in[17], (const float*)d_in[21]};
    const float* red_b1[3] = {(const float*)d_in[14], (const float*)d_in[18], (const float*)d_in[22]};
    const float* red_w2[3] = {(const float*)d_in[15], (const float*)d_in[19], (const float*)d_in[23]};
    const float* red_b2[3] = {(const float*)d_in[16], (const float*)d_in[20], (const float*)d_in[24]};
    const float* W_proc  = (const float*)d_in[25];
    const float* b_proc  = (const float*)d_in[26];
    const float* g_an    = (const float*)d_in[27];
    const float* b_an    = (const float*)d_in[28];
    const float* W_t     = (const float*)d_in[29];
    const float* b_t     = (const float*)d_in[30];
    const float* W_g     = (const float*)d_in[31];
    const float* b_g     = (const float*)d_in[32];
    const float* W_s     = (const float*)d_in[33];
    const float* b_s     = (const float*)d_in[34];  // unused: softmax shift-invariant
    const float* W_h     = (const float*)d_in[35];
    const float* b_h     = (const float*)d_in[36];
    const float* W_c     = (const float*)d_in[37];
    const float* b_c     = (const float*)d_in[38];
    float* out = (float*)d_out;
    (void)b_s;

    constexpr int N = 32768, DIN = 768, D = 512;
    constexpr int NCHUNK = 256;
    char* w = (char*)d_ws;
    auto alloc = [&](size_t bytes) -> char* {
        char* p = w; w += (bytes + 255) & ~(size_t)255; return p;
    };
    _Float16* Ph     = (_Float16*)alloc((size_t)N * D * 2);
    _Float16* CTXh   = (_Float16*)alloc((size_t)N * D * 2);
    _Float16* TMPh   = (_Float16*)alloc((size_t)N * D * 2);
    _Float16* Zrawh  = (_Float16*)alloc((size_t)(N + 16) * D * 2);
    _Float16* Zh     = (_Float16*)alloc((size_t)(N + 16) * D * 2);
    _Float16* datah  = (_Float16*)alloc((size_t)N * DIN * 2);
    _Float16* Ah     = (_Float16*)alloc((size_t)N * 128 * 2);
    _Float16* Ch     = (_Float16*)alloc(128 * D * 2);
    _Float16* CTh    = (_Float16*)alloc(128 * D * 2);
    _Float16* Wpph   = (_Float16*)alloc((size_t)D * DIN * 2);
    _Float16* w1h    = (_Float16*)alloc((size_t)3 * D * D * 2);
    _Float16* w2h    = (_Float16*)alloc((size_t)3 * D * D * 2);
    _Float16* Wproch = (_Float16*)alloc((size_t)D * D * 2);
    _Float16* Wth    = (_Float16*)alloc((size_t)D * D * 2);
    _Float16* Wgh    = (_Float16*)alloc((size_t)D * D * 2);
    float*    Psq    = (float*)alloc((size_t)N * 4);
    float*    Csq    = (float*)alloc(128 * 4);
    float*    Ca     = (float*)alloc(128 * D * 4);
    float*    Cb     = (float*)alloc(128 * D * 4);
    float*    H1     = (float*)alloc(128 * D * 4);
    float*    scr    = (float*)alloc((size_t)(N + 16) * 4);
    float*    PB     = (float*)alloc((size_t)NCHUNK * D * 4);
    float*    bag    = (float*)alloc(D * 4);
    float*    hb     = (float*)alloc(D * 4);
    float*    scal   = (float*)alloc(8 * 4);

    dim3 blk(256);
    dim3 blk512(512);
    auto cgrid = [](size_t n) { return dim3((unsigned)((n / 4 + 255) / 256)); };
    auto mgrid = [](int M_, int Nout_) { return dim3((Nout_ + TBN - 1) / TBN, (M_ + TBM - 1) / TBM); };

    // --- convert weights + data to f16 ---
    cvt_k<<<cgrid((size_t)N * DIN), blk, 0, stream>>>(data, datah, N * DIN);
    cvt_k<<<cgrid((size_t)D * DIN), blk, 0, stream>>>(W_pp, Wpph, D * DIN);
    cvt_k<<<cgrid((size_t)3 * D * D), blk, 0, stream>>>(enh_w1, w1h, 3 * D * D);
    cvt_k<<<cgrid((size_t)3 * D * D), blk, 0, stream>>>(enh_w2, w2h, 3 * D * D);
    cvt_k<<<cgrid((size_t)D * D), blk, 0, stream>>>(W_proc, Wproch, D * D);
    cvt_k<<<cgrid((size_t)D * D), blk, 0, stream>>>(W_t, Wth, D * D);
    cvt_k<<<cgrid((size_t)D * D), blk, 0, stream>>>(W_g, Wgh, D * D);

    // P = leaky(data @ W_pp^T + b_pp) -> f16, with fused Psq accumulation
    hipMemsetAsync(Psq, 0, (size_t)N * 4, stream);
    mgemm<0, 1, true><<<mgrid(N, D), blk512, 0, stream>>>(datah, Wpph, b_pp, Ph, Psq, N, DIN, D);
    // C0 = leaky(protos @ W_cp^T + b_cp) -> fp32, then f16 set via cvtC2
    dot_k<1, false><<<dim3(128 * 512 / 4), blk, 0, stream>>>(protos, W_cp, b_cp, Ca, 128, DIN);
    cvtC2_k<<<dim3(32), blk, 0, stream>>>(Ca, Ch, CTh, Csq, 128);

    float* C = Ca;
    float* Cn = Cb;
    int Kin = 128;
    for (int i = 0; i < 3; i++) {
        int Kout = Kin >> 1;
        // A = softmax(-dist/denom) fused with S = P@C^T
        simgemm<<<dim3(1, N / SBM), blk, 0, stream>>>(Ph, Ch, Psq, Csq, sscale, Ah, N, D, Kin);
        if (i < 2) hipMemsetAsync(Psq, 0, (size_t)N * 4, stream);
        // ctx = A @ C -> f16
        mgemm<0, 0, false><<<mgrid(N, D), blk512, 0, stream>>>(Ah, CTh, nullptr, CTXh, nullptr, N, Kin, D);
        // P = LN(P + ctx) -> f16
        ln_k<<<dim3((N + 3) / 4), blk, 0, stream>>>(Ph, CTXh, ln_g + (size_t)i * D, ln_b + (size_t)i * D, Ph, N);
        // enhancer MLP: P += w2 @ relu(w1 @ P + b1) + b2   (enh2 fuses Psq for next iter)
        mgemm<0, 2, false><<<mgrid(N, D), blk512, 0, stream>>>(Ph, w1h + (size_t)i * D * D, enh_b1 + (size_t)i * D, TMPh, nullptr, N, D, D);
        if (i < 2)
            mgemm<1, 0, true><<<mgrid(N, D), blk512, 0, stream>>>(TMPh, w2h + (size_t)i * D * D, enh_b2 + (size_t)i * D, Ph, Psq, N, D, D);
        else
            mgemm<1, 0, false><<<mgrid(N, D), blk512, 0, stream>>>(TMPh, w2h + (size_t)i * D * D, enh_b2 + (size_t)i * D, Ph, nullptr, N, D, D);
        // ProtoReducer; red2 emits next iteration's f16 C set
        hipMemsetAsync(Csq, 0, 128 * 4, stream);
        red1_k<<<dim3(2, Kin), blk, 0, stream>>>(C, red_w1[i], red_b1[i], H1, Kin);
        red2_k<<<dim3(2, Kout), blk, 0, stream>>>(H1, red_w2[i], red_b2[i], Cn, Ch, CTh, Csq, Kin, Kout);
        float* t = C; C = Cn; Cn = t;
        Kin = Kout;
    }

    // Zraw = relu(proc([P; C]))
    mgemm<0, 2, false><<<mgrid(N, D), blk512, 0, stream>>>(Ph, Wproch, b_proc, Zrawh, nullptr, N, D, D);
    dot_k<2, true><<<dim3(16 * 512 / 4), blk, 0, stream>>>(C, W_proc, b_proc, Zrawh + (size_t)N * D, 16, D);
    // Z = LN(Zraw)
    ln_k<<<dim3((N + 16 + 3) / 4), blk, 0, stream>>>(Zrawh, nullptr, g_an, b_an, Zh, N + 16);

    // scores = (tanh(Z@W_t^T+b_t) * sigmoid(Z@W_g^T+b_g)) @ W_s  (fused; b_s shift-invariant)
    hipMemsetAsync(scr, 0, (size_t)(N + 16) * 4, stream);
    gatgemm<<<mgrid(N + 16, D), blk512, 0, stream>>>(Zh, Wth, Wgh, b_t, b_g, W_s, scr, N + 16, D, D);

    // attention pooling
    pool_k<<<dim3(1), dim3(1024), 0, stream>>>(scr, scal, N + 16);
    int cs = (N + 16 + NCHUNK - 1) / NCHUNK;
    bagp_k<<<dim3(2, NCHUNK), blk, 0, stream>>>(Zh, scr, PB, N + 16, cs);
    bagf_k<<<dim3(2), blk, 0, stream>>>(PB, scal, bag, NCHUNK);

    // classifier head
    h_k<<<dim3(128), blk, 0, stream>>>(bag, W_h, b_h, hb);
    logit_k<<<dim3(1), dim3(128), 0, stream>>>(hb, W_c, b_c, out);
}

// Round 14
// 813.777 us; speedup vs baseline: 1.4529x; 1.0544x over previous
//
#include <hip/hip_runtime.h>
#include <math.h>

typedef _Float16 f16x8 __attribute__((ext_vector_type(8)));
typedef _Float16 f16x4 __attribute__((ext_vector_type(4)));
typedef float f32x4 __attribute__((ext_vector_type(4)));

#define TBM 256
#define TBN 128
#define TBK 32

#define AS1 __attribute__((address_space(1)))
#define AS3 __attribute__((address_space(3)))

__device__ __forceinline__ void gll16(const _Float16* g, _Float16* l)
{
    __builtin_amdgcn_global_load_lds((const AS1 unsigned int*)g,
                                     (AS3 unsigned int*)l, 16, 0, 0);
}

// bijective XCD chunking (m204)
__device__ __forceinline__ int xcd_swz(int d, int nwg)
{
    int q = nwg >> 3, r = nwg & 7;
    int x = d & 7, idx = d >> 3;
    int base = x < r ? x * (q + 1) : r * (q + 1) + (x - r) * q;
    return base + idx;
}

// ---- fast transcendentals ----
__device__ __forceinline__ float fsigmoid(float x)
{
    return __builtin_amdgcn_rcpf(1.f + __expf(-x));
}
__device__ __forceinline__ float ftanh(float x)
{
    float ax = fabsf(x);
    float e = __expf(-2.f * ax);
    float t = (1.f - e) * __builtin_amdgcn_rcpf(1.f + e);
    return copysignf(t, x);
}

// ---------------- wave-per-output dot kernel (small-M fp32 GEMMs) ----------------
template<int ACT, bool F16OUT>
__global__ __launch_bounds__(256)
void dot_k(const float* __restrict__ X, const float* __restrict__ W,
           const float* __restrict__ bias, void* __restrict__ Yv,
           int M, int K)
{
    int gw = (blockIdx.x * 256 + threadIdx.x) >> 6;
    int lane = threadIdx.x & 63;
    if (gw >= M * 512) return;
    int r = gw >> 9, n = gw & 511;
    const float* xr = X + (size_t)r * K;
    const float* wr = W + (size_t)n * K;
    float d = 0.f;
    for (int t = 0; t < K; t += 256) {
        float4 a = *(const float4*)(xr + t + lane * 4);
        float4 b = *(const float4*)(wr + t + lane * 4);
        d += a.x * b.x + a.y * b.y + a.z * b.z + a.w * b.w;
    }
#pragma unroll
    for (int o = 32; o; o >>= 1) d += __shfl_xor(d, o);
    if (lane == 0) {
        float v = d + bias[n];
        if (ACT == 1) v = v > 0.f ? v : 0.01f * v;
        else if (ACT == 2) v = fmaxf(v, 0.f);
        if (F16OUT) ((_Float16*)Yv)[(size_t)r * 512 + n] = (_Float16)v;
        else        ((float*)Yv)[(size_t)r * 512 + n] = v;
    }
}

// C [Kin,512] fp32 -> Ch, CTh f16 + Csq; one wave per row (no atomics)
__global__ __launch_bounds__(256)
void cvtC2_k(const float* __restrict__ C, _Float16* __restrict__ Ch,
             _Float16* __restrict__ CTh, float* __restrict__ Csq, int Kin)
{
    int w = threadIdx.x >> 6, lane = threadIdx.x & 63;
    int row = blockIdx.x * 4 + w;
    if (row >= Kin) return;
    float4 a = *(const float4*)(C + (size_t)row * 512 + lane * 8);
    float4 b = *(const float4*)(C + (size_t)row * 512 + lane * 8 + 4);
    f16x8 h;
    h[0] = (_Float16)a.x; h[1] = (_Float16)a.y; h[2] = (_Float16)a.z; h[3] = (_Float16)a.w;
    h[4] = (_Float16)b.x; h[5] = (_Float16)b.y; h[6] = (_Float16)b.z; h[7] = (_Float16)b.w;
    *(f16x8*)(Ch + (size_t)row * 512 + lane * 8) = h;
    float s = 0.f;
#pragma unroll
    for (int q = 0; q < 8; q++) {
        float f = (float)h[q];
        s += f * f;
        CTh[(size_t)(lane * 8 + q) * Kin + row] = h[q];
    }
#pragma unroll
    for (int o = 32; o; o >>= 1) s += __shfl_xor(s, o);
    if (lane == 0) Csq[row] = s;
}

// ---------------- f16 MFMA GEMM: 256x128 tile, 8 waves, LDS dbuf, repacked epilogue ----------------
// MODE 0: out = act(v) -> Yh f16; MODE 1: out = Yh + v (coalesced RMW)
// ACT: 0 none, 1 leaky, 2 relu ; SQ: atomicAdd row sum-of-squares into Psq
template<int MODE, int ACT, bool SQ>
__global__ __launch_bounds__(512)
void mgemm(const _Float16* __restrict__ A, const _Float16* __restrict__ B,
           const float* __restrict__ bias, _Float16* __restrict__ Yh,
           float* __restrict__ Psq, int M, int K, int Nout)
{
    __shared__ _Float16 As[2][TBM * TBK];
    __shared__ _Float16 Bs[2][TBN * TBK];
    const int tid = threadIdx.x;
    const int lane = tid & 63;
    const int wid = tid >> 6;
    const int wr = wid >> 1, wc = wid & 1;

    int bid = xcd_swz(blockIdx.y * gridDim.x + blockIdx.x, gridDim.x * gridDim.y);
    const int m0 = (bid / gridDim.x) * TBM;
    const int n0 = (bid % gridDim.x) * TBN;

    f32x4 acc[4][4] = {};
    const int nt = K / TBK;

    const int lrow = lane >> 2;
    const int lk = (lane & 3) * 8;

    auto stage = [&](int t, int buf) {
        const int k0 = t * TBK;
#pragma unroll
        for (int q = 0; q < 2; q++) {
            int c = wid * 2 + q;
            int r = c * 16 + lrow;
            int am = min(m0 + r, M - 1);
            gll16(A + (size_t)am * K + k0 + lk, &As[buf][c * 512]);
        }
        {
            int c = wid;
            int r = c * 16 + lrow;
            int bn = min(n0 + r, Nout - 1);
            gll16(B + (size_t)bn * K + k0 + lk, &Bs[buf][c * 512]);
        }
    };

    stage(0, 0);
    __syncthreads();
    for (int t = 0; t < nt; ++t) {
        const int cur = t & 1;
        if (t + 1 < nt) stage(t + 1, cur ^ 1);
        f16x8 af[4], bf[4];
#pragma unroll
        for (int mi = 0; mi < 4; mi++)
            af[mi] = *(const f16x8*)(&As[cur][(wr * 64 + mi * 16 + (lane & 15)) * TBK + (lane >> 4) * 8]);
#pragma unroll
        for (int nj = 0; nj < 4; nj++)
            bf[nj] = *(const f16x8*)(&Bs[cur][(wc * 64 + nj * 16 + (lane & 15)) * TBK + (lane >> 4) * 8]);
#pragma unroll
        for (int mi = 0; mi < 4; mi++)
#pragma unroll
            for (int nj = 0; nj < 4; nj++)
                acc[mi][nj] = __builtin_amdgcn_mfma_f32_16x16x32_f16(af[mi], bf[nj], acc[mi][nj], 0, 0, 0);
        __syncthreads();
    }

    _Float16* eb = &As[0][0];
    const int g = lane >> 4;
#pragma unroll
    for (int p = 0; p < 2; p++) {
        if (p) __syncthreads();
        if ((wr >> 1) == p) {
#pragma unroll
            for (int nj = 0; nj < 4; nj++) {
                int col = wc * 64 + nj * 16 + (lane & 15);
                float bv = bias ? bias[n0 + col] : 0.f;
#pragma unroll
                for (int mi = 0; mi < 4; mi++)
#pragma unroll
                    for (int r = 0; r < 4; r++) {
                        int lr = (wr & 1) * 64 + mi * 16 + g * 4 + r;
                        float v = acc[mi][nj][r] + bv;
                        if (MODE == 0) {
                            if (ACT == 1) v = v > 0.f ? v : 0.01f * v;
                            else if (ACT == 2) v = fmaxf(v, 0.f);
                        }
                        eb[lr * 128 + col] = (_Float16)v;
                    }
            }
        }
        __syncthreads();
        int t4 = tid * 4;
        int lr = t4 >> 4;
        int cbase = (t4 & 15) * 8;
        int m = m0 + p * 128 + lr;
        float sq = 0.f;
        if (m < M) {
#pragma unroll
            for (int q = 0; q < 4; q++) {
                int c0 = cbase + q * 8;
                f16x8 hv = *(f16x8*)(eb + lr * 128 + c0);
                size_t gidx = (size_t)m * Nout + n0 + c0;
                if (MODE == 1) {
                    f16x8 old = *(f16x8*)(Yh + gidx);
                    f16x8 nw;
#pragma unroll
                    for (int e = 0; e < 8; e++) {
                        float s = (float)old[e] + (float)hv[e];
                        nw[e] = (_Float16)s;
                    }
                    *(f16x8*)(Yh + gidx) = nw;
                    hv = nw;
                } else {
                    *(f16x8*)(Yh + gidx) = hv;
                }
                if (SQ) {
#pragma unroll
                    for (int e = 0; e < 8; e++) { float f = (float)hv[e]; sq += f * f; }
                }
            }
        }
        if (SQ) {
            sq += __shfl_xor(sq, 1);
            sq += __shfl_xor(sq, 2);
            if ((lane & 3) == 0 && m < M) atomicAdd(&Psq[m], sq);
        }
    }
}

// ---------------- fused ctx GEMM + LN(P+ctx) -> Ph ----------------
// ctx[m,n] = sum_k A[m,k]*CT[n,k]  (A=Ah [M,Kin] f16, CT=CTh [512,Kin] f16)
// then per row: Ph[m,:] = LN(Ph[m,:] + ctx[m,:]) * g + b
// tile: 128 rows x 512 cols, 8 waves (2 row-groups x 4 col-groups), K=Kin
__global__ __launch_bounds__(512)
void ctxln_k(const _Float16* __restrict__ A, const _Float16* __restrict__ CT,
             const float* __restrict__ g, const float* __restrict__ b,
             _Float16* __restrict__ Ph, int M, int Kin)
{
    __shared__ _Float16 As[2][128 * TBK];     // 8 KB each
    __shared__ _Float16 Bs[2][512 * TBK];     // 32 KB each; also reused as 64x512 epilogue buf
    const int tid = threadIdx.x;
    const int lane = tid & 63;
    const int wid = tid >> 6;                 // 0..7
    const int wr = wid >> 2, wc = wid & 3;    // 2 x 4 wave grid
    const int m0 = blockIdx.y * 128;

    f32x4 acc[4][8] = {};
    const int nt = Kin / TBK;

    const int lrow = lane >> 2;
    const int lk = (lane & 3) * 8;

    auto stage = [&](int t, int buf) {
        const int k0 = t * TBK;
        {   // A: 8 chunks of 16 rows; one chunk per wave
            int r = wid * 16 + lrow;
            gll16(A + (size_t)(m0 + r) * Kin + k0 + lk, &As[buf][wid * 512]);
        }
#pragma unroll
        for (int q = 0; q < 4; q++) {   // B: 32 chunks of 16 rows; 4 per wave
            int c = wid * 4 + q;
            int n = c * 16 + lrow;
            gll16(CT + (size_t)n * Kin + k0 + lk, &Bs[buf][c * 512]);
        }
    };

    stage(0, 0);
    __syncthreads();
    for (int t = 0; t < nt; ++t) {
        const int cur = t & 1;
        if (t + 1 < nt) stage(t + 1, cur ^ 1);
        f16x8 af[4], bf[8];
#pragma unroll
        for (int mi = 0; mi < 4; mi++)
            af[mi] = *(const f16x8*)(&As[cur][(wr * 64 + mi * 16 + (lane & 15)) * TBK + (lane >> 4) * 8]);
#pragma unroll
        for (int nj = 0; nj < 8; nj++)
            bf[nj] = *(const f16x8*)(&Bs[cur][(wc * 128 + nj * 16 + (lane & 15)) * TBK + (lane >> 4) * 8]);
#pragma unroll
        for (int mi = 0; mi < 4; mi++)
#pragma unroll
            for (int nj = 0; nj < 8; nj++)
                acc[mi][nj] = __builtin_amdgcn_mfma_f32_16x16x32_f16(af[mi], bf[nj], acc[mi][nj], 0, 0, 0);
        __syncthreads();
    }

    // ---- epilogue: two 64-row halves; repack ctx to LDS then in-wave LN ----
    _Float16* eb = &Bs[0][0];                 // 64 x 512 f16 = 64 KB
    const int gq = lane >> 4;
#pragma unroll
    for (int p = 0; p < 2; p++) {
        if (p) __syncthreads();
        if (wr == p) {                        // 4 col-waves own this half's rows
#pragma unroll
            for (int nj = 0; nj < 8; nj++) {
                int col = wc * 128 + nj * 16 + (lane & 15);
#pragma unroll
                for (int mi = 0; mi < 4; mi++)
#pragma unroll
                    for (int r = 0; r < 4; r++) {
                        int lr = mi * 16 + gq * 4 + r;   // 0..63
                        eb[lr * 512 + col] = (_Float16)acc[mi][nj][r];
                    }
            }
        }
        __syncthreads();
        // LN: 8 waves x 8 rows; full row (512) in one wave (64 lanes x 8)
#pragma unroll
        for (int rr = 0; rr < 8; rr++) {
            int lr = wid * 8 + rr;            // 0..63
            int m = m0 + p * 64 + lr;
            f16x8 cv = *(f16x8*)(eb + lr * 512 + lane * 8);
            f16x8 pv = *(const f16x8*)(Ph + (size_t)m * 512 + lane * 8);
            float v[8];
            float s = 0.f, ss = 0.f;
#pragma unroll
            for (int q = 0; q < 8; q++) {
                v[q] = (float)pv[q] + (float)cv[q];
                s += v[q]; ss += v[q] * v[q];
            }
#pragma unroll
            for (int o = 32; o; o >>= 1) { s += __shfl_xor(s, o); ss += __shfl_xor(ss, o); }
            float mean = s * (1.f / 512.f);
            float var = ss * (1.f / 512.f) - mean * mean;
            float inv = 1.f / sqrtf(var + 1e-5f);
            int d0 = lane * 8;
            f16x8 o8;
#pragma unroll
            for (int q = 0; q < 8; q++)
                o8[q] = (_Float16)((v[q] - mean) * inv * g[d0 + q] + b[d0 + q]);
            *(f16x8*)(Ph + (size_t)m * 512 + d0) = o8;
        }
    }
}

// ---------------- fused gate + attention-score GEMM ----------------
__global__ __launch_bounds__(512)
void gatgemm(const _Float16* __restrict__ A, const _Float16* __restrict__ B1,
             const _Float16* __restrict__ B2, const float* __restrict__ c1,
             const float* __restrict__ c2, const float* __restrict__ Ws,
             float* __restrict__ scr, int M, int K, int Nout)
{
    __shared__ _Float16 As[2][TBM * TBK];
    __shared__ _Float16 B1s[2][TBN * TBK];
    __shared__ _Float16 B2s[2][TBN * TBK];
    const int tid = threadIdx.x;
    const int lane = tid & 63;
    const int wid = tid >> 6;
    const int wr = wid >> 1, wc = wid & 1;

    int bid = xcd_swz(blockIdx.y * gridDim.x + blockIdx.x, gridDim.x * gridDim.y);
    const int m0 = (bid / gridDim.x) * TBM;
    const int n0 = (bid % gridDim.x) * TBN;

    f32x4 acc1[4][4] = {};
    f32x4 acc2[4][4] = {};
    const int nt = K / TBK;

    const int lrow = lane >> 2;
    const int lk = (lane & 3) * 8;

    auto stage = [&](int t, int buf) {
        const int k0 = t * TBK;
#pragma unroll
        for (int q = 0; q < 2; q++) {
            int c = wid * 2 + q;
            int r = c * 16 + lrow;
            int am = min(m0 + r, M - 1);
            gll16(A + (size_t)am * K + k0 + lk, &As[buf][c * 512]);
        }
        {
            int c = wid;
            int r = c * 16 + lrow;
            int bn = min(n0 + r, Nout - 1);
            gll16(B1 + (size_t)bn * K + k0 + lk, &B1s[buf][c * 512]);
            gll16(B2 + (size_t)bn * K + k0 + lk, &B2s[buf][c * 512]);
        }
    };

    stage(0, 0);
    __syncthreads();
    for (int t = 0; t < nt; ++t) {
        const int cur = t & 1;
        if (t + 1 < nt) stage(t + 1, cur ^ 1);
        f16x8 af[4], bf1[4], bf2[4];
#pragma unroll
        for (int mi = 0; mi < 4; mi++)
            af[mi] = *(const f16x8*)(&As[cur][(wr * 64 + mi * 16 + (lane & 15)) * TBK + (lane >> 4) * 8]);
#pragma unroll
        for (int nj = 0; nj < 4; nj++) {
            int ro = (wc * 64 + nj * 16 + (lane & 15)) * TBK + (lane >> 4) * 8;
            bf1[nj] = *(const f16x8*)(&B1s[cur][ro]);
            bf2[nj] = *(const f16x8*)(&B2s[cur][ro]);
        }
#pragma unroll
        for (int mi = 0; mi < 4; mi++)
#pragma unroll
            for (int nj = 0; nj < 4; nj++) {
                acc1[mi][nj] = __builtin_amdgcn_mfma_f32_16x16x32_f16(af[mi], bf1[nj], acc1[mi][nj], 0, 0, 0);
                acc2[mi][nj] = __builtin_amdgcn_mfma_f32_16x16x32_f16(af[mi], bf2[nj], acc2[mi][nj], 0, 0, 0);
            }
        __syncthreads();
    }

    const int g = lane >> 4;
    float wsv[4];
#pragma unroll
    for (int nj = 0; nj < 4; nj++)
        wsv[nj] = Ws[n0 + wc * 64 + nj * 16 + (lane & 15)];
#pragma unroll
    for (int mi = 0; mi < 4; mi++) {
#pragma unroll
        for (int r = 0; r < 4; r++) {
            float p = 0.f;
#pragma unroll
            for (int nj = 0; nj < 4; nj++) {
                int col = n0 + wc * 64 + nj * 16 + (lane & 15);
                float t1 = ftanh(acc1[mi][nj][r] + c1[col]);
                float g1 = fsigmoid(acc2[mi][nj][r] + c2[col]);
                p += t1 * g1 * wsv[nj];
            }
#pragma unroll
            for (int o = 1; o < 16; o <<= 1) p += __shfl_xor(p, o);
            if ((lane & 15) == 0) {
                int m = m0 + wr * 64 + mi * 16 + g * 4 + r;
                if (m < M) atomicAdd(&scr[m], p);
            }
        }
    }
}

// ---------------- fused sim GEMM + row softmax: 128-row blocks, 4 waves ----------------
#define SBM 128
__global__ __launch_bounds__(256)
void simgemm(const _Float16* __restrict__ A, const _Float16* __restrict__ B,
             const float* __restrict__ Psq, const float* __restrict__ Csq,
             const float* __restrict__ sscale, _Float16* __restrict__ Ah,
             int M, int K, int Kin)
{
    __shared__ _Float16 As[2][SBM * TBK];
    __shared__ _Float16 Bs[2][SBM * TBK];
    __shared__ float redmx[2][SBM];
    __shared__ float redsm[2][SBM];
    const int tid = threadIdx.x;
    const int lane = tid & 63;
    const int wid = tid >> 6;
    const int wr = wid >> 1, wc = wid & 1;
    const int m0 = blockIdx.y * SBM;

    f32x4 acc[4][4] = {};
    const int nt = K / TBK;
    const int lrow = lane >> 2;
    const int lk = (lane & 3) * 8;

    auto stage = [&](int t, int buf) {
        const int k0 = t * TBK;
#pragma unroll
        for (int q = 0; q < 2; q++) {
            int c = wid * 2 + q;
            int r = c * 16 + lrow;
            int am = min(m0 + r, M - 1);
            int bn = min(r, Kin - 1);
            gll16(A + (size_t)am * K + k0 + lk, &As[buf][c * 512]);
            gll16(B + (size_t)bn * K + k0 + lk, &Bs[buf][c * 512]);
        }
    };

    stage(0, 0);
    __syncthreads();
    for (int t = 0; t < nt; ++t) {
        const int cur = t & 1;
        if (t + 1 < nt) stage(t + 1, cur ^ 1);
        f16x8 af[4], bf[4];
#pragma unroll
        for (int mi = 0; mi < 4; mi++)
            af[mi] = *(const f16x8*)(&As[cur][(wr * 64 + mi * 16 + (lane & 15)) * TBK + (lane >> 4) * 8]);
#pragma unroll
        for (int nj = 0; nj < 4; nj++)
            bf[nj] = *(const f16x8*)(&Bs[cur][(wc * 64 + nj * 16 + (lane & 15)) * TBK + (lane >> 4) * 8]);
#pragma unroll
        for (int mi = 0; mi < 4; mi++)
#pragma unroll
            for (int nj = 0; nj < 4; nj++)
                acc[mi][nj] = __builtin_amdgcn_mfma_f32_16x16x32_f16(af[mi], bf[nj], acc[mi][nj], 0, 0, 0);
        __syncthreads();
    }

    const float denom = fmaxf(1e-6f, sscale[0]);
    const int colbase = wc * 64 + (lane & 15);
    const int g = lane >> 4;
    float cc[4];
#pragma unroll
    for (int nj = 0; nj < 4; nj++) {
        int n = colbase + nj * 16;
        cc[nj] = (n < Kin) ? Csq[n] : 0.f;
    }

#pragma unroll
    for (int mi = 0; mi < 4; mi++) {
#pragma unroll
        for (int r = 0; r < 4; r++) {
            int row = wr * 64 + mi * 16 + g * 4 + r;
            float pp = Psq[m0 + row];
            float mx = -INFINITY;
#pragma unroll
            for (int nj = 0; nj < 4; nj++) {
                int n = colbase + nj * 16;
                float v = -INFINITY;
                if (n < Kin)
                    v = -sqrtf(fmaxf(pp + cc[nj] - 2.f * acc[mi][nj][r], 1e-12f)) / denom;
                acc[mi][nj][r] = v;
                mx = fmaxf(mx, v);
            }
#pragma unroll
            for (int o = 1; o < 16; o <<= 1) mx = fmaxf(mx, __shfl_xor(mx, o));
            if ((lane & 15) == 0) redmx[wc][row] = mx;
        }
    }
    __syncthreads();

#pragma unroll
    for (int mi = 0; mi < 4; mi++) {
#pragma unroll
        for (int r = 0; r < 4; r++) {
            int row = wr * 64 + mi * 16 + g * 4 + r;
            float mx = fmaxf(redmx[0][row], redmx[1][row]);
            float s = 0.f;
#pragma unroll
            for (int nj = 0; nj < 4; nj++) {
                int n = colbase + nj * 16;
                float e = (n < Kin) ? __expf(acc[mi][nj][r] - mx) : 0.f;
                acc[mi][nj][r] = e;
                s += e;
            }
#pragma unroll
            for (int o = 1; o < 16; o <<= 1) s += __shfl_xor(s, o);
            if ((lane & 15) == 0) redsm[wc][row] = s;
        }
    }
    __syncthreads();

#pragma unroll
    for (int mi = 0; mi < 4; mi++) {
#pragma unroll
        for (int r = 0; r < 4; r++) {
            int row = wr * 64 + mi * 16 + g * 4 + r;
            float inv = __builtin_amdgcn_rcpf(redsm[0][row] + redsm[1][row]);
            int m = m0 + row;
#pragma unroll
            for (int nj = 0; nj < 4; nj++) {
                int n = colbase + nj * 16;
                if (n < Kin)
                    Ah[(size_t)m * Kin + n] = (_Float16)(acc[mi][nj][r] * inv);
            }
        }
    }
}

// ---------------- converters ----------------
__global__ __launch_bounds__(256)
void cvt_k(const float* __restrict__ x, _Float16* __restrict__ y, int n)
{
    int i = (blockIdx.x * 256 + threadIdx.x) * 4;
    if (i < n) {
        float4 v = *(const float4*)(x + i);
        f16x4 h = { (_Float16)v.x, (_Float16)v.y, (_Float16)v.z, (_Float16)v.w };
        *(f16x4*)(y + i) = h;
    }
}

// ---------------- small kernels (f16 activations) ----------------
__global__ __launch_bounds__(256)
void ln_k(const _Float16* __restrict__ X, const _Float16* __restrict__ R,
          const float* __restrict__ g, const float* __restrict__ b,
          _Float16* __restrict__ Yh, int M)
{
    int wid = threadIdx.x >> 6, lane = threadIdx.x & 63;
    int row = blockIdx.x * 4 + wid;
    if (row >= M) return;
    f16x8 a = *(const f16x8*)(X + (size_t)row * 512 + lane * 8);
    float v[8];
#pragma unroll
    for (int q = 0; q < 8; q++) v[q] = (float)a[q];
    if (R) {
        f16x8 c = *(const f16x8*)(R + (size_t)row * 512 + lane * 8);
#pragma unroll
        for (int q = 0; q < 8; q++) v[q] += (float)c[q];
    }
    float s = 0.f, ss = 0.f;
#pragma unroll
    for (int q = 0; q < 8; q++) { s += v[q]; ss += v[q] * v[q]; }
#pragma unroll
    for (int o = 32; o; o >>= 1) { s += __shfl_xor(s, o); ss += __shfl_xor(ss, o); }
    float mean = s * (1.f / 512.f);
    float var = ss * (1.f / 512.f) - mean * mean;
    float inv = 1.f / sqrtf(var + 1e-5f);
    int d0 = lane * 8;
    f16x8 o8;
#pragma unroll
    for (int q = 0; q < 8; q++)
        o8[q] = (_Float16)((v[q] - mean) * inv * g[d0 + q] + b[d0 + q]);
    *(f16x8*)(Yh + (size_t)row * 512 + d0) = o8;
}

__global__ __launch_bounds__(256)
void red1_k(const float* __restrict__ C, const float* __restrict__ w1,
            const float* __restrict__ b1, float* __restrict__ H1, int Kin)
{
    int d = blockIdx.x * 256 + threadIdx.x;
    int j = blockIdx.y;
    float acc = b1[j];
    for (int k = 0; k < Kin; k++) acc = fmaf(C[(size_t)k * 512 + d], w1[(size_t)j * Kin + k], acc);
    H1[(size_t)j * 512 + d] = fmaxf(acc, 0.f);
}

// red2 + fused f16 conversion/transpose/Csq emission for the NEXT iteration
__global__ __launch_bounds__(256)
void red2_k(const float* __restrict__ H1, const float* __restrict__ w2,
            const float* __restrict__ b2, float* __restrict__ Cn,
            _Float16* __restrict__ Chn, _Float16* __restrict__ CThn,
            float* __restrict__ Csqn, int Kin, int Kout)
{
    int d = blockIdx.x * 256 + threadIdx.x;
    int j2 = blockIdx.y;
    float acc = b2[j2];
    for (int j = 0; j < Kin; j++) acc = fmaf(H1[(size_t)j * 512 + d], w2[(size_t)j2 * Kin + j], acc);
    Cn[(size_t)j2 * 512 + d] = acc;
    _Float16 h = (_Float16)acc;
    Chn[(size_t)j2 * 512 + d] = h;
    CThn[(size_t)d * Kout + j2] = h;
    float f = (float)h;
    float sq = f * f;
#pragma unroll
    for (int o = 32; o; o >>= 1) sq += __shfl_xor(sq, o);
    if ((threadIdx.x & 63) == 0) atomicAdd(&Csqn[j2], sq);
}

__global__ __launch_bounds__(1024)
void pool_k(float* __restrict__ s, float* __restrict__ scal, int M)
{
    __shared__ float sm[16];
    int tid = threadIdx.x, lane = tid & 63, wid = tid >> 6;
    float mx = -INFINITY;
    for (int i = tid * 4; i < M; i += 4096) {
        float4 a = *(const float4*)(s + i);
        mx = fmaxf(fmaxf(fmaxf(mx, a.x), fmaxf(a.y, a.z)), a.w);
    }
#pragma unroll
    for (int o = 32; o; o >>= 1) mx = fmaxf(mx, __shfl_xor(mx, o));
    if (lane == 0) sm[wid] = mx;
    __syncthreads();
    if (wid == 0) {
        float v = (lane < 16) ? sm[lane] : -INFINITY;
#pragma unroll
        for (int o = 8; o; o >>= 1) v = fmaxf(v, __shfl_xor(v, o));
        if (lane == 0) sm[0] = v;
    }
    __syncthreads();
    float gmax = sm[0];
    __syncthreads();
    float sum = 0.f;
    for (int i = tid * 4; i < M; i += 4096) {
        float4 a = *(const float4*)(s + i);
        float4 e;
        e.x = __expf(a.x - gmax); e.y = __expf(a.y - gmax);
        e.z = __expf(a.z - gmax); e.w = __expf(a.w - gmax);
        *(float4*)(s + i) = e;
        sum += e.x + e.y + e.z + e.w;
    }
#pragma unroll
    for (int o = 32; o; o >>= 1) sum += __shfl_xor(sum, o);
    if (lane == 0) sm[wid] = sum;
    __syncthreads();
    if (tid == 0) {
        float t = 0.f;
        for (int w = 0; w < 16; w++) t += sm[w];
        scal[0] = t;
    }
}

__global__ __launch_bounds__(256)
void bagp_k(const _Float16* __restrict__ Z, const float* __restrict__ w,
            float* __restrict__ PB, int M, int cs)
{
    int d = blockIdx.x * 256 + threadIdx.x;
    int chunk = blockIdx.y;
    int i0 = chunk * cs;
    int i1 = min(M, i0 + cs);
    float acc = 0.f;
    for (int i = i0; i < i1; i++) acc = fmaf(w[i], (float)Z[(size_t)i * 512 + d], acc);
    PB[(size_t)chunk * 512 + d] = acc;
}

__global__ __launch_bounds__(256)
void bagf_k(const float* __restrict__ PB, const float* __restrict__ scal,
            float* __restrict__ bag, int nchunk)
{
    int d = blockIdx.x * 256 + threadIdx.x;
    float acc = 0.f;
    for (int c = 0; c < nchunk; c++) acc += PB[(size_t)c * 512 + d];
    bag[d] = acc / scal[0];
}

__global__ __launch_bounds__(256)
void h_k(const float* __restrict__ bag, const float* __restrict__ Wh,
         const float* __restrict__ bh, float* __restrict__ h)
{
    int wid = threadIdx.x >> 6, lane = threadIdx.x & 63;
    int j = blockIdx.x * 4 + wid;
    const float* wr = Wh + (size_t)j * 512;
    float d = 0.f;
#pragma unroll
    for (int t = 0; t < 2; t++) {
        float4 a = *(const float4*)(wr + t * 256 + lane * 4);
        float4 bv = *(const float4*)(bag + t * 256 + lane * 4);
        d += a.x * bv.x + a.y * bv.y + a.z * bv.z + a.w * bv.w;
    }
#pragma unroll
    for (int o = 32; o; o >>= 1) d += __shfl_xor(d, o);
    if (lane == 0) h[j] = fmaxf(d + bh[j], 0.f);
}

__global__ __launch_bounds__(128)
void logit_k(const float* __restrict__ h, const float* __restrict__ Wc,
             const float* __restrict__ bc, float* __restrict__ out)
{
    int wid = threadIdx.x >> 6, lane = threadIdx.x & 63;
    const float* wr = Wc + (size_t)wid * 512;
    float d = 0.f;
#pragma unroll
    for (int t = 0; t < 2; t++) {
        float4 a = *(const float4*)(wr + t * 256 + lane * 4);
        float4 hv = *(const float4*)(h + t * 256 + lane * 4);
        d += a.x * hv.x + a.y * hv.y + a.z * hv.z + a.w * hv.w;
    }
#pragma unroll
    for (int o = 32; o; o >>= 1) d += __shfl_xor(d, o);
    if (lane == 0) out[wid] = d + bc[wid];
}

extern "C" void kernel_launch(void* const* d_in, const int* in_sizes, int n_in,
                              void* d_out, int out_size, void* d_ws, size_t ws_size,
                              hipStream_t stream)
{
    const float* data    = (const float*)d_in[0];
    const float* protos  = (const float*)d_in[1];
    const float* W_pp    = (const float*)d_in[2];
    const float* b_pp    = (const float*)d_in[3];
    const float* W_cp    = (const float*)d_in[4];
    const float* b_cp    = (const float*)d_in[5];
    const float* sscale  = (const float*)d_in[6];
    const float* enh_w1  = (const float*)d_in[7];
    const float* enh_b1  = (const float*)d_in[8];
    const float* enh_w2  = (const float*)d_in[9];
    const float* enh_b2  = (const float*)d_in[10];
    const float* ln_g    = (const float*)d_in[11];
    const float* ln_b    = (const float*)d_in[12];
    const float* red_w1[3] = {(const float*)d_in[13], (const float*)d_in[17], (const float*)d_in[21]};
    const float* red_b1[3] = {(const float*)d_in[14], (const float*)d_in[18], (const float*)d_in[22]};
    const float* red_w2[3] = {(const float*)d_in[15], (const float*)d_in[19], (const float*)d_in[23]};
    const float* red_b2[3] = {(const float*)d_in[16], (const float*)d_in[20], (const float*)d_in[24]};
    const float* W_proc  = (const float*)d_in[25];
    const float* b_proc  = (const float*)d_in[26];
    const float* g_an    = (const float*)d_in[27];
    const float* b_an    = (const float*)d_in[28];
    const float* W_t     = (const float*)d_in[29];
    const float* b_t     = (const float*)d_in[30];
    const float* W_g     = (const float*)d_in[31];
    const float* b_g     = (const float*)d_in[32];
    const float* W_s     = (const float*)d_in[33];
    const float* b_s     = (const float*)d_in[34];  // unused: softmax shift-invariant
    const float* W_h     = (const float*)d_in[35];
    const float* b_h     = (const float*)d_in[36];
    const float* W_c     = (const float*)d_in[37];
    const float* b_c     = (const float*)d_in[38];
    float* out = (float*)d_out;
    (void)b_s;

    constexpr int N = 32768, DIN = 768, D = 512;
    constexpr int NCHUNK = 256;
    char* w = (char*)d_ws;
    auto alloc = [&](size_t bytes) -> char* {
        char* p = w; w += (bytes + 255) & ~(size_t)255; return p;
    };
    _Float16* Ph     = (_Float16*)alloc((size_t)N * D * 2);
    _Float16* TMPh   = (_Float16*)alloc((size_t)N * D * 2);
    _Float16* Zrawh  = (_Float16*)alloc((size_t)(N + 16) * D * 2);
    _Float16* Zh     = (_Float16*)alloc((size_t)(N + 16) * D * 2);
    _Float16* datah  = (_Float16*)alloc((size_t)N * DIN * 2);
    _Float16* Ah     = (_Float16*)alloc((size_t)N * 128 * 2);
    _Float16* Ch     = (_Float16*)alloc(128 * D * 2);
    _Float16* CTh    = (_Float16*)alloc(128 * D * 2);
    _Float16* Wpph   = (_Float16*)alloc((size_t)D * DIN * 2);
    _Float16* w1h    = (_Float16*)alloc((size_t)3 * D * D * 2);
    _Float16* w2h    = (_Float16*)alloc((size_t)3 * D * D * 2);
    _Float16* Wproch = (_Float16*)alloc((size_t)D * D * 2);
    _Float16* Wth    = (_Float16*)alloc((size_t)D * D * 2);
    _Float16* Wgh    = (_Float16*)alloc((size_t)D * D * 2);
    float*    Psq    = (float*)alloc((size_t)N * 4);
    float*    Csq    = (float*)alloc(128 * 4);
    float*    Ca     = (float*)alloc(128 * D * 4);
    float*    Cb     = (float*)alloc(128 * D * 4);
    float*    H1     = (float*)alloc(128 * D * 4);
    float*    scr    = (float*)alloc((size_t)(N + 16) * 4);
    float*    PB     = (float*)alloc((size_t)NCHUNK * D * 4);
    float*    bag    = (float*)alloc(D * 4);
    float*    hb     = (float*)alloc(D * 4);
    float*    scal   = (float*)alloc(8 * 4);

    dim3 blk(256);
    dim3 blk512(512);
    auto cgrid = [](size_t n) { return dim3((unsigned)((n / 4 + 255) / 256)); };
    auto mgrid = [](int M_, int Nout_) { return dim3((Nout_ + TBN - 1) / TBN, (M_ + TBM - 1) / TBM); };

    // --- convert weights + data to f16 ---
    cvt_k<<<cgrid((size_t)N * DIN), blk, 0, stream>>>(data, datah, N * DIN);
    cvt_k<<<cgrid((size_t)D * DIN), blk, 0, stream>>>(W_pp, Wpph, D * DIN);
    cvt_k<<<cgrid((size_t)3 * D * D), blk, 0, stream>>>(enh_w1, w1h, 3 * D * D);
    cvt_k<<<cgrid((size_t)3 * D * D), blk, 0, stream>>>(enh_w2, w2h, 3 * D * D);
    cvt_k<<<cgrid((size_t)D * D), blk, 0, stream>>>(W_proc, Wproch, D * D);
    cvt_k<<<cgrid((size_t)D * D), blk, 0, stream>>>(W_t, Wth, D * D);
    cvt_k<<<cgrid((size_t)D * D), blk, 0, stream>>>(W_g, Wgh, D * D);

    // P = leaky(data @ W_pp^T + b_pp) -> f16, with fused Psq accumulation
    hipMemsetAsync(Psq, 0, (size_t)N * 4, stream);
    mgemm<0, 1, true><<<mgrid(N, D), blk512, 0, stream>>>(datah, Wpph, b_pp, Ph, Psq, N, DIN, D);
    // C0 = leaky(protos @ W_cp^T + b_cp) -> fp32, then f16 set via cvtC2
    dot_k<1, false><<<dim3(128 * 512 / 4), blk, 0, stream>>>(protos, W_cp, b_cp, Ca, 128, DIN);
    cvtC2_k<<<dim3(32), blk, 0, stream>>>(Ca, Ch, CTh, Csq, 128);

    float* C = Ca;
    float* Cn = Cb;
    int Kin = 128;
    for (int i = 0; i < 3; i++) {
        int Kout = Kin >> 1;
        // A = softmax(-dist/denom) fused with S = P@C^T
        simgemm<<<dim3(1, N / SBM), blk, 0, stream>>>(Ph, Ch, Psq, Csq, sscale, Ah, N, D, Kin);
        if (i < 2) hipMemsetAsync(Psq, 0, (size_t)N * 4, stream);
        // P = LN(P + A@C) fused (ctx GEMM + LN + residual)
        ctxln_k<<<dim3(1, N / 128), blk512, 0, stream>>>(Ah, CTh, ln_g + (size_t)i * D, ln_b + (size_t)i * D, Ph, N, Kin);
        // enhancer MLP: P += w2 @ relu(w1 @ P + b1) + b2   (enh2 fuses Psq for next iter)
        mgemm<0, 2, false><<<mgrid(N, D), blk512, 0, stream>>>(Ph, w1h + (size_t)i * D * D, enh_b1 + (size_t)i * D, TMPh, nullptr, N, D, D);
        if (i < 2)
            mgemm<1, 0, true><<<mgrid(N, D), blk512, 0, stream>>>(TMPh, w2h + (size_t)i * D * D, enh_b2 + (size_t)i * D, Ph, Psq, N, D, D);
        else
            mgemm<1, 0, false><<<mgrid(N, D), blk512, 0, stream>>>(TMPh, w2h + (size_t)i * D * D, enh_b2 + (size_t)i * D, Ph, nullptr, N, D, D);
        // ProtoReducer; red2 emits next iteration's f16 C set
        hipMemsetAsync(Csq, 0, 128 * 4, stream);
        red1_k<<<dim3(2, Kin), blk, 0, stream>>>(C, red_w1[i], red_b1[i], H1, Kin);
        red2_k<<<dim3(2, Kout), blk, 0, stream>>>(H1, red_w2[i], red_b2[i], Cn, Ch, CTh, Csq, Kin, Kout);
        float* t = C; C = Cn; Cn = t;
        Kin = Kout;
    }

    // Zraw = relu(proc([P; C]))
    mgemm<0, 2, false><<<mgrid(N, D), blk512, 0, stream>>>(Ph, Wproch, b_proc, Zrawh, nullptr, N, D, D);
    dot_k<2, true><<<dim3(16 * 512 / 4), blk, 0, stream>>>(C, W_proc, b_proc, Zrawh + (size_t)N * D, 16, D);
    // Z = LN(Zraw)
    ln_k<<<dim3((N + 16 + 3) / 4), blk, 0, stream>>>(Zrawh, nullptr, g_an, b_an, Zh, N + 16);

    // scores = (tanh(Z@W_t^T+b_t) * sigmoid(Z@W_g^T+b_g)) @ W_s  (fused)
    hipMemsetAsync(scr, 0, (size_t)(N + 16) * 4, stream);
    gatgemm<<<mgrid(N + 16, D), blk512, 0, stream>>>(Zh, Wth, Wgh, b_t, b_g, W_s, scr, N + 16, D, D);

    // attention pooling
    pool_k<<<dim3(1), dim3(1024), 0, stream>>>(scr, scal, N + 16);
    int cs = (N + 16 + NCHUNK - 1) / NCHUNK;
    bagp_k<<<dim3(2, NCHUNK), blk, 0, stream>>>(Zh, scr, PB, N + 16, cs);
    bagf_k<<<dim3(2), blk, 0, stream>>>(PB, scal, bag, NCHUNK);

    // classifier head
    h_k<<<dim3(128), blk, 0, stream>>>(bag, W_h, b_h, hb);
    logit_k<<<dim3(1), dim3(128), 0, stream>>>(hb, W_c, b_c, out);
}

// Round 15
// 794.814 us; speedup vs baseline: 1.4876x; 1.0239x over previous
//
#include <hip/hip_runtime.h>
#include <math.h>

typedef _Float16 f16x8 __attribute__((ext_vector_type(8)));
typedef _Float16 f16x4 __attribute__((ext_vector_type(4)));
typedef float f32x4 __attribute__((ext_vector_type(4)));

#define TBM 256
#define TBN 128
#define TBK 32

#define AS1 __attribute__((address_space(1)))
#define AS3 __attribute__((address_space(3)))

__device__ __forceinline__ void gll16(const _Float16* g, _Float16* l)
{
    __builtin_amdgcn_global_load_lds((const AS1 unsigned int*)g,
                                     (AS3 unsigned int*)l, 16, 0, 0);
}

// bijective XCD chunking (m204)
__device__ __forceinline__ int xcd_swz(int d, int nwg)
{
    int q = nwg >> 3, r = nwg & 7;
    int x = d & 7, idx = d >> 3;
    int base = x < r ? x * (q + 1) : r * (q + 1) + (x - r) * q;
    return base + idx;
}

// ---- fast transcendentals ----
__device__ __forceinline__ float fsigmoid(float x)
{
    return __builtin_amdgcn_rcpf(1.f + __expf(-x));
}
__device__ __forceinline__ float ftanh(float x)
{
    float ax = fabsf(x);
    float e = __expf(-2.f * ax);
    float t = (1.f - e) * __builtin_amdgcn_rcpf(1.f + e);
    return copysignf(t, x);
}

// ---------------- wave-per-output dot kernel (small-M fp32 GEMMs) ----------------
template<int ACT, bool F16OUT>
__global__ __launch_bounds__(256)
void dot_k(const float* __restrict__ X, const float* __restrict__ W,
           const float* __restrict__ bias, void* __restrict__ Yv,
           int M, int K)
{
    int gw = (blockIdx.x * 256 + threadIdx.x) >> 6;
    int lane = threadIdx.x & 63;
    if (gw >= M * 512) return;
    int r = gw >> 9, n = gw & 511;
    const float* xr = X + (size_t)r * K;
    const float* wr = W + (size_t)n * K;
    float d = 0.f;
    for (int t = 0; t < K; t += 256) {
        float4 a = *(const float4*)(xr + t + lane * 4);
        float4 b = *(const float4*)(wr + t + lane * 4);
        d += a.x * b.x + a.y * b.y + a.z * b.z + a.w * b.w;
    }
#pragma unroll
    for (int o = 32; o; o >>= 1) d += __shfl_xor(d, o);
    if (lane == 0) {
        float v = d + bias[n];
        if (ACT == 1) v = v > 0.f ? v : 0.01f * v;
        else if (ACT == 2) v = fmaxf(v, 0.f);
        if (F16OUT) ((_Float16*)Yv)[(size_t)r * 512 + n] = (_Float16)v;
        else        ((float*)Yv)[(size_t)r * 512 + n] = v;
    }
}

// C [Kin,512] fp32 -> Ch, CTh f16 + Csq; one wave per row (no atomics)
__global__ __launch_bounds__(256)
void cvtC2_k(const float* __restrict__ C, _Float16* __restrict__ Ch,
             _Float16* __restrict__ CTh, float* __restrict__ Csq, int Kin)
{
    int w = threadIdx.x >> 6, lane = threadIdx.x & 63;
    int row = blockIdx.x * 4 + w;
    if (row >= Kin) return;
    float4 a = *(const float4*)(C + (size_t)row * 512 + lane * 8);
    float4 b = *(const float4*)(C + (size_t)row * 512 + lane * 8 + 4);
    f16x8 h;
    h[0] = (_Float16)a.x; h[1] = (_Float16)a.y; h[2] = (_Float16)a.z; h[3] = (_Float16)a.w;
    h[4] = (_Float16)b.x; h[5] = (_Float16)b.y; h[6] = (_Float16)b.z; h[7] = (_Float16)b.w;
    *(f16x8*)(Ch + (size_t)row * 512 + lane * 8) = h;
    float s = 0.f;
#pragma unroll
    for (int q = 0; q < 8; q++) {
        float f = (float)h[q];
        s += f * f;
        CTh[(size_t)(lane * 8 + q) * Kin + row] = h[q];
    }
#pragma unroll
    for (int o = 32; o; o >>= 1) s += __shfl_xor(s, o);
    if (lane == 0) Csq[row] = s;
}

// ---------------- f16 MFMA GEMM: 256x128 tile, 8 waves, LDS dbuf, repacked epilogue ----------------
// MODE 0: out = act(v) -> Yh f16; MODE 1: out = Yh + v (coalesced RMW)
// ACT: 0 none, 1 leaky, 2 relu ; SQ: atomicAdd row sum-of-squares into Psq
template<int MODE, int ACT, bool SQ>
__global__ __launch_bounds__(512)
void mgemm(const _Float16* __restrict__ A, const _Float16* __restrict__ B,
           const float* __restrict__ bias, _Float16* __restrict__ Yh,
           float* __restrict__ Psq, int M, int K, int Nout)
{
    __shared__ _Float16 As[2][TBM * TBK];
    __shared__ _Float16 Bs[2][TBN * TBK];
    const int tid = threadIdx.x;
    const int lane = tid & 63;
    const int wid = tid >> 6;
    const int wr = wid >> 1, wc = wid & 1;

    int bid = xcd_swz(blockIdx.y * gridDim.x + blockIdx.x, gridDim.x * gridDim.y);
    const int m0 = (bid / gridDim.x) * TBM;
    const int n0 = (bid % gridDim.x) * TBN;

    f32x4 acc[4][4] = {};
    const int nt = K / TBK;

    const int lrow = lane >> 2;
    const int lk = (lane & 3) * 8;

    auto stage = [&](int t, int buf) {
        const int k0 = t * TBK;
#pragma unroll
        for (int q = 0; q < 2; q++) {
            int c = wid * 2 + q;
            int r = c * 16 + lrow;
            int am = min(m0 + r, M - 1);
            gll16(A + (size_t)am * K + k0 + lk, &As[buf][c * 512]);
        }
        {
            int c = wid;
            int r = c * 16 + lrow;
            int bn = min(n0 + r, Nout - 1);
            gll16(B + (size_t)bn * K + k0 + lk, &Bs[buf][c * 512]);
        }
    };

    stage(0, 0);
    __syncthreads();
    for (int t = 0; t < nt; ++t) {
        const int cur = t & 1;
        if (t + 1 < nt) stage(t + 1, cur ^ 1);
        f16x8 af[4], bf[4];
#pragma unroll
        for (int mi = 0; mi < 4; mi++)
            af[mi] = *(const f16x8*)(&As[cur][(wr * 64 + mi * 16 + (lane & 15)) * TBK + (lane >> 4) * 8]);
#pragma unroll
        for (int nj = 0; nj < 4; nj++)
            bf[nj] = *(const f16x8*)(&Bs[cur][(wc * 64 + nj * 16 + (lane & 15)) * TBK + (lane >> 4) * 8]);
#pragma unroll
        for (int mi = 0; mi < 4; mi++)
#pragma unroll
            for (int nj = 0; nj < 4; nj++)
                acc[mi][nj] = __builtin_amdgcn_mfma_f32_16x16x32_f16(af[mi], bf[nj], acc[mi][nj], 0, 0, 0);
        __syncthreads();
    }

    _Float16* eb = &As[0][0];
    const int g = lane >> 4;
#pragma unroll
    for (int p = 0; p < 2; p++) {
        if (p) __syncthreads();
        if ((wr >> 1) == p) {
#pragma unroll
            for (int nj = 0; nj < 4; nj++) {
                int col = wc * 64 + nj * 16 + (lane & 15);
                float bv = bias ? bias[n0 + col] : 0.f;
#pragma unroll
                for (int mi = 0; mi < 4; mi++)
#pragma unroll
                    for (int r = 0; r < 4; r++) {
                        int lr = (wr & 1) * 64 + mi * 16 + g * 4 + r;
                        float v = acc[mi][nj][r] + bv;
                        if (MODE == 0) {
                            if (ACT == 1) v = v > 0.f ? v : 0.01f * v;
                            else if (ACT == 2) v = fmaxf(v, 0.f);
                        }
                        eb[lr * 128 + col] = (_Float16)v;
                    }
            }
        }
        __syncthreads();
        int t4 = tid * 4;
        int lr = t4 >> 4;
        int cbase = (t4 & 15) * 8;
        int m = m0 + p * 128 + lr;
        float sq = 0.f;
        if (m < M) {
#pragma unroll
            for (int q = 0; q < 4; q++) {
                int c0 = cbase + q * 8;
                f16x8 hv = *(f16x8*)(eb + lr * 128 + c0);
                size_t gidx = (size_t)m * Nout + n0 + c0;
                if (MODE == 1) {
                    f16x8 old = *(f16x8*)(Yh + gidx);
                    f16x8 nw;
#pragma unroll
                    for (int e = 0; e < 8; e++) {
                        float s = (float)old[e] + (float)hv[e];
                        nw[e] = (_Float16)s;
                    }
                    *(f16x8*)(Yh + gidx) = nw;
                    hv = nw;
                } else {
                    *(f16x8*)(Yh + gidx) = hv;
                }
                if (SQ) {
#pragma unroll
                    for (int e = 0; e < 8; e++) { float f = (float)hv[e]; sq += f * f; }
                }
            }
        }
        if (SQ) {
            sq += __shfl_xor(sq, 1);
            sq += __shfl_xor(sq, 2);
            if ((lane & 3) == 0 && m < M) atomicAdd(&Psq[m], sq);
        }
    }
}

// ---------------- fused ctx GEMM + LN(P+ctx) -> Ph ----------------
// tile: 128 rows x 512 cols, 8 waves (2 row-groups x 4 col-groups), K=Kin
__global__ __launch_bounds__(512)
void ctxln_k(const _Float16* __restrict__ A, const _Float16* __restrict__ CT,
             const float* __restrict__ g, const float* __restrict__ b,
             _Float16* __restrict__ Ph, int M, int Kin)
{
    __shared__ _Float16 As[2][128 * TBK];
    __shared__ _Float16 Bs[2][512 * TBK];
    const int tid = threadIdx.x;
    const int lane = tid & 63;
    const int wid = tid >> 6;
    const int wr = wid >> 2, wc = wid & 3;
    const int m0 = blockIdx.y * 128;

    f32x4 acc[4][8] = {};
    const int nt = Kin / TBK;

    const int lrow = lane >> 2;
    const int lk = (lane & 3) * 8;

    auto stage = [&](int t, int buf) {
        const int k0 = t * TBK;
        {
            int r = wid * 16 + lrow;
            gll16(A + (size_t)(m0 + r) * Kin + k0 + lk, &As[buf][wid * 512]);
        }
#pragma unroll
        for (int q = 0; q < 4; q++) {
            int c = wid * 4 + q;
            int n = c * 16 + lrow;
            gll16(CT + (size_t)n * Kin + k0 + lk, &Bs[buf][c * 512]);
        }
    };

    stage(0, 0);
    __syncthreads();
    for (int t = 0; t < nt; ++t) {
        const int cur = t & 1;
        if (t + 1 < nt) stage(t + 1, cur ^ 1);
        f16x8 af[4], bf[8];
#pragma unroll
        for (int mi = 0; mi < 4; mi++)
            af[mi] = *(const f16x8*)(&As[cur][(wr * 64 + mi * 16 + (lane & 15)) * TBK + (lane >> 4) * 8]);
#pragma unroll
        for (int nj = 0; nj < 8; nj++)
            bf[nj] = *(const f16x8*)(&Bs[cur][(wc * 128 + nj * 16 + (lane & 15)) * TBK + (lane >> 4) * 8]);
#pragma unroll
        for (int mi = 0; mi < 4; mi++)
#pragma unroll
            for (int nj = 0; nj < 8; nj++)
                acc[mi][nj] = __builtin_amdgcn_mfma_f32_16x16x32_f16(af[mi], bf[nj], acc[mi][nj], 0, 0, 0);
        __syncthreads();
    }

    _Float16* eb = &Bs[0][0];
    const int gq = lane >> 4;
#pragma unroll
    for (int p = 0; p < 2; p++) {
        if (p) __syncthreads();
        if (wr == p) {
#pragma unroll
            for (int nj = 0; nj < 8; nj++) {
                int col = wc * 128 + nj * 16 + (lane & 15);
#pragma unroll
                for (int mi = 0; mi < 4; mi++)
#pragma unroll
                    for (int r = 0; r < 4; r++) {
                        int lr = mi * 16 + gq * 4 + r;
                        eb[lr * 512 + col] = (_Float16)acc[mi][nj][r];
                    }
            }
        }
        __syncthreads();
#pragma unroll
        for (int rr = 0; rr < 8; rr++) {
            int lr = wid * 8 + rr;
            int m = m0 + p * 64 + lr;
            f16x8 cv = *(f16x8*)(eb + lr * 512 + lane * 8);
            f16x8 pv = *(const f16x8*)(Ph + (size_t)m * 512 + lane * 8);
            float v[8];
            float s = 0.f, ss = 0.f;
#pragma unroll
            for (int q = 0; q < 8; q++) {
                v[q] = (float)pv[q] + (float)cv[q];
                s += v[q]; ss += v[q] * v[q];
            }
#pragma unroll
            for (int o = 32; o; o >>= 1) { s += __shfl_xor(s, o); ss += __shfl_xor(ss, o); }
            float mean = s * (1.f / 512.f);
            float var = ss * (1.f / 512.f) - mean * mean;
            float inv = 1.f / sqrtf(var + 1e-5f);
            int d0 = lane * 8;
            f16x8 o8;
#pragma unroll
            for (int q = 0; q < 8; q++)
                o8[q] = (_Float16)((v[q] - mean) * inv * g[d0 + q] + b[d0 + q]);
            *(f16x8*)(Ph + (size_t)m * 512 + d0) = o8;
        }
    }
}

// ---------------- fused proc GEMM + relu + LN -> Zh ----------------
// Zh[m,:] = LN(relu(A[m,:]@W^T + bias)) * g + b ; tile 128 rows x 512 cols, K=512
__global__ __launch_bounds__(512)
void procln_k(const _Float16* __restrict__ A, const _Float16* __restrict__ W,
              const float* __restrict__ bias, const float* __restrict__ g,
              const float* __restrict__ b, _Float16* __restrict__ Zh, int M)
{
    __shared__ _Float16 As[2][128 * TBK];
    __shared__ _Float16 Bs[2][512 * TBK];
    const int tid = threadIdx.x;
    const int lane = tid & 63;
    const int wid = tid >> 6;
    const int wr = wid >> 2, wc = wid & 3;
    const int m0 = blockIdx.y * 128;
    const int K = 512;

    f32x4 acc[4][8] = {};
    const int nt = K / TBK;

    const int lrow = lane >> 2;
    const int lk = (lane & 3) * 8;

    auto stage = [&](int t, int buf) {
        const int k0 = t * TBK;
        {
            int r = wid * 16 + lrow;
            gll16(A + (size_t)(m0 + r) * K + k0 + lk, &As[buf][wid * 512]);
        }
#pragma unroll
        for (int q = 0; q < 4; q++) {
            int c = wid * 4 + q;
            int n = c * 16 + lrow;
            gll16(W + (size_t)n * K + k0 + lk, &Bs[buf][c * 512]);
        }
    };

    stage(0, 0);
    __syncthreads();
    for (int t = 0; t < nt; ++t) {
        const int cur = t & 1;
        if (t + 1 < nt) stage(t + 1, cur ^ 1);
        f16x8 af[4], bf[8];
#pragma unroll
        for (int mi = 0; mi < 4; mi++)
            af[mi] = *(const f16x8*)(&As[cur][(wr * 64 + mi * 16 + (lane & 15)) * TBK + (lane >> 4) * 8]);
#pragma unroll
        for (int nj = 0; nj < 8; nj++)
            bf[nj] = *(const f16x8*)(&Bs[cur][(wc * 128 + nj * 16 + (lane & 15)) * TBK + (lane >> 4) * 8]);
#pragma unroll
        for (int mi = 0; mi < 4; mi++)
#pragma unroll
            for (int nj = 0; nj < 8; nj++)
                acc[mi][nj] = __builtin_amdgcn_mfma_f32_16x16x32_f16(af[mi], bf[nj], acc[mi][nj], 0, 0, 0);
        __syncthreads();
    }

    _Float16* eb = &Bs[0][0];
    const int gq = lane >> 4;
#pragma unroll
    for (int p = 0; p < 2; p++) {
        if (p) __syncthreads();
        if (wr == p) {
#pragma unroll
            for (int nj = 0; nj < 8; nj++) {
                int col = wc * 128 + nj * 16 + (lane & 15);
                float bv = bias[col];
#pragma unroll
                for (int mi = 0; mi < 4; mi++)
#pragma unroll
                    for (int r = 0; r < 4; r++) {
                        int lr = mi * 16 + gq * 4 + r;
                        eb[lr * 512 + col] = (_Float16)fmaxf(acc[mi][nj][r] + bv, 0.f);
                    }
            }
        }
        __syncthreads();
#pragma unroll
        for (int rr = 0; rr < 8; rr++) {
            int lr = wid * 8 + rr;
            int m = m0 + p * 64 + lr;
            f16x8 cv = *(f16x8*)(eb + lr * 512 + lane * 8);
            float v[8];
            float s = 0.f, ss = 0.f;
#pragma unroll
            for (int q = 0; q < 8; q++) {
                v[q] = (float)cv[q];
                s += v[q]; ss += v[q] * v[q];
            }
#pragma unroll
            for (int o = 32; o; o >>= 1) { s += __shfl_xor(s, o); ss += __shfl_xor(ss, o); }
            float mean = s * (1.f / 512.f);
            float var = ss * (1.f / 512.f) - mean * mean;
            float inv = 1.f / sqrtf(var + 1e-5f);
            int d0 = lane * 8;
            f16x8 o8;
#pragma unroll
            for (int q = 0; q < 8; q++)
                o8[q] = (_Float16)((v[q] - mean) * inv * g[d0 + q] + b[d0 + q]);
            *(f16x8*)(Zh + (size_t)m * 512 + d0) = o8;
        }
    }
}

// ---------------- fused gate + attention-score GEMM ----------------
__global__ __launch_bounds__(512)
void gatgemm(const _Float16* __restrict__ A, const _Float16* __restrict__ B1,
             const _Float16* __restrict__ B2, const float* __restrict__ c1,
             const float* __restrict__ c2, const float* __restrict__ Ws,
             float* __restrict__ scr, int M, int K, int Nout)
{
    __shared__ _Float16 As[2][TBM * TBK];
    __shared__ _Float16 B1s[2][TBN * TBK];
    __shared__ _Float16 B2s[2][TBN * TBK];
    const int tid = threadIdx.x;
    const int lane = tid & 63;
    const int wid = tid >> 6;
    const int wr = wid >> 1, wc = wid & 1;

    int bid = xcd_swz(blockIdx.y * gridDim.x + blockIdx.x, gridDim.x * gridDim.y);
    const int m0 = (bid / gridDim.x) * TBM;
    const int n0 = (bid % gridDim.x) * TBN;

    f32x4 acc1[4][4] = {};
    f32x4 acc2[4][4] = {};
    const int nt = K / TBK;

    const int lrow = lane >> 2;
    const int lk = (lane & 3) * 8;

    auto stage = [&](int t, int buf) {
        const int k0 = t * TBK;
#pragma unroll
        for (int q = 0; q < 2; q++) {
            int c = wid * 2 + q;
            int r = c * 16 + lrow;
            int am = min(m0 + r, M - 1);
            gll16(A + (size_t)am * K + k0 + lk, &As[buf][c * 512]);
        }
        {
            int c = wid;
            int r = c * 16 + lrow;
            int bn = min(n0 + r, Nout - 1);
            gll16(B1 + (size_t)bn * K + k0 + lk, &B1s[buf][c * 512]);
            gll16(B2 + (size_t)bn * K + k0 + lk, &B2s[buf][c * 512]);
        }
    };

    stage(0, 0);
    __syncthreads();
    for (int t = 0; t < nt; ++t) {
        const int cur = t & 1;
        if (t + 1 < nt) stage(t + 1, cur ^ 1);
        f16x8 af[4], bf1[4], bf2[4];
#pragma unroll
        for (int mi = 0; mi < 4; mi++)
            af[mi] = *(const f16x8*)(&As[cur][(wr * 64 + mi * 16 + (lane & 15)) * TBK + (lane >> 4) * 8]);
#pragma unroll
        for (int nj = 0; nj < 4; nj++) {
            int ro = (wc * 64 + nj * 16 + (lane & 15)) * TBK + (lane >> 4) * 8;
            bf1[nj] = *(const f16x8*)(&B1s[cur][ro]);
            bf2[nj] = *(const f16x8*)(&B2s[cur][ro]);
        }
#pragma unroll
        for (int mi = 0; mi < 4; mi++)
#pragma unroll
            for (int nj = 0; nj < 4; nj++) {
                acc1[mi][nj] = __builtin_amdgcn_mfma_f32_16x16x32_f16(af[mi], bf1[nj], acc1[mi][nj], 0, 0, 0);
                acc2[mi][nj] = __builtin_amdgcn_mfma_f32_16x16x32_f16(af[mi], bf2[nj], acc2[mi][nj], 0, 0, 0);
            }
        __syncthreads();
    }

    const int g = lane >> 4;
    float wsv[4];
#pragma unroll
    for (int nj = 0; nj < 4; nj++)
        wsv[nj] = Ws[n0 + wc * 64 + nj * 16 + (lane & 15)];
#pragma unroll
    for (int mi = 0; mi < 4; mi++) {
#pragma unroll
        for (int r = 0; r < 4; r++) {
            float p = 0.f;
#pragma unroll
            for (int nj = 0; nj < 4; nj++) {
                int col = n0 + wc * 64 + nj * 16 + (lane & 15);
                float t1 = ftanh(acc1[mi][nj][r] + c1[col]);
                float g1 = fsigmoid(acc2[mi][nj][r] + c2[col]);
                p += t1 * g1 * wsv[nj];
            }
#pragma unroll
            for (int o = 1; o < 16; o <<= 1) p += __shfl_xor(p, o);
            if ((lane & 15) == 0) {
                int m = m0 + wr * 64 + mi * 16 + g * 4 + r;
                if (m < M) atomicAdd(&scr[m], p);
            }
        }
    }
}

// ---------------- fused sim GEMM + row softmax: 128-row blocks, 4 waves ----------------
#define SBM 128
__global__ __launch_bounds__(256)
void simgemm(const _Float16* __restrict__ A, const _Float16* __restrict__ B,
             const float* __restrict__ Psq, const float* __restrict__ Csq,
             const float* __restrict__ sscale, _Float16* __restrict__ Ah,
             int M, int K, int Kin)
{
    __shared__ _Float16 As[2][SBM * TBK];
    __shared__ _Float16 Bs[2][SBM * TBK];
    __shared__ float redmx[2][SBM];
    __shared__ float redsm[2][SBM];
    const int tid = threadIdx.x;
    const int lane = tid & 63;
    const int wid = tid >> 6;
    const int wr = wid >> 1, wc = wid & 1;
    const int m0 = blockIdx.y * SBM;

    f32x4 acc[4][4] = {};
    const int nt = K / TBK;
    const int lrow = lane >> 2;
    const int lk = (lane & 3) * 8;

    auto stage = [&](int t, int buf) {
        const int k0 = t * TBK;
#pragma unroll
        for (int q = 0; q < 2; q++) {
            int c = wid * 2 + q;
            int r = c * 16 + lrow;
            int am = min(m0 + r, M - 1);
            gll16(A + (size_t)am * K + k0 + lk, &As[buf][c * 512]);
            if (c * 16 < Kin) {             // skip fully-OOB B chunks
                int bn = min(r, Kin - 1);
                gll16(B + (size_t)bn * K + k0 + lk, &Bs[buf][c * 512]);
            }
        }
    };

    stage(0, 0);
    __syncthreads();
    for (int t = 0; t < nt; ++t) {
        const int cur = t & 1;
        if (t + 1 < nt) stage(t + 1, cur ^ 1);
        f16x8 af[4], bf[4];
#pragma unroll
        for (int mi = 0; mi < 4; mi++)
            af[mi] = *(const f16x8*)(&As[cur][(wr * 64 + mi * 16 + (lane & 15)) * TBK + (lane >> 4) * 8]);
#pragma unroll
        for (int nj = 0; nj < 4; nj++)
            bf[nj] = *(const f16x8*)(&Bs[cur][(wc * 64 + nj * 16 + (lane & 15)) * TBK + (lane >> 4) * 8]);
#pragma unroll
        for (int mi = 0; mi < 4; mi++)
#pragma unroll
            for (int nj = 0; nj < 4; nj++)
                acc[mi][nj] = __builtin_amdgcn_mfma_f32_16x16x32_f16(af[mi], bf[nj], acc[mi][nj], 0, 0, 0);
        __syncthreads();
    }

    const float denom = fmaxf(1e-6f, sscale[0]);
    const int colbase = wc * 64 + (lane & 15);
    const int g = lane >> 4;
    float cc[4];
#pragma unroll
    for (int nj = 0; nj < 4; nj++) {
        int n = colbase + nj * 16;
        cc[nj] = (n < Kin) ? Csq[n] : 0.f;
    }

#pragma unroll
    for (int mi = 0; mi < 4; mi++) {
#pragma unroll
        for (int r = 0; r < 4; r++) {
            int row = wr * 64 + mi * 16 + g * 4 + r;
            float pp = Psq[m0 + row];
            float mx = -INFINITY;
#pragma unroll
            for (int nj = 0; nj < 4; nj++) {
                int n = colbase + nj * 16;
                float v = -INFINITY;
                if (n < Kin)
                    v = -sqrtf(fmaxf(pp + cc[nj] - 2.f * acc[mi][nj][r], 1e-12f)) / denom;
                acc[mi][nj][r] = v;
                mx = fmaxf(mx, v);
            }
#pragma unroll
            for (int o = 1; o < 16; o <<= 1) mx = fmaxf(mx, __shfl_xor(mx, o));
            if ((lane & 15) == 0) redmx[wc][row] = mx;
        }
    }
    __syncthreads();

#pragma unroll
    for (int mi = 0; mi < 4; mi++) {
#pragma unroll
        for (int r = 0; r < 4; r++) {
            int row = wr * 64 + mi * 16 + g * 4 + r;
            float mx = fmaxf(redmx[0][row], redmx[1][row]);
            float s = 0.f;
#pragma unroll
            for (int nj = 0; nj < 4; nj++) {
                int n = colbase + nj * 16;
                float e = (n < Kin) ? __expf(acc[mi][nj][r] - mx) : 0.f;
                acc[mi][nj][r] = e;
                s += e;
            }
#pragma unroll
            for (int o = 1; o < 16; o <<= 1) s += __shfl_xor(s, o);
            if ((lane & 15) == 0) redsm[wc][row] = s;
        }
    }
    __syncthreads();

#pragma unroll
    for (int mi = 0; mi < 4; mi++) {
#pragma unroll
        for (int r = 0; r < 4; r++) {
            int row = wr * 64 + mi * 16 + g * 4 + r;
            float inv = __builtin_amdgcn_rcpf(redsm[0][row] + redsm[1][row]);
            int m = m0 + row;
#pragma unroll
            for (int nj = 0; nj < 4; nj++) {
                int n = colbase + nj * 16;
                if (n < Kin)
                    Ah[(size_t)m * Kin + n] = (_Float16)(acc[mi][nj][r] * inv);
            }
        }
    }
}

// ---------------- converters ----------------
__global__ __launch_bounds__(256)
void cvt_k(const float* __restrict__ x, _Float16* __restrict__ y, int n)
{
    int i = (blockIdx.x * 256 + threadIdx.x) * 4;
    if (i < n) {
        float4 v = *(const float4*)(x + i);
        f16x4 h = { (_Float16)v.x, (_Float16)v.y, (_Float16)v.z, (_Float16)v.w };
        *(f16x4*)(y + i) = h;
    }
}

// ---------------- small kernels (f16 activations) ----------------
__global__ __launch_bounds__(256)
void ln_k(const _Float16* __restrict__ X, const _Float16* __restrict__ R,
          const float* __restrict__ g, const float* __restrict__ b,
          _Float16* __restrict__ Yh, int M)
{
    int wid = threadIdx.x >> 6, lane = threadIdx.x & 63;
    int row = blockIdx.x * 4 + wid;
    if (row >= M) return;
    f16x8 a = *(const f16x8*)(X + (size_t)row * 512 + lane * 8);
    float v[8];
#pragma unroll
    for (int q = 0; q < 8; q++) v[q] = (float)a[q];
    if (R) {
        f16x8 c = *(const f16x8*)(R + (size_t)row * 512 + lane * 8);
#pragma unroll
        for (int q = 0; q < 8; q++) v[q] += (float)c[q];
    }
    float s = 0.f, ss = 0.f;
#pragma unroll
    for (int q = 0; q < 8; q++) { s += v[q]; ss += v[q] * v[q]; }
#pragma unroll
    for (int o = 32; o; o >>= 1) { s += __shfl_xor(s, o); ss += __shfl_xor(ss, o); }
    float mean = s * (1.f / 512.f);
    float var = ss * (1.f / 512.f) - mean * mean;
    float inv = 1.f / sqrtf(var + 1e-5f);
    int d0 = lane * 8;
    f16x8 o8;
#pragma unroll
    for (int q = 0; q < 8; q++)
        o8[q] = (_Float16)((v[q] - mean) * inv * g[d0 + q] + b[d0 + q]);
    *(f16x8*)(Yh + (size_t)row * 512 + d0) = o8;
}

__global__ __launch_bounds__(256)
void red1_k(const float* __restrict__ C, const float* __restrict__ w1,
            const float* __restrict__ b1, float* __restrict__ H1, int Kin)
{
    int d = blockIdx.x * 256 + threadIdx.x;
    int j = blockIdx.y;
    float acc = b1[j];
    for (int k = 0; k < Kin; k++) acc = fmaf(C[(size_t)k * 512 + d], w1[(size_t)j * Kin + k], acc);
    H1[(size_t)j * 512 + d] = fmaxf(acc, 0.f);
}

// red2 + fused f16 conversion/transpose/Csq emission for the NEXT iteration
__global__ __launch_bounds__(256)
void red2_k(const float* __restrict__ H1, const float* __restrict__ w2,
            const float* __restrict__ b2, float* __restrict__ Cn,
            _Float16* __restrict__ Chn, _Float16* __restrict__ CThn,
            float* __restrict__ Csqn, int Kin, int Kout)
{
    int d = blockIdx.x * 256 + threadIdx.x;
    int j2 = blockIdx.y;
    float acc = b2[j2];
    for (int j = 0; j < Kin; j++) acc = fmaf(H1[(size_t)j * 512 + d], w2[(size_t)j2 * Kin + j], acc);
    Cn[(size_t)j2 * 512 + d] = acc;
    _Float16 h = (_Float16)acc;
    Chn[(size_t)j2 * 512 + d] = h;
    CThn[(size_t)d * Kout + j2] = h;
    float f = (float)h;
    float sq = f * f;
#pragma unroll
    for (int o = 32; o; o >>= 1) sq += __shfl_xor(sq, o);
    if ((threadIdx.x & 63) == 0) atomicAdd(&Csqn[j2], sq);
}

__global__ __launch_bounds__(1024)
void pool_k(float* __restrict__ s, float* __restrict__ scal, int M)
{
    __shared__ float sm[16];
    int tid = threadIdx.x, lane = tid & 63, wid = tid >> 6;
    float mx = -INFINITY;
    for (int i = tid * 4; i < M; i += 4096) {
        float4 a = *(const float4*)(s + i);
        mx = fmaxf(fmaxf(fmaxf(mx, a.x), fmaxf(a.y, a.z)), a.w);
    }
#pragma unroll
    for (int o = 32; o; o >>= 1) mx = fmaxf(mx, __shfl_xor(mx, o));
    if (lane == 0) sm[wid] = mx;
    __syncthreads();
    if (wid == 0) {
        float v = (lane < 16) ? sm[lane] : -INFINITY;
#pragma unroll
        for (int o = 8; o; o >>= 1) v = fmaxf(v, __shfl_xor(v, o));
        if (lane == 0) sm[0] = v;
    }
    __syncthreads();
    float gmax = sm[0];
    __syncthreads();
    float sum = 0.f;
    for (int i = tid * 4; i < M; i += 4096) {
        float4 a = *(const float4*)(s + i);
        float4 e;
        e.x = __expf(a.x - gmax); e.y = __expf(a.y - gmax);
        e.z = __expf(a.z - gmax); e.w = __expf(a.w - gmax);
        *(float4*)(s + i) = e;
        sum += e.x + e.y + e.z + e.w;
    }
#pragma unroll
    for (int o = 32; o; o >>= 1) sum += __shfl_xor(sum, o);
    if (lane == 0) sm[wid] = sum;
    __syncthreads();
    if (tid == 0) {
        float t = 0.f;
        for (int w = 0; w < 16; w++) t += sm[w];
        scal[0] = t;
    }
}

__global__ __launch_bounds__(256)
void bagp_k(const _Float16* __restrict__ Z, const float* __restrict__ w,
            float* __restrict__ PB, int M, int cs)
{
    int d = blockIdx.x * 256 + threadIdx.x;
    int chunk = blockIdx.y;
    int i0 = chunk * cs;
    int i1 = min(M, i0 + cs);
    float acc = 0.f;
    for (int i = i0; i < i1; i++) acc = fmaf(w[i], (float)Z[(size_t)i * 512 + d], acc);
    PB[(size_t)chunk * 512 + d] = acc;
}

__global__ __launch_bounds__(256)
void bagf_k(const float* __restrict__ PB, const float* __restrict__ scal,
            float* __restrict__ bag, int nchunk)
{
    int d = blockIdx.x * 256 + threadIdx.x;
    float acc = 0.f;
    for (int c = 0; c < nchunk; c++) acc += PB[(size_t)c * 512 + d];
    bag[d] = acc / scal[0];
}

__global__ __launch_bounds__(256)
void h_k(const float* __restrict__ bag, const float* __restrict__ Wh,
         const float* __restrict__ bh, float* __restrict__ h)
{
    int wid = threadIdx.x >> 6, lane = threadIdx.x & 63;
    int j = blockIdx.x * 4 + wid;
    const float* wr = Wh + (size_t)j * 512;
    float d = 0.f;
#pragma unroll
    for (int t = 0; t < 2; t++) {
        float4 a = *(const float4*)(wr + t * 256 + lane * 4);
        float4 bv = *(const float4*)(bag + t * 256 + lane * 4);
        d += a.x * bv.x + a.y * bv.y + a.z * bv.z + a.w * bv.w;
    }
#pragma unroll
    for (int o = 32; o; o >>= 1) d += __shfl_xor(d, o);
    if (lane == 0) h[j] = fmaxf(d + bh[j], 0.f);
}

__global__ __launch_bounds__(128)
void logit_k(const float* __restrict__ h, const float* __restrict__ Wc,
             const float* __restrict__ bc, float* __restrict__ out)
{
    int wid = threadIdx.x >> 6, lane = threadIdx.x & 63;
    const float* wr = Wc + (size_t)wid * 512;
    float d = 0.f;
#pragma unroll
    for (int t = 0; t < 2; t++) {
        float4 a = *(const float4*)(wr + t * 256 + lane * 4);
        float4 hv = *(const float4*)(h + t * 256 + lane * 4);
        d += a.x * hv.x + a.y * hv.y + a.z * hv.z + a.w * hv.w;
    }
#pragma unroll
    for (int o = 32; o; o >>= 1) d += __shfl_xor(d, o);
    if (lane == 0) out[wid] = d + bc[wid];
}

extern "C" void kernel_launch(void* const* d_in, const int* in_sizes, int n_in,
                              void* d_out, int out_size, void* d_ws, size_t ws_size,
                              hipStream_t stream)
{
    const float* data    = (const float*)d_in[0];
    const float* protos  = (const float*)d_in[1];
    const float* W_pp    = (const float*)d_in[2];
    const float* b_pp    = (const float*)d_in[3];
    const float* W_cp    = (const float*)d_in[4];
    const float* b_cp    = (const float*)d_in[5];
    const float* sscale  = (const float*)d_in[6];
    const float* enh_w1  = (const float*)d_in[7];
    const float* enh_b1  = (const float*)d_in[8];
    const float* enh_w2  = (const float*)d_in[9];
    const float* enh_b2  = (const float*)d_in[10];
    const float* ln_g    = (const float*)d_in[11];
    const float* ln_b    = (const float*)d_in[12];
    const float* red_w1[3] = {(const float*)d_in[13], (const float*)d_in[17], (const float*)d_in[21]};
    const float* red_b1[3] = {(const float*)d_in[14], (const float*)d_in[18], (const float*)d_in[22]};
    const float* red_w2[3] = {(const float*)d_in[15], (const float*)d_in[19], (const float*)d_in[23]};
    const float* red_b2[3] = {(const float*)d_in[16], (const float*)d_in[20], (const float*)d_in[24]};
    const float* W_proc  = (const float*)d_in[25];
    const float* b_proc  = (const float*)d_in[26];
    const float* g_an    = (const float*)d_in[27];
    const float* b_an    = (const float*)d_in[28];
    const float* W_t     = (const float*)d_in[29];
    const float* b_t     = (const float*)d_in[30];
    const float* W_g     = (const float*)d_in[31];
    const float* b_g     = (const float*)d_in[32];
    const float* W_s     = (const float*)d_in[33];
    const float* b_s     = (const float*)d_in[34];  // unused: softmax shift-invariant
    const float* W_h     = (const float*)d_in[35];
    const float* b_h     = (const float*)d_in[36];
    const float* W_c     = (const float*)d_in[37];
    const float* b_c     = (const float*)d_in[38];
    float* out = (float*)d_out;
    (void)b_s;

    constexpr int N = 32768, DIN = 768, D = 512;
    constexpr int NCHUNK = 256;
    char* w = (char*)d_ws;
    auto alloc = [&](size_t bytes) -> char* {
        char* p = w; w += (bytes + 255) & ~(size_t)255; return p;
    };
    _Float16* Ph     = (_Float16*)alloc((size_t)N * D * 2);
    _Float16* TMPh   = (_Float16*)alloc((size_t)N * D * 2);
    _Float16* Zh     = (_Float16*)alloc((size_t)(N + 16) * D * 2);
    _Float16* Ztail  = (_Float16*)alloc((size_t)16 * D * 2);
    _Float16* datah  = (_Float16*)alloc((size_t)N * DIN * 2);
    _Float16* Ah     = (_Float16*)alloc((size_t)N * 128 * 2);
    _Float16* Ch     = (_Float16*)alloc(128 * D * 2);
    _Float16* CTh    = (_Float16*)alloc(128 * D * 2);
    _Float16* Wpph   = (_Float16*)alloc((size_t)D * DIN * 2);
    _Float16* w1h    = (_Float16*)alloc((size_t)3 * D * D * 2);
    _Float16* w2h    = (_Float16*)alloc((size_t)3 * D * D * 2);
    _Float16* Wproch = (_Float16*)alloc((size_t)D * D * 2);
    _Float16* Wth    = (_Float16*)alloc((size_t)D * D * 2);
    _Float16* Wgh    = (_Float16*)alloc((size_t)D * D * 2);
    float*    Psq    = (float*)alloc((size_t)N * 4);
    float*    Csq    = (float*)alloc(128 * 4);
    float*    Ca     = (float*)alloc(128 * D * 4);
    float*    Cb     = (float*)alloc(128 * D * 4);
    float*    H1     = (float*)alloc(128 * D * 4);
    float*    scr    = (float*)alloc((size_t)(N + 16) * 4);
    float*    PB     = (float*)alloc((size_t)NCHUNK * D * 4);
    float*    bag    = (float*)alloc(D * 4);
    float*    hb     = (float*)alloc(D * 4);
    float*    scal   = (float*)alloc(8 * 4);

    dim3 blk(256);
    dim3 blk512(512);
    auto cgrid = [](size_t n) { return dim3((unsigned)((n / 4 + 255) / 256)); };
    auto mgrid = [](int M_, int Nout_) { return dim3((Nout_ + TBN - 1) / TBN, (M_ + TBM - 1) / TBM); };

    // --- convert weights + data to f16 ---
    cvt_k<<<cgrid((size_t)N * DIN), blk, 0, stream>>>(data, datah, N * DIN);
    cvt_k<<<cgrid((size_t)D * DIN), blk, 0, stream>>>(W_pp, Wpph, D * DIN);
    cvt_k<<<cgrid((size_t)3 * D * D), blk, 0, stream>>>(enh_w1, w1h, 3 * D * D);
    cvt_k<<<cgrid((size_t)3 * D * D), blk, 0, stream>>>(enh_w2, w2h, 3 * D * D);
    cvt_k<<<cgrid((size_t)D * D), blk, 0, stream>>>(W_proc, Wproch, D * D);
    cvt_k<<<cgrid((size_t)D * D), blk, 0, stream>>>(W_t, Wth, D * D);
    cvt_k<<<cgrid((size_t)D * D), blk, 0, stream>>>(W_g, Wgh, D * D);

    // P = leaky(data @ W_pp^T + b_pp) -> f16, with fused Psq accumulation
    hipMemsetAsync(Psq, 0, (size_t)N * 4, stream);
    mgemm<0, 1, true><<<mgrid(N, D), blk512, 0, stream>>>(datah, Wpph, b_pp, Ph, Psq, N, DIN, D);
    // C0 = leaky(protos @ W_cp^T + b_cp) -> fp32, then f16 set via cvtC2
    dot_k<1, false><<<dim3(128 * 512 / 4), blk, 0, stream>>>(protos, W_cp, b_cp, Ca, 128, DIN);
    cvtC2_k<<<dim3(32), blk, 0, stream>>>(Ca, Ch, CTh, Csq, 128);

    float* C = Ca;
    float* Cn = Cb;
    int Kin = 128;
    for (int i = 0; i < 3; i++) {
        int Kout = Kin >> 1;
        // A = softmax(-dist/denom) fused with S = P@C^T
        simgemm<<<dim3(1, N / SBM), blk, 0, stream>>>(Ph, Ch, Psq, Csq, sscale, Ah, N, D, Kin);
        if (i < 2) hipMemsetAsync(Psq, 0, (size_t)N * 4, stream);
        // P = LN(P + A@C) fused
        ctxln_k<<<dim3(1, N / 128), blk512, 0, stream>>>(Ah, CTh, ln_g + (size_t)i * D, ln_b + (size_t)i * D, Ph, N, Kin);
        // enhancer MLP: P += w2 @ relu(w1 @ P + b1) + b2   (enh2 fuses Psq for next iter)
        mgemm<0, 2, false><<<mgrid(N, D), blk512, 0, stream>>>(Ph, w1h + (size_t)i * D * D, enh_b1 + (size_t)i * D, TMPh, nullptr, N, D, D);
        if (i < 2)
            mgemm<1, 0, true><<<mgrid(N, D), blk512, 0, stream>>>(TMPh, w2h + (size_t)i * D * D, enh_b2 + (size_t)i * D, Ph, Psq, N, D, D);
        else
            mgemm<1, 0, false><<<mgrid(N, D), blk512, 0, stream>>>(TMPh, w2h + (size_t)i * D * D, enh_b2 + (size_t)i * D, Ph, nullptr, N, D, D);
        // ProtoReducer; red2 emits next iteration's f16 C set
        hipMemsetAsync(Csq, 0, 128 * 4, stream);
        red1_k<<<dim3(2, Kin), blk, 0, stream>>>(C, red_w1[i], red_b1[i], H1, Kin);
        red2_k<<<dim3(2, Kout), blk, 0, stream>>>(H1, red_w2[i], red_b2[i], Cn, Ch, CTh, Csq, Kin, Kout);
        float* t = C; C = Cn; Cn = t;
        Kin = Kout;
    }

    // Z(main) = LN(relu(P @ W_proc^T + b_proc)) fused
    procln_k<<<dim3(1, N / 128), blk512, 0, stream>>>(Ph, Wproch, b_proc, g_an, b_an, Zh, N);
    // Z(tail, 16 C rows): relu(proc) then LN
    dot_k<2, true><<<dim3(16 * 512 / 4), blk, 0, stream>>>(C, W_proc, b_proc, Ztail, 16, D);
    ln_k<<<dim3(4), blk, 0, stream>>>(Ztail, nullptr, g_an, b_an, Zh + (size_t)N * D, 16);

    // scores = (tanh(Z@W_t^T+b_t) * sigmoid(Z@W_g^T+b_g)) @ W_s  (fused)
    hipMemsetAsync(scr, 0, (size_t)(N + 16) * 4, stream);
    gatgemm<<<mgrid(N + 16, D), blk512, 0, stream>>>(Zh, Wth, Wgh, b_t, b_g, W_s, scr, N + 16, D, D);

    // attention pooling
    pool_k<<<dim3(1), dim3(1024), 0, stream>>>(scr, scal, N + 16);
    int cs = (N + 16 + NCHUNK - 1) / NCHUNK;
    bagp_k<<<dim3(2, NCHUNK), blk, 0, stream>>>(Zh, scr, PB, N + 16, cs);
    bagf_k<<<dim3(2), blk, 0, stream>>>(PB, scal, bag, NCHUNK);

    // classifier head
    h_k<<<dim3(128), blk, 0, stream>>>(bag, W_h, b_h, hb);
    logit_k<<<dim3(1), dim3(128), 0, stream>>>(hb, W_c, b_c, out);
}

// Round 16
// 772.487 us; speedup vs baseline: 1.5306x; 1.0289x over previous
//
#include <hip/hip_runtime.h>
#include <math.h>

typedef _Float16 f16x8 __attribute__((ext_vector_type(8)));
typedef _Float16 f16x4 __attribute__((ext_vector_type(4)));
typedef float f32x4 __attribute__((ext_vector_type(4)));

#define TBM 256
#define TBN 128
#define TBK 32

#define AS1 __attribute__((address_space(1)))
#define AS3 __attribute__((address_space(3)))

__device__ __forceinline__ void gll16(const _Float16* g, _Float16* l)
{
    __builtin_amdgcn_global_load_lds((const AS1 unsigned int*)g,
                                     (AS3 unsigned int*)l, 16, 0, 0);
}

// bijective XCD chunking (m204)
__device__ __forceinline__ int xcd_swz(int d, int nwg)
{
    int q = nwg >> 3, r = nwg & 7;
    int x = d & 7, idx = d >> 3;
    int base = x < r ? x * (q + 1) : r * (q + 1) + (x - r) * q;
    return base + idx;
}

// ---- fast transcendentals ----
__device__ __forceinline__ float fsigmoid(float x)
{
    return __builtin_amdgcn_rcpf(1.f + __expf(-x));
}
__device__ __forceinline__ float ftanh(float x)
{
    float ax = fabsf(x);
    float e = __expf(-2.f * ax);
    float t = (1.f - e) * __builtin_amdgcn_rcpf(1.f + e);
    return copysignf(t, x);
}

// ---------------- merged fp32->f16 converter (all weights + data, 1 launch) ----------------
struct CvtSegs {
    const float* src[7];
    _Float16* dst[7];
    int cum4[8];   // quad prefix sums
};

__global__ __launch_bounds__(256)
void cvtall_k(CvtSegs a)
{
    int total = a.cum4[7];
    for (int i = blockIdx.x * 256 + threadIdx.x; i < total; i += gridDim.x * 256) {
        int s = 0;
        while (i >= a.cum4[s + 1]) s++;
        int loc = (i - a.cum4[s]) * 4;
        float4 v = *(const float4*)(a.src[s] + loc);
        f16x4 h = { (_Float16)v.x, (_Float16)v.y, (_Float16)v.z, (_Float16)v.w };
        *(f16x4*)(a.dst[s] + loc) = h;
    }
}

// ---------------- wave-per-output dot kernel (small-M fp32 GEMMs) ----------------
template<int ACT, bool F16OUT>
__global__ __launch_bounds__(256)
void dot_k(const float* __restrict__ X, const float* __restrict__ W,
           const float* __restrict__ bias, void* __restrict__ Yv,
           int M, int K)
{
    int gw = (blockIdx.x * 256 + threadIdx.x) >> 6;
    int lane = threadIdx.x & 63;
    if (gw >= M * 512) return;
    int r = gw >> 9, n = gw & 511;
    const float* xr = X + (size_t)r * K;
    const float* wr = W + (size_t)n * K;
    float d = 0.f;
    for (int t = 0; t < K; t += 256) {
        float4 a = *(const float4*)(xr + t + lane * 4);
        float4 b = *(const float4*)(wr + t + lane * 4);
        d += a.x * b.x + a.y * b.y + a.z * b.z + a.w * b.w;
    }
#pragma unroll
    for (int o = 32; o; o >>= 1) d += __shfl_xor(d, o);
    if (lane == 0) {
        float v = d + bias[n];
        if (ACT == 1) v = v > 0.f ? v : 0.01f * v;
        else if (ACT == 2) v = fmaxf(v, 0.f);
        if (F16OUT) ((_Float16*)Yv)[(size_t)r * 512 + n] = (_Float16)v;
        else        ((float*)Yv)[(size_t)r * 512 + n] = v;
    }
}

// C [Kin,512] fp32 -> Ch, CTh f16 + Csq2 (slot0=sum, slot1=0); one wave per row
__global__ __launch_bounds__(256)
void cvtC2_k(const float* __restrict__ C, _Float16* __restrict__ Ch,
             _Float16* __restrict__ CTh, float* __restrict__ Csq2, int Kin)
{
    int w = threadIdx.x >> 6, lane = threadIdx.x & 63;
    int row = blockIdx.x * 4 + w;
    if (row >= Kin) return;
    float4 a = *(const float4*)(C + (size_t)row * 512 + lane * 8);
    float4 b = *(const float4*)(C + (size_t)row * 512 + lane * 8 + 4);
    f16x8 h;
    h[0] = (_Float16)a.x; h[1] = (_Float16)a.y; h[2] = (_Float16)a.z; h[3] = (_Float16)a.w;
    h[4] = (_Float16)b.x; h[5] = (_Float16)b.y; h[6] = (_Float16)b.z; h[7] = (_Float16)b.w;
    *(f16x8*)(Ch + (size_t)row * 512 + lane * 8) = h;
    float s = 0.f;
#pragma unroll
    for (int q = 0; q < 8; q++) {
        float f = (float)h[q];
        s += f * f;
        CTh[(size_t)(lane * 8 + q) * Kin + row] = h[q];
    }
#pragma unroll
    for (int o = 32; o; o >>= 1) s += __shfl_xor(s, o);
    if (lane == 0) { Csq2[row * 2] = s; Csq2[row * 2 + 1] = 0.f; }
}

// ---------------- f16 MFMA GEMM: 256x128 tile, 8 waves, LDS dbuf, repacked epilogue ----------------
// MODE 0: out = act(v) -> Yh f16; MODE 1: out = Yh + v (coalesced RMW)
// ACT: 0 none, 1 leaky, 2 relu ; SQ: store per-col-block row sum-of-squares into Psq4[m*4+cb]
template<int MODE, int ACT, bool SQ>
__global__ __launch_bounds__(512)
void mgemm(const _Float16* __restrict__ A, const _Float16* __restrict__ B,
           const float* __restrict__ bias, _Float16* __restrict__ Yh,
           float* __restrict__ Psq4, int M, int K, int Nout)
{
    __shared__ _Float16 As[2][TBM * TBK];
    __shared__ _Float16 Bs[2][TBN * TBK];
    const int tid = threadIdx.x;
    const int lane = tid & 63;
    const int wid = tid >> 6;
    const int wr = wid >> 1, wc = wid & 1;

    int bid = xcd_swz(blockIdx.y * gridDim.x + blockIdx.x, gridDim.x * gridDim.y);
    const int m0 = (bid / gridDim.x) * TBM;
    const int n0 = (bid % gridDim.x) * TBN;

    f32x4 acc[4][4] = {};
    const int nt = K / TBK;

    const int lrow = lane >> 2;
    const int lk = (lane & 3) * 8;

    auto stage = [&](int t, int buf) {
        const int k0 = t * TBK;
#pragma unroll
        for (int q = 0; q < 2; q++) {
            int c = wid * 2 + q;
            int r = c * 16 + lrow;
            int am = min(m0 + r, M - 1);
            gll16(A + (size_t)am * K + k0 + lk, &As[buf][c * 512]);
        }
        {
            int c = wid;
            int r = c * 16 + lrow;
            int bn = min(n0 + r, Nout - 1);
            gll16(B + (size_t)bn * K + k0 + lk, &Bs[buf][c * 512]);
        }
    };

    stage(0, 0);
    __syncthreads();
    for (int t = 0; t < nt; ++t) {
        const int cur = t & 1;
        if (t + 1 < nt) stage(t + 1, cur ^ 1);
        f16x8 af[4], bf[4];
#pragma unroll
        for (int mi = 0; mi < 4; mi++)
            af[mi] = *(const f16x8*)(&As[cur][(wr * 64 + mi * 16 + (lane & 15)) * TBK + (lane >> 4) * 8]);
#pragma unroll
        for (int nj = 0; nj < 4; nj++)
            bf[nj] = *(const f16x8*)(&Bs[cur][(wc * 64 + nj * 16 + (lane & 15)) * TBK + (lane >> 4) * 8]);
#pragma unroll
        for (int mi = 0; mi < 4; mi++)
#pragma unroll
            for (int nj = 0; nj < 4; nj++)
                acc[mi][nj] = __builtin_amdgcn_mfma_f32_16x16x32_f16(af[mi], bf[nj], acc[mi][nj], 0, 0, 0);
        __syncthreads();
    }

    _Float16* eb = &As[0][0];
    const int g = lane >> 4;
#pragma unroll
    for (int p = 0; p < 2; p++) {
        if (p) __syncthreads();
        if ((wr >> 1) == p) {
#pragma unroll
            for (int nj = 0; nj < 4; nj++) {
                int col = wc * 64 + nj * 16 + (lane & 15);
                float bv = bias ? bias[n0 + col] : 0.f;
#pragma unroll
                for (int mi = 0; mi < 4; mi++)
#pragma unroll
                    for (int r = 0; r < 4; r++) {
                        int lr = (wr & 1) * 64 + mi * 16 + g * 4 + r;
                        float v = acc[mi][nj][r] + bv;
                        if (MODE == 0) {
                            if (ACT == 1) v = v > 0.f ? v : 0.01f * v;
                            else if (ACT == 2) v = fmaxf(v, 0.f);
                        }
                        eb[lr * 128 + col] = (_Float16)v;
                    }
            }
        }
        __syncthreads();
        int t4 = tid * 4;
        int lr = t4 >> 4;
        int cbase = (t4 & 15) * 8;
        int m = m0 + p * 128 + lr;
        float sq = 0.f;
        if (m < M) {
#pragma unroll
            for (int q = 0; q < 4; q++) {
                int c0 = cbase + q * 8;
                f16x8 hv = *(f16x8*)(eb + lr * 128 + c0);
                size_t gidx = (size_t)m * Nout + n0 + c0;
                if (MODE == 1) {
                    f16x8 old = *(f16x8*)(Yh + gidx);
                    f16x8 nw;
#pragma unroll
                    for (int e = 0; e < 8; e++) {
                        float s = (float)old[e] + (float)hv[e];
                        nw[e] = (_Float16)s;
                    }
                    *(f16x8*)(Yh + gidx) = nw;
                    hv = nw;
                } else {
                    *(f16x8*)(Yh + gidx) = hv;
                }
                if (SQ) {
#pragma unroll
                    for (int e = 0; e < 8; e++) { float f = (float)hv[e]; sq += f * f; }
                }
            }
        }
        if (SQ) {
            sq += __shfl_xor(sq, 1);
            sq += __shfl_xor(sq, 2);
            if ((lane & 3) == 0 && m < M) Psq4[(size_t)m * 4 + (n0 >> 7)] = sq;
        }
    }
}

// ---------------- fused ctx GEMM + LN(P+ctx) -> Ph ----------------
__global__ __launch_bounds__(512)
void ctxln_k(const _Float16* __restrict__ A, const _Float16* __restrict__ CT,
             const float* __restrict__ g, const float* __restrict__ b,
             _Float16* __restrict__ Ph, int M, int Kin)
{
    __shared__ _Float16 As[2][128 * TBK];
    __shared__ _Float16 Bs[2][512 * TBK];
    const int tid = threadIdx.x;
    const int lane = tid & 63;
    const int wid = tid >> 6;
    const int wr = wid >> 2, wc = wid & 3;
    const int m0 = blockIdx.y * 128;

    f32x4 acc[4][8] = {};
    const int nt = Kin / TBK;

    const int lrow = lane >> 2;
    const int lk = (lane & 3) * 8;

    auto stage = [&](int t, int buf) {
        const int k0 = t * TBK;
        {
            int r = wid * 16 + lrow;
            gll16(A + (size_t)(m0 + r) * Kin + k0 + lk, &As[buf][wid * 512]);
        }
#pragma unroll
        for (int q = 0; q < 4; q++) {
            int c = wid * 4 + q;
            int n = c * 16 + lrow;
            gll16(CT + (size_t)n * Kin + k0 + lk, &Bs[buf][c * 512]);
        }
    };

    stage(0, 0);
    __syncthreads();
    for (int t = 0; t < nt; ++t) {
        const int cur = t & 1;
        if (t + 1 < nt) stage(t + 1, cur ^ 1);
        f16x8 af[4], bf[8];
#pragma unroll
        for (int mi = 0; mi < 4; mi++)
            af[mi] = *(const f16x8*)(&As[cur][(wr * 64 + mi * 16 + (lane & 15)) * TBK + (lane >> 4) * 8]);
#pragma unroll
        for (int nj = 0; nj < 8; nj++)
            bf[nj] = *(const f16x8*)(&Bs[cur][(wc * 128 + nj * 16 + (lane & 15)) * TBK + (lane >> 4) * 8]);
#pragma unroll
        for (int mi = 0; mi < 4; mi++)
#pragma unroll
            for (int nj = 0; nj < 8; nj++)
                acc[mi][nj] = __builtin_amdgcn_mfma_f32_16x16x32_f16(af[mi], bf[nj], acc[mi][nj], 0, 0, 0);
        __syncthreads();
    }

    _Float16* eb = &Bs[0][0];
    const int gq = lane >> 4;
#pragma unroll
    for (int p = 0; p < 2; p++) {
        if (p) __syncthreads();
        if (wr == p) {
#pragma unroll
            for (int nj = 0; nj < 8; nj++) {
                int col = wc * 128 + nj * 16 + (lane & 15);
#pragma unroll
                for (int mi = 0; mi < 4; mi++)
#pragma unroll
                    for (int r = 0; r < 4; r++) {
                        int lr = mi * 16 + gq * 4 + r;
                        eb[lr * 512 + col] = (_Float16)acc[mi][nj][r];
                    }
            }
        }
        __syncthreads();
#pragma unroll
        for (int rr = 0; rr < 8; rr++) {
            int lr = wid * 8 + rr;
            int m = m0 + p * 64 + lr;
            f16x8 cv = *(f16x8*)(eb + lr * 512 + lane * 8);
            f16x8 pv = *(const f16x8*)(Ph + (size_t)m * 512 + lane * 8);
            float v[8];
            float s = 0.f, ss = 0.f;
#pragma unroll
            for (int q = 0; q < 8; q++) {
                v[q] = (float)pv[q] + (float)cv[q];
                s += v[q]; ss += v[q] * v[q];
            }
#pragma unroll
            for (int o = 32; o; o >>= 1) { s += __shfl_xor(s, o); ss += __shfl_xor(ss, o); }
            float mean = s * (1.f / 512.f);
            float var = ss * (1.f / 512.f) - mean * mean;
            float inv = 1.f / sqrtf(var + 1e-5f);
            int d0 = lane * 8;
            f16x8 o8;
#pragma unroll
            for (int q = 0; q < 8; q++)
                o8[q] = (_Float16)((v[q] - mean) * inv * g[d0 + q] + b[d0 + q]);
            *(f16x8*)(Ph + (size_t)m * 512 + d0) = o8;
        }
    }
}

// ---------------- fused proc GEMM + relu + LN -> Zh ----------------
__global__ __launch_bounds__(512)
void procln_k(const _Float16* __restrict__ A, const _Float16* __restrict__ W,
              const float* __restrict__ bias, const float* __restrict__ g,
              const float* __restrict__ b, _Float16* __restrict__ Zh, int M)
{
    __shared__ _Float16 As[2][128 * TBK];
    __shared__ _Float16 Bs[2][512 * TBK];
    const int tid = threadIdx.x;
    const int lane = tid & 63;
    const int wid = tid >> 6;
    const int wr = wid >> 2, wc = wid & 3;
    const int m0 = blockIdx.y * 128;
    const int K = 512;

    f32x4 acc[4][8] = {};
    const int nt = K / TBK;

    const int lrow = lane >> 2;
    const int lk = (lane & 3) * 8;

    auto stage = [&](int t, int buf) {
        const int k0 = t * TBK;
        {
            int r = wid * 16 + lrow;
            gll16(A + (size_t)(m0 + r) * K + k0 + lk, &As[buf][wid * 512]);
        }
#pragma unroll
        for (int q = 0; q < 4; q++) {
            int c = wid * 4 + q;
            int n = c * 16 + lrow;
            gll16(W + (size_t)n * K + k0 + lk, &Bs[buf][c * 512]);
        }
    };

    stage(0, 0);
    __syncthreads();
    for (int t = 0; t < nt; ++t) {
        const int cur = t & 1;
        if (t + 1 < nt) stage(t + 1, cur ^ 1);
        f16x8 af[4], bf[8];
#pragma unroll
        for (int mi = 0; mi < 4; mi++)
            af[mi] = *(const f16x8*)(&As[cur][(wr * 64 + mi * 16 + (lane & 15)) * TBK + (lane >> 4) * 8]);
#pragma unroll
        for (int nj = 0; nj < 8; nj++)
            bf[nj] = *(const f16x8*)(&Bs[cur][(wc * 128 + nj * 16 + (lane & 15)) * TBK + (lane >> 4) * 8]);
#pragma unroll
        for (int mi = 0; mi < 4; mi++)
#pragma unroll
            for (int nj = 0; nj < 8; nj++)
                acc[mi][nj] = __builtin_amdgcn_mfma_f32_16x16x32_f16(af[mi], bf[nj], acc[mi][nj], 0, 0, 0);
        __syncthreads();
    }

    _Float16* eb = &Bs[0][0];
    const int gq = lane >> 4;
#pragma unroll
    for (int p = 0; p < 2; p++) {
        if (p) __syncthreads();
        if (wr == p) {
#pragma unroll
            for (int nj = 0; nj < 8; nj++) {
                int col = wc * 128 + nj * 16 + (lane & 15);
                float bv = bias[col];
#pragma unroll
                for (int mi = 0; mi < 4; mi++)
#pragma unroll
                    for (int r = 0; r < 4; r++) {
                        int lr = mi * 16 + gq * 4 + r;
                        eb[lr * 512 + col] = (_Float16)fmaxf(acc[mi][nj][r] + bv, 0.f);
                    }
            }
        }
        __syncthreads();
#pragma unroll
        for (int rr = 0; rr < 8; rr++) {
            int lr = wid * 8 + rr;
            int m = m0 + p * 64 + lr;
            f16x8 cv = *(f16x8*)(eb + lr * 512 + lane * 8);
            float v[8];
            float s = 0.f, ss = 0.f;
#pragma unroll
            for (int q = 0; q < 8; q++) {
                v[q] = (float)cv[q];
                s += v[q]; ss += v[q] * v[q];
            }
#pragma unroll
            for (int o = 32; o; o >>= 1) { s += __shfl_xor(s, o); ss += __shfl_xor(ss, o); }
            float mean = s * (1.f / 512.f);
            float var = ss * (1.f / 512.f) - mean * mean;
            float inv = 1.f / sqrtf(var + 1e-5f);
            int d0 = lane * 8;
            f16x8 o8;
#pragma unroll
            for (int q = 0; q < 8; q++)
                o8[q] = (_Float16)((v[q] - mean) * inv * g[d0 + q] + b[d0 + q]);
            *(f16x8*)(Zh + (size_t)m * 512 + d0) = o8;
        }
    }
}

// ---------------- fused gate + attention-score GEMM (per-col-block partials, no atomics) ----------------
__global__ __launch_bounds__(512)
void gatgemm(const _Float16* __restrict__ A, const _Float16* __restrict__ B1,
             const _Float16* __restrict__ B2, const float* __restrict__ c1,
             const float* __restrict__ c2, const float* __restrict__ Ws,
             float* __restrict__ scr4, int M, int K, int Nout)
{
    __shared__ _Float16 As[2][TBM * TBK];
    __shared__ _Float16 B1s[2][TBN * TBK];
    __shared__ _Float16 B2s[2][TBN * TBK];
    const int tid = threadIdx.x;
    const int lane = tid & 63;
    const int wid = tid >> 6;
    const int wr = wid >> 1, wc = wid & 1;

    int bid = xcd_swz(blockIdx.y * gridDim.x + blockIdx.x, gridDim.x * gridDim.y);
    const int m0 = (bid / gridDim.x) * TBM;
    const int n0 = (bid % gridDim.x) * TBN;

    f32x4 acc1[4][4] = {};
    f32x4 acc2[4][4] = {};
    const int nt = K / TBK;

    const int lrow = lane >> 2;
    const int lk = (lane & 3) * 8;

    auto stage = [&](int t, int buf) {
        const int k0 = t * TBK;
#pragma unroll
        for (int q = 0; q < 2; q++) {
            int c = wid * 2 + q;
            int r = c * 16 + lrow;
            int am = min(m0 + r, M - 1);
            gll16(A + (size_t)am * K + k0 + lk, &As[buf][c * 512]);
        }
        {
            int c = wid;
            int r = c * 16 + lrow;
            int bn = min(n0 + r, Nout - 1);
            gll16(B1 + (size_t)bn * K + k0 + lk, &B1s[buf][c * 512]);
            gll16(B2 + (size_t)bn * K + k0 + lk, &B2s[buf][c * 512]);
        }
    };

    stage(0, 0);
    __syncthreads();
    for (int t = 0; t < nt; ++t) {
        const int cur = t & 1;
        if (t + 1 < nt) stage(t + 1, cur ^ 1);
        f16x8 af[4], bf1[4], bf2[4];
#pragma unroll
        for (int mi = 0; mi < 4; mi++)
            af[mi] = *(const f16x8*)(&As[cur][(wr * 64 + mi * 16 + (lane & 15)) * TBK + (lane >> 4) * 8]);
#pragma unroll
        for (int nj = 0; nj < 4; nj++) {
            int ro = (wc * 64 + nj * 16 + (lane & 15)) * TBK + (lane >> 4) * 8;
            bf1[nj] = *(const f16x8*)(&B1s[cur][ro]);
            bf2[nj] = *(const f16x8*)(&B2s[cur][ro]);
        }
#pragma unroll
        for (int mi = 0; mi < 4; mi++)
#pragma unroll
            for (int nj = 0; nj < 4; nj++) {
                acc1[mi][nj] = __builtin_amdgcn_mfma_f32_16x16x32_f16(af[mi], bf1[nj], acc1[mi][nj], 0, 0, 0);
                acc2[mi][nj] = __builtin_amdgcn_mfma_f32_16x16x32_f16(af[mi], bf2[nj], acc2[mi][nj], 0, 0, 0);
            }
        __syncthreads();
    }

    const int g = lane >> 4;
    float wsv[4];
#pragma unroll
    for (int nj = 0; nj < 4; nj++)
        wsv[nj] = Ws[n0 + wc * 64 + nj * 16 + (lane & 15)];
#pragma unroll
    for (int mi = 0; mi < 4; mi++) {
#pragma unroll
        for (int r = 0; r < 4; r++) {
            float p = 0.f;
#pragma unroll
            for (int nj = 0; nj < 4; nj++) {
                int col = n0 + wc * 64 + nj * 16 + (lane & 15);
                float t1 = ftanh(acc1[mi][nj][r] + c1[col]);
                float g1 = fsigmoid(acc2[mi][nj][r] + c2[col]);
                p += t1 * g1 * wsv[nj];
            }
#pragma unroll
            for (int o = 1; o < 16; o <<= 1) p += __shfl_xor(p, o);
            if ((lane & 15) == 0) {
                int m = m0 + wr * 64 + mi * 16 + g * 4 + r;
                if (m < M) scr4[(size_t)m * 4 + (n0 >> 7)] = p;
            }
        }
    }
}

// ---------------- fused sim GEMM + row softmax, Kin=128: 128-row blocks, 4 waves ----------------
#define SBM 128
__global__ __launch_bounds__(256)
void simgemm(const _Float16* __restrict__ A, const _Float16* __restrict__ B,
             const float* __restrict__ Psq4, const float* __restrict__ Csq2,
             const float* __restrict__ sscale, _Float16* __restrict__ Ah,
             int M, int K)
{
    const int Kin = 128;
    __shared__ _Float16 As[2][SBM * TBK];
    __shared__ _Float16 Bs[2][SBM * TBK];
    __shared__ float redmx[2][SBM];
    __shared__ float redsm[2][SBM];
    const int tid = threadIdx.x;
    const int lane = tid & 63;
    const int wid = tid >> 6;
    const int wr = wid >> 1, wc = wid & 1;
    const int m0 = blockIdx.y * SBM;

    f32x4 acc[4][4] = {};
    const int nt = K / TBK;
    const int lrow = lane >> 2;
    const int lk = (lane & 3) * 8;

    auto stage = [&](int t, int buf) {
        const int k0 = t * TBK;
#pragma unroll
        for (int q = 0; q < 2; q++) {
            int c = wid * 2 + q;
            int r = c * 16 + lrow;
            gll16(A + (size_t)(m0 + r) * K + k0 + lk, &As[buf][c * 512]);
            gll16(B + (size_t)r * K + k0 + lk, &Bs[buf][c * 512]);
        }
    };

    stage(0, 0);
    __syncthreads();
    for (int t = 0; t < nt; ++t) {
        const int cur = t & 1;
        if (t + 1 < nt) stage(t + 1, cur ^ 1);
        f16x8 af[4], bf[4];
#pragma unroll
        for (int mi = 0; mi < 4; mi++)
            af[mi] = *(const f16x8*)(&As[cur][(wr * 64 + mi * 16 + (lane & 15)) * TBK + (lane >> 4) * 8]);
#pragma unroll
        for (int nj = 0; nj < 4; nj++)
            bf[nj] = *(const f16x8*)(&Bs[cur][(wc * 64 + nj * 16 + (lane & 15)) * TBK + (lane >> 4) * 8]);
#pragma unroll
        for (int mi = 0; mi < 4; mi++)
#pragma unroll
            for (int nj = 0; nj < 4; nj++)
                acc[mi][nj] = __builtin_amdgcn_mfma_f32_16x16x32_f16(af[mi], bf[nj], acc[mi][nj], 0, 0, 0);
        __syncthreads();
    }

    const float denom = fmaxf(1e-6f, sscale[0]);
    const int colbase = wc * 64 + (lane & 15);
    const int g = lane >> 4;
    float cc[4];
#pragma unroll
    for (int nj = 0; nj < 4; nj++) {
        int n = colbase + nj * 16;
        cc[nj] = Csq2[n * 2] + Csq2[n * 2 + 1];
    }

#pragma unroll
    for (int mi = 0; mi < 4; mi++) {
#pragma unroll
        for (int r = 0; r < 4; r++) {
            int row = wr * 64 + mi * 16 + g * 4 + r;
            float4 pq = *(const float4*)(Psq4 + (size_t)(m0 + row) * 4);
            float pp = (pq.x + pq.y) + (pq.z + pq.w);
            float mx = -INFINITY;
#pragma unroll
            for (int nj = 0; nj < 4; nj++) {
                float v = -sqrtf(fmaxf(pp + cc[nj] - 2.f * acc[mi][nj][r], 1e-12f)) / denom;
                acc[mi][nj][r] = v;
                mx = fmaxf(mx, v);
            }
#pragma unroll
            for (int o = 1; o < 16; o <<= 1) mx = fmaxf(mx, __shfl_xor(mx, o));
            if ((lane & 15) == 0) redmx[wc][row] = mx;
        }
    }
    __syncthreads();

#pragma unroll
    for (int mi = 0; mi < 4; mi++) {
#pragma unroll
        for (int r = 0; r < 4; r++) {
            int row = wr * 64 + mi * 16 + g * 4 + r;
            float mx = fmaxf(redmx[0][row], redmx[1][row]);
            float s = 0.f;
#pragma unroll
            for (int nj = 0; nj < 4; nj++) {
                float e = __expf(acc[mi][nj][r] - mx);
                acc[mi][nj][r] = e;
                s += e;
            }
#pragma unroll
            for (int o = 1; o < 16; o <<= 1) s += __shfl_xor(s, o);
            if ((lane & 15) == 0) redsm[wc][row] = s;
        }
    }
    __syncthreads();

#pragma unroll
    for (int mi = 0; mi < 4; mi++) {
#pragma unroll
        for (int r = 0; r < 4; r++) {
            int row = wr * 64 + mi * 16 + g * 4 + r;
            float inv = __builtin_amdgcn_rcpf(redsm[0][row] + redsm[1][row]);
            int m = m0 + row;
#pragma unroll
            for (int nj = 0; nj < 4; nj++)
                Ah[(size_t)m * Kin + colbase + nj * 16] = (_Float16)(acc[mi][nj][r] * inv);
        }
    }
}

// ---------------- fused sim GEMM + row softmax, KIN<=64: 256-row blocks, 4 waves ----------------
// all KIN cols live in one wave -> softmax is pure 16-lane shuffles, no LDS reduce
template<int KIN>
__global__ __launch_bounds__(256)
void simgemm_s(const _Float16* __restrict__ A, const _Float16* __restrict__ B,
               const float* __restrict__ Psq4, const float* __restrict__ Csq2,
               const float* __restrict__ sscale, _Float16* __restrict__ Ah,
               int M, int K)
{
    constexpr int NB = KIN / 16;
    __shared__ _Float16 As[2][256 * TBK];
    __shared__ _Float16 Bs[2][KIN * TBK];
    const int tid = threadIdx.x;
    const int lane = tid & 63;
    const int wid = tid >> 6;           // 0..3 row-groups of 64
    const int m0 = blockIdx.y * 256;

    f32x4 acc[4][NB] = {};
    const int nt = K / TBK;
    const int lrow = lane >> 2;
    const int lk = (lane & 3) * 8;

    auto stage = [&](int t, int buf) {
        const int k0 = t * TBK;
#pragma unroll
        for (int q = 0; q < 4; q++) {
            int c = wid * 4 + q;
            int r = c * 16 + lrow;
            gll16(A + (size_t)(m0 + r) * K + k0 + lk, &As[buf][c * 512]);
        }
        if (wid < NB) {
            int r = wid * 16 + lrow;
            gll16(B + (size_t)r * K + k0 + lk, &Bs[buf][wid * 512]);
        }
    };

    stage(0, 0);
    __syncthreads();
    for (int t = 0; t < nt; ++t) {
        const int cur = t & 1;
        if (t + 1 < nt) stage(t + 1, cur ^ 1);
        f16x8 af[4], bf[NB];
#pragma unroll
        for (int mi = 0; mi < 4; mi++)
            af[mi] = *(const f16x8*)(&As[cur][(wid * 64 + mi * 16 + (lane & 15)) * TBK + (lane >> 4) * 8]);
#pragma unroll
        for (int nj = 0; nj < NB; nj++)
            bf[nj] = *(const f16x8*)(&Bs[cur][(nj * 16 + (lane & 15)) * TBK + (lane >> 4) * 8]);
#pragma unroll
        for (int mi = 0; mi < 4; mi++)
#pragma unroll
            for (int nj = 0; nj < NB; nj++)
                acc[mi][nj] = __builtin_amdgcn_mfma_f32_16x16x32_f16(af[mi], bf[nj], acc[mi][nj], 0, 0, 0);
        __syncthreads();
    }

    const float denom = fmaxf(1e-6f, sscale[0]);
    const int g = lane >> 4;
    float cc[NB];
#pragma unroll
    for (int nj = 0; nj < NB; nj++) {
        int n = nj * 16 + (lane & 15);
        cc[nj] = Csq2[n * 2] + Csq2[n * 2 + 1];
    }

#pragma unroll
    for (int mi = 0; mi < 4; mi++) {
#pragma unroll
        for (int r = 0; r < 4; r++) {
            int m = m0 + wid * 64 + mi * 16 + g * 4 + r;
            float4 pq = *(const float4*)(Psq4 + (size_t)m * 4);
            float pp = (pq.x + pq.y) + (pq.z + pq.w);
            float vv[NB];
            float mx = -INFINITY;
#pragma unroll
            for (int nj = 0; nj < NB; nj++) {
                float v = -sqrtf(fmaxf(pp + cc[nj] - 2.f * acc[mi][nj][r], 1e-12f)) / denom;
                vv[nj] = v;
                mx = fmaxf(mx, v);
            }
#pragma unroll
            for (int o = 1; o < 16; o <<= 1) mx = fmaxf(mx, __shfl_xor(mx, o));
            float s = 0.f;
#pragma unroll
            for (int nj = 0; nj < NB; nj++) { float e = __expf(vv[nj] - mx); vv[nj] = e; s += e; }
#pragma unroll
            for (int o = 1; o < 16; o <<= 1) s += __shfl_xor(s, o);
            float inv = __builtin_amdgcn_rcpf(s);
#pragma unroll
            for (int nj = 0; nj < NB; nj++)
                Ah[(size_t)m * KIN + nj * 16 + (lane & 15)] = (_Float16)(vv[nj] * inv);
        }
    }
}

// ---------------- small kernels (f16 activations) ----------------
__global__ __launch_bounds__(256)
void ln_k(const _Float16* __restrict__ X, const _Float16* __restrict__ R,
          const float* __restrict__ g, const float* __restrict__ b,
          _Float16* __restrict__ Yh, int M)
{
    int wid = threadIdx.x >> 6, lane = threadIdx.x & 63;
    int row = blockIdx.x * 4 + wid;
    if (row >= M) return;
    f16x8 a = *(const f16x8*)(X + (size_t)row * 512 + lane * 8);
    float v[8];
#pragma unroll
    for (int q = 0; q < 8; q++) v[q] = (float)a[q];
    if (R) {
        f16x8 c = *(const f16x8*)(R + (size_t)row * 512 + lane * 8);
#pragma unroll
        for (int q = 0; q < 8; q++) v[q] += (float)c[q];
    }
    float s = 0.f, ss = 0.f;
#pragma unroll
    for (int q = 0; q < 8; q++) { s += v[q]; ss += v[q] * v[q]; }
#pragma unroll
    for (int o = 32; o; o >>= 1) { s += __shfl_xor(s, o); ss += __shfl_xor(ss, o); }
    float mean = s * (1.f / 512.f);
    float var = ss * (1.f / 512.f) - mean * mean;
    float inv = 1.f / sqrtf(var + 1e-5f);
    int d0 = lane * 8;
    f16x8 o8;
#pragma unroll
    for (int q = 0; q < 8; q++)
        o8[q] = (_Float16)((v[q] - mean) * inv * g[d0 + q] + b[d0 + q]);
    *(f16x8*)(Yh + (size_t)row * 512 + d0) = o8;
}

__global__ __launch_bounds__(256)
void red1_k(const float* __restrict__ C, const float* __restrict__ w1,
            const float* __restrict__ b1, float* __restrict__ H1, int Kin)
{
    int d = blockIdx.x * 256 + threadIdx.x;
    int j = blockIdx.y;
    float acc = b1[j];
    for (int k = 0; k < Kin; k++) acc = fmaf(C[(size_t)k * 512 + d], w1[(size_t)j * Kin + k], acc);
    H1[(size_t)j * 512 + d] = fmaxf(acc, 0.f);
}

// red2 + fused f16 conversion/transpose/Csq2 emission (block-reduced, no atomics)
__global__ __launch_bounds__(256)
void red2_k(const float* __restrict__ H1, const float* __restrict__ w2,
            const float* __restrict__ b2, float* __restrict__ Cn,
            _Float16* __restrict__ Chn, _Float16* __restrict__ CThn,
            float* __restrict__ Csq2, int Kin, int Kout)
{
    __shared__ float sm[4];
    int d = blockIdx.x * 256 + threadIdx.x;
    int j2 = blockIdx.y;
    float acc = b2[j2];
    for (int j = 0; j < Kin; j++) acc = fmaf(H1[(size_t)j * 512 + d], w2[(size_t)j2 * Kin + j], acc);
    Cn[(size_t)j2 * 512 + d] = acc;
    _Float16 h = (_Float16)acc;
    Chn[(size_t)j2 * 512 + d] = h;
    CThn[(size_t)d * Kout + j2] = h;
    float f = (float)h;
    float sq = f * f;
#pragma unroll
    for (int o = 32; o; o >>= 1) sq += __shfl_xor(sq, o);
    if ((threadIdx.x & 63) == 0) sm[threadIdx.x >> 6] = sq;
    __syncthreads();
    if (threadIdx.x == 0)
        Csq2[j2 * 2 + blockIdx.x] = (sm[0] + sm[1]) + (sm[2] + sm[3]);
}

// single block: sum scr4 partials -> scr, softmax-exp in place, scal = sum(exp)
__global__ __launch_bounds__(1024)
void pool_k(const float4* __restrict__ s4, float* __restrict__ s,
            float* __restrict__ scal, int M)
{
    __shared__ float sm[16];
    int tid = threadIdx.x, lane = tid & 63, wid = tid >> 6;
    float mx = -INFINITY;
    for (int i = tid; i < M; i += 1024) {
        float4 a = s4[i];
        float v = (a.x + a.y) + (a.z + a.w);
        s[i] = v;
        mx = fmaxf(mx, v);
    }
#pragma unroll
    for (int o = 32; o; o >>= 1) mx = fmaxf(mx, __shfl_xor(mx, o));
    if (lane == 0) sm[wid] = mx;
    __syncthreads();
    if (wid == 0) {
        float v = (lane < 16) ? sm[lane] : -INFINITY;
#pragma unroll
        for (int o = 8; o; o >>= 1) v = fmaxf(v, __shfl_xor(v, o));
        if (lane == 0) sm[0] = v;
    }
    __syncthreads();
    float gmax = sm[0];
    __syncthreads();
    float sum = 0.f;
    for (int i = tid; i < M; i += 1024) {
        float e = __expf(s[i] - gmax);
        s[i] = e;
        sum += e;
    }
#pragma unroll
    for (int o = 32; o; o >>= 1) sum += __shfl_xor(sum, o);
    if (lane == 0) sm[wid] = sum;
    __syncthreads();
    if (tid == 0) {
        float t = 0.f;
        for (int w = 0; w < 16; w++) t += sm[w];
        scal[0] = t;
    }
}

__global__ __launch_bounds__(256)
void bagp_k(const _Float16* __restrict__ Z, const float* __restrict__ w,
            float* __restrict__ PB, int M, int cs)
{
    int d = blockIdx.x * 256 + threadIdx.x;
    int chunk = blockIdx.y;
    int i0 = chunk * cs;
    int i1 = min(M, i0 + cs);
    float acc = 0.f;
    for (int i = i0; i < i1; i++) acc = fmaf(w[i], (float)Z[(size_t)i * 512 + d], acc);
    PB[(size_t)chunk * 512 + d] = acc;
}

__global__ __launch_bounds__(256)
void bagf_k(const float* __restrict__ PB, const float* __restrict__ scal,
            float* __restrict__ bag, int nchunk)
{
    int d = blockIdx.x * 256 + threadIdx.x;
    float acc = 0.f;
    for (int c = 0; c < nchunk; c++) acc += PB[(size_t)c * 512 + d];
    bag[d] = acc / scal[0];
}

__global__ __launch_bounds__(256)
void h_k(const float* __restrict__ bag, const float* __restrict__ Wh,
         const float* __restrict__ bh, float* __restrict__ h)
{
    int wid = threadIdx.x >> 6, lane = threadIdx.x & 63;
    int j = blockIdx.x * 4 + wid;
    const float* wr = Wh + (size_t)j * 512;
    float d = 0.f;
#pragma unroll
    for (int t = 0; t < 2; t++) {
        float4 a = *(const float4*)(wr + t * 256 + lane * 4);
        float4 bv = *(const float4*)(bag + t * 256 + lane * 4);
        d += a.x * bv.x + a.y * bv.y + a.z * bv.z + a.w * bv.w;
    }
#pragma unroll
    for (int o = 32; o; o >>= 1) d += __shfl_xor(d, o);
    if (lane == 0) h[j] = fmaxf(d + bh[j], 0.f);
}

__global__ __launch_bounds__(128)
void logit_k(const float* __restrict__ h, const float* __restrict__ Wc,
             const float* __restrict__ bc, float* __restrict__ out)
{
    int wid = threadIdx.x >> 6, lane = threadIdx.x & 63;
    const float* wr = Wc + (size_t)wid * 512;
    float d = 0.f;
#pragma unroll
    for (int t = 0; t < 2; t++) {
        float4 a = *(const float4*)(wr + t * 256 + lane * 4);
        float4 hv = *(const float4*)(h + t * 256 + lane * 4);
        d += a.x * hv.x + a.y * hv.y + a.z * hv.z + a.w * hv.w;
    }
#pragma unroll
    for (int o = 32; o; o >>= 1) d += __shfl_xor(d, o);
    if (lane == 0) out[wid] = d + bc[wid];
}

extern "C" void kernel_launch(void* const* d_in, const int* in_sizes, int n_in,
                              void* d_out, int out_size, void* d_ws, size_t ws_size,
                              hipStream_t stream)
{
    const float* data    = (const float*)d_in[0];
    const float* protos  = (const float*)d_in[1];
    const float* W_pp    = (const float*)d_in[2];
    const float* b_pp    = (const float*)d_in[3];
    const float* W_cp    = (const float*)d_in[4];
    const float* b_cp    = (const float*)d_in[5];
    const float* sscale  = (const float*)d_in[6];
    const float* enh_w1  = (const float*)d_in[7];
    const float* enh_b1  = (const float*)d_in[8];
    const float* enh_w2  = (const float*)d_in[9];
    const float* enh_b2  = (const float*)d_in[10];
    const float* ln_g    = (const float*)d_in[11];
    const float* ln_b    = (const float*)d_in[12];
    const float* red_w1[3] = {(const float*)d_in[13], (const float*)d_in[17], (const float*)d_in[21]};
    const float* red_b1[3] = {(const float*)d_in[14], (const float*)d_in[18], (const float*)d_in[22]};
    const float* red_w2[3] = {(const float*)d_in[15], (const float*)d_in[19], (const float*)d_in[23]};
    const float* red_b2[3] = {(const float*)d_in[16], (const float*)d_in[20], (const float*)d_in[24]};
    const float* W_proc  = (const float*)d_in[25];
    const float* b_proc  = (const float*)d_in[26];
    const float* g_an    = (const float*)d_in[27];
    const float* b_an    = (const float*)d_in[28];
    const float* W_t     = (const float*)d_in[29];
    const float* b_t     = (const float*)d_in[30];
    const float* W_g     = (const float*)d_in[31];
    const float* b_g     = (const float*)d_in[32];
    const float* W_s     = (const float*)d_in[33];
    const float* b_s     = (const float*)d_in[34];  // unused: softmax shift-invariant
    const float* W_h     = (const float*)d_in[35];
    const float* b_h     = (const float*)d_in[36];
    const float* W_c     = (const float*)d_in[37];
    const float* b_c     = (const float*)d_in[38];
    float* out = (float*)d_out;
    (void)b_s;

    constexpr int N = 32768, DIN = 768, D = 512;
    constexpr int NCHUNK = 256;
    char* w = (char*)d_ws;
    auto alloc = [&](size_t bytes) -> char* {
        char* p = w; w += (bytes + 255) & ~(size_t)255; return p;
    };
    _Float16* Ph     = (_Float16*)alloc((size_t)N * D * 2);
    _Float16* TMPh   = (_Float16*)alloc((size_t)N * D * 2);
    _Float16* Zh     = (_Float16*)alloc((size_t)(N + 16) * D * 2);
    _Float16* Ztail  = (_Float16*)alloc((size_t)16 * D * 2);
    _Float16* datah  = (_Float16*)alloc((size_t)N * DIN * 2);
    _Float16* Ah     = (_Float16*)alloc((size_t)N * 128 * 2);
    _Float16* Ch     = (_Float16*)alloc(128 * D * 2);
    _Float16* CTh    = (_Float16*)alloc(128 * D * 2);
    _Float16* Wpph   = (_Float16*)alloc((size_t)D * DIN * 2);
    _Float16* w1h    = (_Float16*)alloc((size_t)3 * D * D * 2);
    _Float16* w2h    = (_Float16*)alloc((size_t)3 * D * D * 2);
    _Float16* Wproch = (_Float16*)alloc((size_t)D * D * 2);
    _Float16* Wth    = (_Float16*)alloc((size_t)D * D * 2);
    _Float16* Wgh    = (_Float16*)alloc((size_t)D * D * 2);
    float*    Psq4   = (float*)alloc((size_t)N * 4 * 4);
    float*    Csq2   = (float*)alloc(128 * 2 * 4);
    float*    Ca     = (float*)alloc(128 * D * 4);
    float*    Cb     = (float*)alloc(128 * D * 4);
    float*    H1     = (float*)alloc(128 * D * 4);
    float*    scr4   = (float*)alloc((size_t)(N + 16) * 4 * 4);
    float*    scr    = (float*)alloc((size_t)(N + 16) * 4);
    float*    PB     = (float*)alloc((size_t)NCHUNK * D * 4);
    float*    bag    = (float*)alloc(D * 4);
    float*    hb     = (float*)alloc(D * 4);
    float*    scal   = (float*)alloc(8 * 4);

    dim3 blk(256);
    dim3 blk512(512);
    auto mgrid = [](int M_, int Nout_) { return dim3((Nout_ + TBN - 1) / TBN, (M_ + TBM - 1) / TBM); };

    // --- merged fp32->f16 conversion: data + all weights, one launch ---
    {
        CvtSegs cs;
        const float* srcs[7] = { data, W_pp, enh_w1, enh_w2, W_proc, W_t, W_g };
        _Float16* dsts[7]    = { datah, Wpph, w1h, w2h, Wproch, Wth, Wgh };
        int sizes[7] = { N * DIN, D * DIN, 3 * D * D, 3 * D * D, D * D, D * D, D * D };
        int c = 0;
        cs.cum4[0] = 0;
        for (int s = 0; s < 7; s++) {
            cs.src[s] = srcs[s]; cs.dst[s] = dsts[s];
            c += sizes[s] / 4;
            cs.cum4[s + 1] = c;
        }
        cvtall_k<<<dim3(4096), blk, 0, stream>>>(cs);
    }

    // P = leaky(data @ W_pp^T + b_pp) -> f16, per-col-block Psq4 partials
    mgemm<0, 1, true><<<mgrid(N, D), blk512, 0, stream>>>(datah, Wpph, b_pp, Ph, Psq4, N, DIN, D);
    // C0 = leaky(protos @ W_cp^T + b_cp) -> fp32, then f16 set via cvtC2
    dot_k<1, false><<<dim3(128 * 512 / 4), blk, 0, stream>>>(protos, W_cp, b_cp, Ca, 128, DIN);
    cvtC2_k<<<dim3(32), blk, 0, stream>>>(Ca, Ch, CTh, Csq2, 128);

    float* C = Ca;
    float* Cn = Cb;
    int Kin = 128;
    for (int i = 0; i < 3; i++) {
        int Kout = Kin >> 1;
        // A = softmax(-dist/denom) fused with S = P@C^T
        if (i == 0)
            simgemm<<<dim3(1, N / SBM), blk, 0, stream>>>(Ph, Ch, Psq4, Csq2, sscale, Ah, N, D);
        else if (i == 1)
            simgemm_s<64><<<dim3(1, N / 256), blk, 0, stream>>>(Ph, Ch, Psq4, Csq2, sscale, Ah, N, D);
        else
            simgemm_s<32><<<dim3(1, N / 256), blk, 0, stream>>>(Ph, Ch, Psq4, Csq2, sscale, Ah, N, D);
        // P = LN(P + A@C) fused
        ctxln_k<<<dim3(1, N / 128), blk512, 0, stream>>>(Ah, CTh, ln_g + (size_t)i * D, ln_b + (size_t)i * D, Ph, N, Kin);
        // enhancer MLP: P += w2 @ relu(w1 @ P + b1) + b2   (enh2 emits Psq4 for next iter)
        mgemm<0, 2, false><<<mgrid(N, D), blk512, 0, stream>>>(Ph, w1h + (size_t)i * D * D, enh_b1 + (size_t)i * D, TMPh, nullptr, N, D, D);
        if (i < 2)
            mgemm<1, 0, true><<<mgrid(N, D), blk512, 0, stream>>>(TMPh, w2h + (size_t)i * D * D, enh_b2 + (size_t)i * D, Ph, Psq4, N, D, D);
        else
            mgemm<1, 0, false><<<mgrid(N, D), blk512, 0, stream>>>(TMPh, w2h + (size_t)i * D * D, enh_b2 + (size_t)i * D, Ph, nullptr, N, D, D);
        // ProtoReducer; red2 emits next iteration's f16 C set + Csq2
        red1_k<<<dim3(2, Kin), blk, 0, stream>>>(C, red_w1[i], red_b1[i], H1, Kin);
        red2_k<<<dim3(2, Kout), blk, 0, stream>>>(H1, red_w2[i], red_b2[i], Cn, Ch, CTh, Csq2, Kin, Kout);
        float* t = C; C = Cn; Cn = t;
        Kin = Kout;
    }

    // Z(main) = LN(relu(P @ W_proc^T + b_proc)) fused
    procln_k<<<dim3(1, N / 128), blk512, 0, stream>>>(Ph, Wproch, b_proc, g_an, b_an, Zh, N);
    // Z(tail, 16 C rows)
    dot_k<2, true><<<dim3(16 * 512 / 4), blk, 0, stream>>>(C, W_proc, b_proc, Ztail, 16, D);
    ln_k<<<dim3(4), blk, 0, stream>>>(Ztail, nullptr, g_an, b_an, Zh + (size_t)N * D, 16);

    // scores: per-col-block partials into scr4 (no memset, no atomics)
    gatgemm<<<mgrid(N + 16, D), blk512, 0, stream>>>(Zh, Wth, Wgh, b_t, b_g, W_s, scr4, N + 16, D, D);

    // attention pooling
    pool_k<<<dim3(1), dim3(1024), 0, stream>>>((const float4*)scr4, scr, scal, N + 16);
    int cs2 = (N + 16 + NCHUNK - 1) / NCHUNK;
    bagp_k<<<dim3(2, NCHUNK), blk, 0, stream>>>(Zh, scr, PB, N + 16, cs2);
    bagf_k<<<dim3(2), blk, 0, stream>>>(PB, scal, bag, NCHUNK);

    // classifier head
    h_k<<<dim3(128), blk, 0, stream>>>(bag, W_h, b_h, hb);
    logit_k<<<dim3(1), dim3(128), 0, stream>>>(hb, W_c, b_c, out);
}

// Round 17
// 757.710 us; speedup vs baseline: 1.5604x; 1.0195x over previous
//
#include <hip/hip_runtime.h>
#include <math.h>

typedef _Float16 f16x8 __attribute__((ext_vector_type(8)));
typedef _Float16 f16x4 __attribute__((ext_vector_type(4)));
typedef float f32x4 __attribute__((ext_vector_type(4)));

#define TBM 256
#define TBN 128
#define TBK 32

#define AS1 __attribute__((address_space(1)))
#define AS3 __attribute__((address_space(3)))

__device__ __forceinline__ void gll16(const _Float16* g, _Float16* l)
{
    __builtin_amdgcn_global_load_lds((const AS1 unsigned int*)g,
                                     (AS3 unsigned int*)l, 16, 0, 0);
}

// bijective XCD chunking (m204)
__device__ __forceinline__ int xcd_swz(int d, int nwg)
{
    int q = nwg >> 3, r = nwg & 7;
    int x = d & 7, idx = d >> 3;
    int base = x < r ? x * (q + 1) : r * (q + 1) + (x - r) * q;
    return base + idx;
}

// ---- fast transcendentals ----
__device__ __forceinline__ float fsigmoid(float x)
{
    return __builtin_amdgcn_rcpf(1.f + __expf(-x));
}
__device__ __forceinline__ float ftanh(float x)
{
    float ax = fabsf(x);
    float e = __expf(-2.f * ax);
    float t = (1.f - e) * __builtin_amdgcn_rcpf(1.f + e);
    return copysignf(t, x);
}

// ---------------- merged fp32->f16 converter (weights only, 1 launch) ----------------
struct CvtSegs {
    const float* src[6];
    _Float16* dst[6];
    int cum4[7];   // quad prefix sums
};

__global__ __launch_bounds__(256)
void cvtall_k(CvtSegs a)
{
    int total = a.cum4[6];
    for (int i = blockIdx.x * 256 + threadIdx.x; i < total; i += gridDim.x * 256) {
        int s = 0;
        while (i >= a.cum4[s + 1]) s++;
        int loc = (i - a.cum4[s]) * 4;
        float4 v = *(const float4*)(a.src[s] + loc);
        f16x4 h = { (_Float16)v.x, (_Float16)v.y, (_Float16)v.z, (_Float16)v.w };
        *(f16x4*)(a.dst[s] + loc) = h;
    }
}

// ---------------- wave-per-output dot kernel (small-M fp32 GEMMs) ----------------
template<int ACT, bool F16OUT>
__global__ __launch_bounds__(256)
void dot_k(const float* __restrict__ X, const float* __restrict__ W,
           const float* __restrict__ bias, void* __restrict__ Yv,
           int M, int K)
{
    int gw = (blockIdx.x * 256 + threadIdx.x) >> 6;
    int lane = threadIdx.x & 63;
    if (gw >= M * 512) return;
    int r = gw >> 9, n = gw & 511;
    const float* xr = X + (size_t)r * K;
    const float* wr = W + (size_t)n * K;
    float d = 0.f;
    for (int t = 0; t < K; t += 256) {
        float4 a = *(const float4*)(xr + t + lane * 4);
        float4 b = *(const float4*)(wr + t + lane * 4);
        d += a.x * b.x + a.y * b.y + a.z * b.z + a.w * b.w;
    }
#pragma unroll
    for (int o = 32; o; o >>= 1) d += __shfl_xor(d, o);
    if (lane == 0) {
        float v = d + bias[n];
        if (ACT == 1) v = v > 0.f ? v : 0.01f * v;
        else if (ACT == 2) v = fmaxf(v, 0.f);
        if (F16OUT) ((_Float16*)Yv)[(size_t)r * 512 + n] = (_Float16)v;
        else        ((float*)Yv)[(size_t)r * 512 + n] = v;
    }
}

// C [Kin,512] fp32 -> Ch, CTh f16 + Csq2 (slot0=sum, slot1=0); one wave per row
__global__ __launch_bounds__(256)
void cvtC2_k(const float* __restrict__ C, _Float16* __restrict__ Ch,
             _Float16* __restrict__ CTh, float* __restrict__ Csq2, int Kin)
{
    int w = threadIdx.x >> 6, lane = threadIdx.x & 63;
    int row = blockIdx.x * 4 + w;
    if (row >= Kin) return;
    float4 a = *(const float4*)(C + (size_t)row * 512 + lane * 8);
    float4 b = *(const float4*)(C + (size_t)row * 512 + lane * 8 + 4);
    f16x8 h;
    h[0] = (_Float16)a.x; h[1] = (_Float16)a.y; h[2] = (_Float16)a.z; h[3] = (_Float16)a.w;
    h[4] = (_Float16)b.x; h[5] = (_Float16)b.y; h[6] = (_Float16)b.z; h[7] = (_Float16)b.w;
    *(f16x8*)(Ch + (size_t)row * 512 + lane * 8) = h;
    float s = 0.f;
#pragma unroll
    for (int q = 0; q < 8; q++) {
        float f = (float)h[q];
        s += f * f;
        CTh[(size_t)(lane * 8 + q) * Kin + row] = h[q];
    }
#pragma unroll
    for (int o = 32; o; o >>= 1) s += __shfl_xor(s, o);
    if (lane == 0) { Csq2[row * 2] = s; Csq2[row * 2 + 1] = 0.f; }
}

// ---------------- f16 MFMA GEMM: 256x128 tile, 8 waves, LDS dbuf, repacked epilogue ----------------
// MODE 0: out = act(v) -> Yh f16; MODE 1: out = Yh + v (coalesced RMW)
// ACT: 0 none, 1 leaky, 2 relu ; SQ: store per-col-block row sum-of-squares into Psq4[m*4+cb]
template<int MODE, int ACT, bool SQ>
__global__ __launch_bounds__(512)
void mgemm(const _Float16* __restrict__ A, const _Float16* __restrict__ B,
           const float* __restrict__ bias, _Float16* __restrict__ Yh,
           float* __restrict__ Psq4, int M, int K, int Nout)
{
    __shared__ _Float16 As[2][TBM * TBK];
    __shared__ _Float16 Bs[2][TBN * TBK];
    const int tid = threadIdx.x;
    const int lane = tid & 63;
    const int wid = tid >> 6;
    const int wr = wid >> 1, wc = wid & 1;

    int bid = xcd_swz(blockIdx.y * gridDim.x + blockIdx.x, gridDim.x * gridDim.y);
    const int m0 = (bid / gridDim.x) * TBM;
    const int n0 = (bid % gridDim.x) * TBN;

    f32x4 acc[4][4] = {};
    const int nt = K / TBK;

    const int lrow = lane >> 2;
    const int lk = (lane & 3) * 8;

    auto stage = [&](int t, int buf) {
        const int k0 = t * TBK;
#pragma unroll
        for (int q = 0; q < 2; q++) {
            int c = wid * 2 + q;
            int r = c * 16 + lrow;
            int am = min(m0 + r, M - 1);
            gll16(A + (size_t)am * K + k0 + lk, &As[buf][c * 512]);
        }
        {
            int c = wid;
            int r = c * 16 + lrow;
            int bn = min(n0 + r, Nout - 1);
            gll16(B + (size_t)bn * K + k0 + lk, &Bs[buf][c * 512]);
        }
    };

    stage(0, 0);
    __syncthreads();
    for (int t = 0; t < nt; ++t) {
        const int cur = t & 1;
        if (t + 1 < nt) stage(t + 1, cur ^ 1);
        f16x8 af[4], bf[4];
#pragma unroll
        for (int mi = 0; mi < 4; mi++)
            af[mi] = *(const f16x8*)(&As[cur][(wr * 64 + mi * 16 + (lane & 15)) * TBK + (lane >> 4) * 8]);
#pragma unroll
        for (int nj = 0; nj < 4; nj++)
            bf[nj] = *(const f16x8*)(&Bs[cur][(wc * 64 + nj * 16 + (lane & 15)) * TBK + (lane >> 4) * 8]);
#pragma unroll
        for (int mi = 0; mi < 4; mi++)
#pragma unroll
            for (int nj = 0; nj < 4; nj++)
                acc[mi][nj] = __builtin_amdgcn_mfma_f32_16x16x32_f16(af[mi], bf[nj], acc[mi][nj], 0, 0, 0);
        __syncthreads();
    }

    _Float16* eb = &As[0][0];
    const int g = lane >> 4;
#pragma unroll
    for (int p = 0; p < 2; p++) {
        if (p) __syncthreads();
        if ((wr >> 1) == p) {
#pragma unroll
            for (int nj = 0; nj < 4; nj++) {
                int col = wc * 64 + nj * 16 + (lane & 15);
                float bv = bias ? bias[n0 + col] : 0.f;
#pragma unroll
                for (int mi = 0; mi < 4; mi++)
#pragma unroll
                    for (int r = 0; r < 4; r++) {
                        int lr = (wr & 1) * 64 + mi * 16 + g * 4 + r;
                        float v = acc[mi][nj][r] + bv;
                        if (MODE == 0) {
                            if (ACT == 1) v = v > 0.f ? v : 0.01f * v;
                            else if (ACT == 2) v = fmaxf(v, 0.f);
                        }
                        eb[lr * 128 + col] = (_Float16)v;
                    }
            }
        }
        __syncthreads();
        int t4 = tid * 4;
        int lr = t4 >> 4;
        int cbase = (t4 & 15) * 8;
        int m = m0 + p * 128 + lr;
        float sq = 0.f;
        if (m < M) {
#pragma unroll
            for (int q = 0; q < 4; q++) {
                int c0 = cbase + q * 8;
                f16x8 hv = *(f16x8*)(eb + lr * 128 + c0);
                size_t gidx = (size_t)m * Nout + n0 + c0;
                if (MODE == 1) {
                    f16x8 old = *(f16x8*)(Yh + gidx);
                    f16x8 nw;
#pragma unroll
                    for (int e = 0; e < 8; e++) {
                        float s = (float)old[e] + (float)hv[e];
                        nw[e] = (_Float16)s;
                    }
                    *(f16x8*)(Yh + gidx) = nw;
                    hv = nw;
                } else {
                    *(f16x8*)(Yh + gidx) = hv;
                }
                if (SQ) {
#pragma unroll
                    for (int e = 0; e < 8; e++) { float f = (float)hv[e]; sq += f * f; }
                }
            }
        }
        if (SQ) {
            sq += __shfl_xor(sq, 1);
            sq += __shfl_xor(sq, 2);
            if ((lane & 3) == 0 && m < M) Psq4[(size_t)m * 4 + (n0 >> 7)] = sq;
        }
    }
}

// ---------------- P-projection GEMM: fp32 A read directly, converted during reg-staging ----------------
// out = leaky(A32 @ B^T + bias) -> Yh f16 ; Psq4 partials. 256x128 tile, 8 waves.
__global__ __launch_bounds__(512)
void pgemm32(const float* __restrict__ A32, const _Float16* __restrict__ B,
             const float* __restrict__ bias, _Float16* __restrict__ Yh,
             float* __restrict__ Psq4, int M, int K, int Nout)
{
    __shared__ _Float16 As[2][TBM * TBK];
    __shared__ _Float16 Bs[2][TBN * TBK];
    const int tid = threadIdx.x;
    const int lane = tid & 63;
    const int wid = tid >> 6;
    const int wr = wid >> 1, wc = wid & 1;

    int bid = xcd_swz(blockIdx.y * gridDim.x + blockIdx.x, gridDim.x * gridDim.y);
    const int m0 = (bid / gridDim.x) * TBM;
    const int n0 = (bid % gridDim.x) * TBN;

    f32x4 acc[4][4] = {};
    const int nt = K / TBK;

    const int lrow = lane >> 2;
    const int lk = (lane & 3) * 8;

    auto stage = [&](int t, int buf) {
        const int k0 = t * TBK;
        // A: fp32 load + convert + 16B LDS write (same layout as gll path)
#pragma unroll
        for (int q = 0; q < 2; q++) {
            int c = wid * 2 + q;
            int r = c * 16 + lrow;
            int am = min(m0 + r, M - 1);
            const float* src = A32 + (size_t)am * K + k0 + lk;
            float4 a0 = *(const float4*)src;
            float4 a1 = *(const float4*)(src + 4);
            f16x8 h;
            h[0] = (_Float16)a0.x; h[1] = (_Float16)a0.y; h[2] = (_Float16)a0.z; h[3] = (_Float16)a0.w;
            h[4] = (_Float16)a1.x; h[5] = (_Float16)a1.y; h[6] = (_Float16)a1.z; h[7] = (_Float16)a1.w;
            *(f16x8*)(&As[buf][c * 512 + lane * 8]) = h;
        }
        {
            int c = wid;
            int r = c * 16 + lrow;
            int bn = min(n0 + r, Nout - 1);
            gll16(B + (size_t)bn * K + k0 + lk, &Bs[buf][c * 512]);
        }
    };

    stage(0, 0);
    __syncthreads();
    for (int t = 0; t < nt; ++t) {
        const int cur = t & 1;
        if (t + 1 < nt) stage(t + 1, cur ^ 1);
        f16x8 af[4], bf[4];
#pragma unroll
        for (int mi = 0; mi < 4; mi++)
            af[mi] = *(const f16x8*)(&As[cur][(wr * 64 + mi * 16 + (lane & 15)) * TBK + (lane >> 4) * 8]);
#pragma unroll
        for (int nj = 0; nj < 4; nj++)
            bf[nj] = *(const f16x8*)(&Bs[cur][(wc * 64 + nj * 16 + (lane & 15)) * TBK + (lane >> 4) * 8]);
#pragma unroll
        for (int mi = 0; mi < 4; mi++)
#pragma unroll
            for (int nj = 0; nj < 4; nj++)
                acc[mi][nj] = __builtin_amdgcn_mfma_f32_16x16x32_f16(af[mi], bf[nj], acc[mi][nj], 0, 0, 0);
        __syncthreads();
    }

    _Float16* eb = &As[0][0];
    const int g = lane >> 4;
#pragma unroll
    for (int p = 0; p < 2; p++) {
        if (p) __syncthreads();
        if ((wr >> 1) == p) {
#pragma unroll
            for (int nj = 0; nj < 4; nj++) {
                int col = wc * 64 + nj * 16 + (lane & 15);
                float bv = bias[n0 + col];
#pragma unroll
                for (int mi = 0; mi < 4; mi++)
#pragma unroll
                    for (int r = 0; r < 4; r++) {
                        int lr = (wr & 1) * 64 + mi * 16 + g * 4 + r;
                        float v = acc[mi][nj][r] + bv;
                        v = v > 0.f ? v : 0.01f * v;
                        eb[lr * 128 + col] = (_Float16)v;
                    }
            }
        }
        __syncthreads();
        int t4 = tid * 4;
        int lr = t4 >> 4;
        int cbase = (t4 & 15) * 8;
        int m = m0 + p * 128 + lr;
        float sq = 0.f;
        if (m < M) {
#pragma unroll
            for (int q = 0; q < 4; q++) {
                int c0 = cbase + q * 8;
                f16x8 hv = *(f16x8*)(eb + lr * 128 + c0);
                *(f16x8*)(Yh + (size_t)m * Nout + n0 + c0) = hv;
#pragma unroll
                for (int e = 0; e < 8; e++) { float f = (float)hv[e]; sq += f * f; }
            }
        }
        sq += __shfl_xor(sq, 1);
        sq += __shfl_xor(sq, 2);
        if ((lane & 3) == 0 && m < M) Psq4[(size_t)m * 4 + (n0 >> 7)] = sq;
    }
}

// ---------------- fused ctx GEMM + LN(P+ctx) -> Ph ----------------
__global__ __launch_bounds__(512)
void ctxln_k(const _Float16* __restrict__ A, const _Float16* __restrict__ CT,
             const float* __restrict__ g, const float* __restrict__ b,
             _Float16* __restrict__ Ph, int M, int Kin)
{
    __shared__ _Float16 As[2][128 * TBK];
    __shared__ _Float16 Bs[2][512 * TBK];
    const int tid = threadIdx.x;
    const int lane = tid & 63;
    const int wid = tid >> 6;
    const int wr = wid >> 2, wc = wid & 3;
    const int m0 = blockIdx.y * 128;

    f32x4 acc[4][8] = {};
    const int nt = Kin / TBK;

    const int lrow = lane >> 2;
    const int lk = (lane & 3) * 8;

    auto stage = [&](int t, int buf) {
        const int k0 = t * TBK;
        {
            int r = wid * 16 + lrow;
            gll16(A + (size_t)(m0 + r) * Kin + k0 + lk, &As[buf][wid * 512]);
        }
#pragma unroll
        for (int q = 0; q < 4; q++) {
            int c = wid * 4 + q;
            int n = c * 16 + lrow;
            gll16(CT + (size_t)n * Kin + k0 + lk, &Bs[buf][c * 512]);
        }
    };

    stage(0, 0);
    __syncthreads();
    for (int t = 0; t < nt; ++t) {
        const int cur = t & 1;
        if (t + 1 < nt) stage(t + 1, cur ^ 1);
        f16x8 af[4], bf[8];
#pragma unroll
        for (int mi = 0; mi < 4; mi++)
            af[mi] = *(const f16x8*)(&As[cur][(wr * 64 + mi * 16 + (lane & 15)) * TBK + (lane >> 4) * 8]);
#pragma unroll
        for (int nj = 0; nj < 8; nj++)
            bf[nj] = *(const f16x8*)(&Bs[cur][(wc * 128 + nj * 16 + (lane & 15)) * TBK + (lane >> 4) * 8]);
#pragma unroll
        for (int mi = 0; mi < 4; mi++)
#pragma unroll
            for (int nj = 0; nj < 8; nj++)
                acc[mi][nj] = __builtin_amdgcn_mfma_f32_16x16x32_f16(af[mi], bf[nj], acc[mi][nj], 0, 0, 0);
        __syncthreads();
    }

    _Float16* eb = &Bs[0][0];
    const int gq = lane >> 4;
#pragma unroll
    for (int p = 0; p < 2; p++) {
        if (p) __syncthreads();
        if (wr == p) {
#pragma unroll
            for (int nj = 0; nj < 8; nj++) {
                int col = wc * 128 + nj * 16 + (lane & 15);
#pragma unroll
                for (int mi = 0; mi < 4; mi++)
#pragma unroll
                    for (int r = 0; r < 4; r++) {
                        int lr = mi * 16 + gq * 4 + r;
                        eb[lr * 512 + col] = (_Float16)acc[mi][nj][r];
                    }
            }
        }
        __syncthreads();
#pragma unroll
        for (int rr = 0; rr < 8; rr++) {
            int lr = wid * 8 + rr;
            int m = m0 + p * 64 + lr;
            f16x8 cv = *(f16x8*)(eb + lr * 512 + lane * 8);
            f16x8 pv = *(const f16x8*)(Ph + (size_t)m * 512 + lane * 8);
            float v[8];
            float s = 0.f, ss = 0.f;
#pragma unroll
            for (int q = 0; q < 8; q++) {
                v[q] = (float)pv[q] + (float)cv[q];
                s += v[q]; ss += v[q] * v[q];
            }
#pragma unroll
            for (int o = 32; o; o >>= 1) { s += __shfl_xor(s, o); ss += __shfl_xor(ss, o); }
            float mean = s * (1.f / 512.f);
            float var = ss * (1.f / 512.f) - mean * mean;
            float inv = 1.f / sqrtf(var + 1e-5f);
            int d0 = lane * 8;
            f16x8 o8;
#pragma unroll
            for (int q = 0; q < 8; q++)
                o8[q] = (_Float16)((v[q] - mean) * inv * g[d0 + q] + b[d0 + q]);
            *(f16x8*)(Ph + (size_t)m * 512 + d0) = o8;
        }
    }
}

// ---------------- fused proc GEMM + relu + LN -> Zh ----------------
__global__ __launch_bounds__(512)
void procln_k(const _Float16* __restrict__ A, const _Float16* __restrict__ W,
              const float* __restrict__ bias, const float* __restrict__ g,
              const float* __restrict__ b, _Float16* __restrict__ Zh, int M)
{
    __shared__ _Float16 As[2][128 * TBK];
    __shared__ _Float16 Bs[2][512 * TBK];
    const int tid = threadIdx.x;
    const int lane = tid & 63;
    const int wid = tid >> 6;
    const int wr = wid >> 2, wc = wid & 3;
    const int m0 = blockIdx.y * 128;
    const int K = 512;

    f32x4 acc[4][8] = {};
    const int nt = K / TBK;

    const int lrow = lane >> 2;
    const int lk = (lane & 3) * 8;

    auto stage = [&](int t, int buf) {
        const int k0 = t * TBK;
        {
            int r = wid * 16 + lrow;
            gll16(A + (size_t)(m0 + r) * K + k0 + lk, &As[buf][wid * 512]);
        }
#pragma unroll
        for (int q = 0; q < 4; q++) {
            int c = wid * 4 + q;
            int n = c * 16 + lrow;
            gll16(W + (size_t)n * K + k0 + lk, &Bs[buf][c * 512]);
        }
    };

    stage(0, 0);
    __syncthreads();
    for (int t = 0; t < nt; ++t) {
        const int cur = t & 1;
        if (t + 1 < nt) stage(t + 1, cur ^ 1);
        f16x8 af[4], bf[8];
#pragma unroll
        for (int mi = 0; mi < 4; mi++)
            af[mi] = *(const f16x8*)(&As[cur][(wr * 64 + mi * 16 + (lane & 15)) * TBK + (lane >> 4) * 8]);
#pragma unroll
        for (int nj = 0; nj < 8; nj++)
            bf[nj] = *(const f16x8*)(&Bs[cur][(wc * 128 + nj * 16 + (lane & 15)) * TBK + (lane >> 4) * 8]);
#pragma unroll
        for (int mi = 0; mi < 4; mi++)
#pragma unroll
            for (int nj = 0; nj < 8; nj++)
                acc[mi][nj] = __builtin_amdgcn_mfma_f32_16x16x32_f16(af[mi], bf[nj], acc[mi][nj], 0, 0, 0);
        __syncthreads();
    }

    _Float16* eb = &Bs[0][0];
    const int gq = lane >> 4;
#pragma unroll
    for (int p = 0; p < 2; p++) {
        if (p) __syncthreads();
        if (wr == p) {
#pragma unroll
            for (int nj = 0; nj < 8; nj++) {
                int col = wc * 128 + nj * 16 + (lane & 15);
                float bv = bias[col];
#pragma unroll
                for (int mi = 0; mi < 4; mi++)
#pragma unroll
                    for (int r = 0; r < 4; r++) {
                        int lr = mi * 16 + gq * 4 + r;
                        eb[lr * 512 + col] = (_Float16)fmaxf(acc[mi][nj][r] + bv, 0.f);
                    }
            }
        }
        __syncthreads();
#pragma unroll
        for (int rr = 0; rr < 8; rr++) {
            int lr = wid * 8 + rr;
            int m = m0 + p * 64 + lr;
            f16x8 cv = *(f16x8*)(eb + lr * 512 + lane * 8);
            float v[8];
            float s = 0.f, ss = 0.f;
#pragma unroll
            for (int q = 0; q < 8; q++) {
                v[q] = (float)cv[q];
                s += v[q]; ss += v[q] * v[q];
            }
#pragma unroll
            for (int o = 32; o; o >>= 1) { s += __shfl_xor(s, o); ss += __shfl_xor(ss, o); }
            float mean = s * (1.f / 512.f);
            float var = ss * (1.f / 512.f) - mean * mean;
            float inv = 1.f / sqrtf(var + 1e-5f);
            int d0 = lane * 8;
            f16x8 o8;
#pragma unroll
            for (int q = 0; q < 8; q++)
                o8[q] = (_Float16)((v[q] - mean) * inv * g[d0 + q] + b[d0 + q]);
            *(f16x8*)(Zh + (size_t)m * 512 + d0) = o8;
        }
    }
}

// ---------------- fused gate + attention-score GEMM (per-col-block partials, no atomics) ----------------
__global__ __launch_bounds__(512)
void gatgemm(const _Float16* __restrict__ A, const _Float16* __restrict__ B1,
             const _Float16* __restrict__ B2, const float* __restrict__ c1,
             const float* __restrict__ c2, const float* __restrict__ Ws,
             float* __restrict__ scr4, int M, int K, int Nout)
{
    __shared__ _Float16 As[2][TBM * TBK];
    __shared__ _Float16 B1s[2][TBN * TBK];
    __shared__ _Float16 B2s[2][TBN * TBK];
    const int tid = threadIdx.x;
    const int lane = tid & 63;
    const int wid = tid >> 6;
    const int wr = wid >> 1, wc = wid & 1;

    int bid = xcd_swz(blockIdx.y * gridDim.x + blockIdx.x, gridDim.x * gridDim.y);
    const int m0 = (bid / gridDim.x) * TBM;
    const int n0 = (bid % gridDim.x) * TBN;

    f32x4 acc1[4][4] = {};
    f32x4 acc2[4][4] = {};
    const int nt = K / TBK;

    const int lrow = lane >> 2;
    const int lk = (lane & 3) * 8;

    auto stage = [&](int t, int buf) {
        const int k0 = t * TBK;
#pragma unroll
        for (int q = 0; q < 2; q++) {
            int c = wid * 2 + q;
            int r = c * 16 + lrow;
            int am = min(m0 + r, M - 1);
            gll16(A + (size_t)am * K + k0 + lk, &As[buf][c * 512]);
        }
        {
            int c = wid;
            int r = c * 16 + lrow;
            int bn = min(n0 + r, Nout - 1);
            gll16(B1 + (size_t)bn * K + k0 + lk, &B1s[buf][c * 512]);
            gll16(B2 + (size_t)bn * K + k0 + lk, &B2s[buf][c * 512]);
        }
    };

    stage(0, 0);
    __syncthreads();
    for (int t = 0; t < nt; ++t) {
        const int cur = t & 1;
        if (t + 1 < nt) stage(t + 1, cur ^ 1);
        f16x8 af[4], bf1[4], bf2[4];
#pragma unroll
        for (int mi = 0; mi < 4; mi++)
            af[mi] = *(const f16x8*)(&As[cur][(wr * 64 + mi * 16 + (lane & 15)) * TBK + (lane >> 4) * 8]);
#pragma unroll
        for (int nj = 0; nj < 4; nj++) {
            int ro = (wc * 64 + nj * 16 + (lane & 15)) * TBK + (lane >> 4) * 8;
            bf1[nj] = *(const f16x8*)(&B1s[cur][ro]);
            bf2[nj] = *(const f16x8*)(&B2s[cur][ro]);
        }
#pragma unroll
        for (int mi = 0; mi < 4; mi++)
#pragma unroll
            for (int nj = 0; nj < 4; nj++) {
                acc1[mi][nj] = __builtin_amdgcn_mfma_f32_16x16x32_f16(af[mi], bf1[nj], acc1[mi][nj], 0, 0, 0);
                acc2[mi][nj] = __builtin_amdgcn_mfma_f32_16x16x32_f16(af[mi], bf2[nj], acc2[mi][nj], 0, 0, 0);
            }
        __syncthreads();
    }

    const int g = lane >> 4;
    float wsv[4];
#pragma unroll
    for (int nj = 0; nj < 4; nj++)
        wsv[nj] = Ws[n0 + wc * 64 + nj * 16 + (lane & 15)];
#pragma unroll
    for (int mi = 0; mi < 4; mi++) {
#pragma unroll
        for (int r = 0; r < 4; r++) {
            float p = 0.f;
#pragma unroll
            for (int nj = 0; nj < 4; nj++) {
                int col = n0 + wc * 64 + nj * 16 + (lane & 15);
                float t1 = ftanh(acc1[mi][nj][r] + c1[col]);
                float g1 = fsigmoid(acc2[mi][nj][r] + c2[col]);
                p += t1 * g1 * wsv[nj];
            }
#pragma unroll
            for (int o = 1; o < 16; o <<= 1) p += __shfl_xor(p, o);
            if ((lane & 15) == 0) {
                int m = m0 + wr * 64 + mi * 16 + g * 4 + r;
                if (m < M) scr4[(size_t)m * 4 + (n0 >> 7)] = p;
            }
        }
    }
}

// ---------------- fused sim GEMM + row softmax, Kin=128: 128-row blocks, 4 waves ----------------
#define SBM 128
__global__ __launch_bounds__(256)
void simgemm(const _Float16* __restrict__ A, const _Float16* __restrict__ B,
             const float* __restrict__ Psq4, const float* __restrict__ Csq2,
             const float* __restrict__ sscale, _Float16* __restrict__ Ah,
             int M, int K)
{
    const int Kin = 128;
    __shared__ _Float16 As[2][SBM * TBK];
    __shared__ _Float16 Bs[2][SBM * TBK];
    __shared__ float redmx[2][SBM];
    __shared__ float redsm[2][SBM];
    const int tid = threadIdx.x;
    const int lane = tid & 63;
    const int wid = tid >> 6;
    const int wr = wid >> 1, wc = wid & 1;
    const int m0 = blockIdx.y * SBM;

    f32x4 acc[4][4] = {};
    const int nt = K / TBK;
    const int lrow = lane >> 2;
    const int lk = (lane & 3) * 8;

    auto stage = [&](int t, int buf) {
        const int k0 = t * TBK;
#pragma unroll
        for (int q = 0; q < 2; q++) {
            int c = wid * 2 + q;
            int r = c * 16 + lrow;
            gll16(A + (size_t)(m0 + r) * K + k0 + lk, &As[buf][c * 512]);
            gll16(B + (size_t)r * K + k0 + lk, &Bs[buf][c * 512]);
        }
    };

    stage(0, 0);
    __syncthreads();
    for (int t = 0; t < nt; ++t) {
        const int cur = t & 1;
        if (t + 1 < nt) stage(t + 1, cur ^ 1);
        f16x8 af[4], bf[4];
#pragma unroll
        for (int mi = 0; mi < 4; mi++)
            af[mi] = *(const f16x8*)(&As[cur][(wr * 64 + mi * 16 + (lane & 15)) * TBK + (lane >> 4) * 8]);
#pragma unroll
        for (int nj = 0; nj < 4; nj++)
            bf[nj] = *(const f16x8*)(&Bs[cur][(wc * 64 + nj * 16 + (lane & 15)) * TBK + (lane >> 4) * 8]);
#pragma unroll
        for (int mi = 0; mi < 4; mi++)
#pragma unroll
            for (int nj = 0; nj < 4; nj++)
                acc[mi][nj] = __builtin_amdgcn_mfma_f32_16x16x32_f16(af[mi], bf[nj], acc[mi][nj], 0, 0, 0);
        __syncthreads();
    }

    const float denom = fmaxf(1e-6f, sscale[0]);
    const int colbase = wc * 64 + (lane & 15);
    const int g = lane >> 4;
    float cc[4];
#pragma unroll
    for (int nj = 0; nj < 4; nj++) {
        int n = colbase + nj * 16;
        cc[nj] = Csq2[n * 2] + Csq2[n * 2 + 1];
    }

#pragma unroll
    for (int mi = 0; mi < 4; mi++) {
#pragma unroll
        for (int r = 0; r < 4; r++) {
            int row = wr * 64 + mi * 16 + g * 4 + r;
            float4 pq = *(const float4*)(Psq4 + (size_t)(m0 + row) * 4);
            float pp = (pq.x + pq.y) + (pq.z + pq.w);
            float mx = -INFINITY;
#pragma unroll
            for (int nj = 0; nj < 4; nj++) {
                float v = -sqrtf(fmaxf(pp + cc[nj] - 2.f * acc[mi][nj][r], 1e-12f)) / denom;
                acc[mi][nj][r] = v;
                mx = fmaxf(mx, v);
            }
#pragma unroll
            for (int o = 1; o < 16; o <<= 1) mx = fmaxf(mx, __shfl_xor(mx, o));
            if ((lane & 15) == 0) redmx[wc][row] = mx;
        }
    }
    __syncthreads();

#pragma unroll
    for (int mi = 0; mi < 4; mi++) {
#pragma unroll
        for (int r = 0; r < 4; r++) {
            int row = wr * 64 + mi * 16 + g * 4 + r;
            float mx = fmaxf(redmx[0][row], redmx[1][row]);
            float s = 0.f;
#pragma unroll
            for (int nj = 0; nj < 4; nj++) {
                float e = __expf(acc[mi][nj][r] - mx);
                acc[mi][nj][r] = e;
                s += e;
            }
#pragma unroll
            for (int o = 1; o < 16; o <<= 1) s += __shfl_xor(s, o);
            if ((lane & 15) == 0) redsm[wc][row] = s;
        }
    }
    __syncthreads();

#pragma unroll
    for (int mi = 0; mi < 4; mi++) {
#pragma unroll
        for (int r = 0; r < 4; r++) {
            int row = wr * 64 + mi * 16 + g * 4 + r;
            float inv = __builtin_amdgcn_rcpf(redsm[0][row] + redsm[1][row]);
            int m = m0 + row;
#pragma unroll
            for (int nj = 0; nj < 4; nj++)
                Ah[(size_t)m * Kin + colbase + nj * 16] = (_Float16)(acc[mi][nj][r] * inv);
        }
    }
}

// ---------------- fused sim GEMM + row softmax, KIN<=64: 256-row blocks, 4 waves ----------------
template<int KIN>
__global__ __launch_bounds__(256)
void simgemm_s(const _Float16* __restrict__ A, const _Float16* __restrict__ B,
               const float* __restrict__ Psq4, const float* __restrict__ Csq2,
               const float* __restrict__ sscale, _Float16* __restrict__ Ah,
               int M, int K)
{
    constexpr int NB = KIN / 16;
    __shared__ _Float16 As[2][256 * TBK];
    __shared__ _Float16 Bs[2][KIN * TBK];
    const int tid = threadIdx.x;
    const int lane = tid & 63;
    const int wid = tid >> 6;
    const int m0 = blockIdx.y * 256;

    f32x4 acc[4][NB] = {};
    const int nt = K / TBK;
    const int lrow = lane >> 2;
    const int lk = (lane & 3) * 8;

    auto stage = [&](int t, int buf) {
        const int k0 = t * TBK;
#pragma unroll
        for (int q = 0; q < 4; q++) {
            int c = wid * 4 + q;
            int r = c * 16 + lrow;
            gll16(A + (size_t)(m0 + r) * K + k0 + lk, &As[buf][c * 512]);
        }
        if (wid < NB) {
            int r = wid * 16 + lrow;
            gll16(B + (size_t)r * K + k0 + lk, &Bs[buf][wid * 512]);
        }
    };

    stage(0, 0);
    __syncthreads();
    for (int t = 0; t < nt; ++t) {
        const int cur = t & 1;
        if (t + 1 < nt) stage(t + 1, cur ^ 1);
        f16x8 af[4], bf[NB];
#pragma unroll
        for (int mi = 0; mi < 4; mi++)
            af[mi] = *(const f16x8*)(&As[cur][(wid * 64 + mi * 16 + (lane & 15)) * TBK + (lane >> 4) * 8]);
#pragma unroll
        for (int nj = 0; nj < NB; nj++)
            bf[nj] = *(const f16x8*)(&Bs[cur][(nj * 16 + (lane & 15)) * TBK + (lane >> 4) * 8]);
#pragma unroll
        for (int mi = 0; mi < 4; mi++)
#pragma unroll
            for (int nj = 0; nj < NB; nj++)
                acc[mi][nj] = __builtin_amdgcn_mfma_f32_16x16x32_f16(af[mi], bf[nj], acc[mi][nj], 0, 0, 0);
        __syncthreads();
    }

    const float denom = fmaxf(1e-6f, sscale[0]);
    const int g = lane >> 4;
    float cc[NB];
#pragma unroll
    for (int nj = 0; nj < NB; nj++) {
        int n = nj * 16 + (lane & 15);
        cc[nj] = Csq2[n * 2] + Csq2[n * 2 + 1];
    }

#pragma unroll
    for (int mi = 0; mi < 4; mi++) {
#pragma unroll
        for (int r = 0; r < 4; r++) {
            int m = m0 + wid * 64 + mi * 16 + g * 4 + r;
            float4 pq = *(const float4*)(Psq4 + (size_t)m * 4);
            float pp = (pq.x + pq.y) + (pq.z + pq.w);
            float vv[NB];
            float mx = -INFINITY;
#pragma unroll
            for (int nj = 0; nj < NB; nj++) {
                float v = -sqrtf(fmaxf(pp + cc[nj] - 2.f * acc[mi][nj][r], 1e-12f)) / denom;
                vv[nj] = v;
                mx = fmaxf(mx, v);
            }
#pragma unroll
            for (int o = 1; o < 16; o <<= 1) mx = fmaxf(mx, __shfl_xor(mx, o));
            float s = 0.f;
#pragma unroll
            for (int nj = 0; nj < NB; nj++) { float e = __expf(vv[nj] - mx); vv[nj] = e; s += e; }
#pragma unroll
            for (int o = 1; o < 16; o <<= 1) s += __shfl_xor(s, o);
            float inv = __builtin_amdgcn_rcpf(s);
#pragma unroll
            for (int nj = 0; nj < NB; nj++)
                Ah[(size_t)m * KIN + nj * 16 + (lane & 15)] = (_Float16)(vv[nj] * inv);
        }
    }
}

// ---------------- small kernels (f16 activations) ----------------
__global__ __launch_bounds__(256)
void ln_k(const _Float16* __restrict__ X, const _Float16* __restrict__ R,
          const float* __restrict__ g, const float* __restrict__ b,
          _Float16* __restrict__ Yh, int M)
{
    int wid = threadIdx.x >> 6, lane = threadIdx.x & 63;
    int row = blockIdx.x * 4 + wid;
    if (row >= M) return;
    f16x8 a = *(const f16x8*)(X + (size_t)row * 512 + lane * 8);
    float v[8];
#pragma unroll
    for (int q = 0; q < 8; q++) v[q] = (float)a[q];
    if (R) {
        f16x8 c = *(const f16x8*)(R + (size_t)row * 512 + lane * 8);
#pragma unroll
        for (int q = 0; q < 8; q++) v[q] += (float)c[q];
    }
    float s = 0.f, ss = 0.f;
#pragma unroll
    for (int q = 0; q < 8; q++) { s += v[q]; ss += v[q] * v[q]; }
#pragma unroll
    for (int o = 32; o; o >>= 1) { s += __shfl_xor(s, o); ss += __shfl_xor(ss, o); }
    float mean = s * (1.f / 512.f);
    float var = ss * (1.f / 512.f) - mean * mean;
    float inv = 1.f / sqrtf(var + 1e-5f);
    int d0 = lane * 8;
    f16x8 o8;
#pragma unroll
    for (int q = 0; q < 8; q++)
        o8[q] = (_Float16)((v[q] - mean) * inv * g[d0 + q] + b[d0 + q]);
    *(f16x8*)(Yh + (size_t)row * 512 + d0) = o8;
}

__global__ __launch_bounds__(256)
void red1_k(const float* __restrict__ C, const float* __restrict__ w1,
            const float* __restrict__ b1, float* __restrict__ H1, int Kin)
{
    int d = blockIdx.x * 256 + threadIdx.x;
    int j = blockIdx.y;
    float acc = b1[j];
    for (int k = 0; k < Kin; k++) acc = fmaf(C[(size_t)k * 512 + d], w1[(size_t)j * Kin + k], acc);
    H1[(size_t)j * 512 + d] = fmaxf(acc, 0.f);
}

// red2 + fused f16 conversion/transpose/Csq2 emission (block-reduced, no atomics)
__global__ __launch_bounds__(256)
void red2_k(const float* __restrict__ H1, const float* __restrict__ w2,
            const float* __restrict__ b2, float* __restrict__ Cn,
            _Float16* __restrict__ Chn, _Float16* __restrict__ CThn,
            float* __restrict__ Csq2, int Kin, int Kout)
{
    __shared__ float sm[4];
    int d = blockIdx.x * 256 + threadIdx.x;
    int j2 = blockIdx.y;
    float acc = b2[j2];
    for (int j = 0; j < Kin; j++) acc = fmaf(H1[(size_t)j * 512 + d], w2[(size_t)j2 * Kin + j], acc);
    Cn[(size_t)j2 * 512 + d] = acc;
    _Float16 h = (_Float16)acc;
    Chn[(size_t)j2 * 512 + d] = h;
    CThn[(size_t)d * Kout + j2] = h;
    float f = (float)h;
    float sq = f * f;
#pragma unroll
    for (int o = 32; o; o >>= 1) sq += __shfl_xor(sq, o);
    if ((threadIdx.x & 63) == 0) sm[threadIdx.x >> 6] = sq;
    __syncthreads();
    if (threadIdx.x == 0)
        Csq2[j2 * 2 + blockIdx.x] = (sm[0] + sm[1]) + (sm[2] + sm[3]);
}

// single block: sum scr4 partials -> scr, softmax-exp in place, scal = sum(exp)
__global__ __launch_bounds__(1024)
void pool_k(const float4* __restrict__ s4, float* __restrict__ s,
            float* __restrict__ scal, int M)
{
    __shared__ float sm[16];
    int tid = threadIdx.x, lane = tid & 63, wid = tid >> 6;
    float mx = -INFINITY;
    for (int i = tid; i < M; i += 1024) {
        float4 a = s4[i];
        float v = (a.x + a.y) + (a.z + a.w);
        s[i] = v;
        mx = fmaxf(mx, v);
    }
#pragma unroll
    for (int o = 32; o; o >>= 1) mx = fmaxf(mx, __shfl_xor(mx, o));
    if (lane == 0) sm[wid] = mx;
    __syncthreads();
    if (wid == 0) {
        float v = (lane < 16) ? sm[lane] : -INFINITY;
#pragma unroll
        for (int o = 8; o; o >>= 1) v = fmaxf(v, __shfl_xor(v, o));
        if (lane == 0) sm[0] = v;
    }
    __syncthreads();
    float gmax = sm[0];
    __syncthreads();
    float sum = 0.f;
    for (int i = tid; i < M; i += 1024) {
        float e = __expf(s[i] - gmax);
        s[i] = e;
        sum += e;
    }
#pragma unroll
    for (int o = 32; o; o >>= 1) sum += __shfl_xor(sum, o);
    if (lane == 0) sm[wid] = sum;
    __syncthreads();
    if (tid == 0) {
        float t = 0.f;
        for (int w = 0; w < 16; w++) t += sm[w];
        scal[0] = t;
    }
}

__global__ __launch_bounds__(256)
void bagp_k(const _Float16* __restrict__ Z, const float* __restrict__ w,
            float* __restrict__ PB, int M, int cs)
{
    int d = blockIdx.x * 256 + threadIdx.x;
    int chunk = blockIdx.y;
    int i0 = chunk * cs;
    int i1 = min(M, i0 + cs);
    float acc = 0.f;
    for (int i = i0; i < i1; i++) acc = fmaf(w[i], (float)Z[(size_t)i * 512 + d], acc);
    PB[(size_t)chunk * 512 + d] = acc;
}

__global__ __launch_bounds__(256)
void bagf_k(const float* __restrict__ PB, const float* __restrict__ scal,
            float* __restrict__ bag, int nchunk)
{
    int d = blockIdx.x * 256 + threadIdx.x;
    float acc = 0.f;
    for (int c = 0; c < nchunk; c++) acc += PB[(size_t)c * 512 + d];
    bag[d] = acc / scal[0];
}

__global__ __launch_bounds__(256)
void h_k(const float* __restrict__ bag, const float* __restrict__ Wh,
         const float* __restrict__ bh, float* __restrict__ h)
{
    int wid = threadIdx.x >> 6, lane = threadIdx.x & 63;
    int j = blockIdx.x * 4 + wid;
    const float* wr = Wh + (size_t)j * 512;
    float d = 0.f;
#pragma unroll
    for (int t = 0; t < 2; t++) {
        float4 a = *(const float4*)(wr + t * 256 + lane * 4);
        float4 bv = *(const float4*)(bag + t * 256 + lane * 4);
        d += a.x * bv.x + a.y * bv.y + a.z * bv.z + a.w * bv.w;
    }
#pragma unroll
    for (int o = 32; o; o >>= 1) d += __shfl_xor(d, o);
    if (lane == 0) h[j] = fmaxf(d + bh[j], 0.f);
}

__global__ __launch_bounds__(128)
void logit_k(const float* __restrict__ h, const float* __restrict__ Wc,
             const float* __restrict__ bc, float* __restrict__ out)
{
    int wid = threadIdx.x >> 6, lane = threadIdx.x & 63;
    const float* wr = Wc + (size_t)wid * 512;
    float d = 0.f;
#pragma unroll
    for (int t = 0; t < 2; t++) {
        float4 a = *(const float4*)(wr + t * 256 + lane * 4);
        float4 hv = *(const float4*)(h + t * 256 + lane * 4);
        d += a.x * hv.x + a.y * hv.y + a.z * hv.z + a.w * hv.w;
    }
#pragma unroll
    for (int o = 32; o; o >>= 1) d += __shfl_xor(d, o);
    if (lane == 0) out[wid] = d + bc[wid];
}

extern "C" void kernel_launch(void* const* d_in, const int* in_sizes, int n_in,
                              void* d_out, int out_size, void* d_ws, size_t ws_size,
                              hipStream_t stream)
{
    const float* data    = (const float*)d_in[0];
    const float* protos  = (const float*)d_in[1];
    const float* W_pp    = (const float*)d_in[2];
    const float* b_pp    = (const float*)d_in[3];
    const float* W_cp    = (const float*)d_in[4];
    const float* b_cp    = (const float*)d_in[5];
    const float* sscale  = (const float*)d_in[6];
    const float* enh_w1  = (const float*)d_in[7];
    const float* enh_b1  = (const float*)d_in[8];
    const float* enh_w2  = (const float*)d_in[9];
    const float* enh_b2  = (const float*)d_in[10];
    const float* ln_g    = (const float*)d_in[11];
    const float* ln_b    = (const float*)d_in[12];
    const float* red_w1[3] = {(const float*)d_in[13], (const float*)d_in[17], (const float*)d_in[21]};
    const float* red_b1[3] = {(const float*)d_in[14], (const float*)d_in[18], (const float*)d_in[22]};
    const float* red_w2[3] = {(const float*)d_in[15], (const float*)d_in[19], (const float*)d_in[23]};
    const float* red_b2[3] = {(const float*)d_in[16], (const float*)d_in[20], (const float*)d_in[24]};
    const float* W_proc  = (const float*)d_in[25];
    const float* b_proc  = (const float*)d_in[26];
    const float* g_an    = (const float*)d_in[27];
    const float* b_an    = (const float*)d_in[28];
    const float* W_t     = (const float*)d_in[29];
    const float* b_t     = (const float*)d_in[30];
    const float* W_g     = (const float*)d_in[31];
    const float* b_g     = (const float*)d_in[32];
    const float* W_s     = (const float*)d_in[33];
    const float* b_s     = (const float*)d_in[34];  // unused: softmax shift-invariant
    const float* W_h     = (const float*)d_in[35];
    const float* b_h     = (const float*)d_in[36];
    const float* W_c     = (const float*)d_in[37];
    const float* b_c     = (const float*)d_in[38];
    float* out = (float*)d_out;
    (void)b_s;

    constexpr int N = 32768, DIN = 768, D = 512;
    constexpr int NCHUNK = 256;
    char* w = (char*)d_ws;
    auto alloc = [&](size_t bytes) -> char* {
        char* p = w; w += (bytes + 255) & ~(size_t)255; return p;
    };
    _Float16* Ph     = (_Float16*)alloc((size_t)N * D * 2);
    _Float16* TMPh   = (_Float16*)alloc((size_t)N * D * 2);
    _Float16* Zh     = (_Float16*)alloc((size_t)(N + 16) * D * 2);
    _Float16* Ztail  = (_Float16*)alloc((size_t)16 * D * 2);
    _Float16* Ah     = (_Float16*)alloc((size_t)N * 128 * 2);
    _Float16* Ch     = (_Float16*)alloc(128 * D * 2);
    _Float16* CTh    = (_Float16*)alloc(128 * D * 2);
    _Float16* Wpph   = (_Float16*)alloc((size_t)D * DIN * 2);
    _Float16* w1h    = (_Float16*)alloc((size_t)3 * D * D * 2);
    _Float16* w2h    = (_Float16*)alloc((size_t)3 * D * D * 2);
    _Float16* Wproch = (_Float16*)alloc((size_t)D * D * 2);
    _Float16* Wth    = (_Float16*)alloc((size_t)D * D * 2);
    _Float16* Wgh    = (_Float16*)alloc((size_t)D * D * 2);
    float*    Psq4   = (float*)alloc((size_t)N * 4 * 4);
    float*    Csq2   = (float*)alloc(128 * 2 * 4);
    float*    Ca     = (float*)alloc(128 * D * 4);
    float*    Cb     = (float*)alloc(128 * D * 4);
    float*    H1     = (float*)alloc(128 * D * 4);
    float*    scr4   = (float*)alloc((size_t)(N + 16) * 4 * 4);
    float*    scr    = (float*)alloc((size_t)(N + 16) * 4);
    float*    PB     = (float*)alloc((size_t)NCHUNK * D * 4);
    float*    bag    = (float*)alloc(D * 4);
    float*    hb     = (float*)alloc(D * 4);
    float*    scal   = (float*)alloc(8 * 4);

    dim3 blk(256);
    dim3 blk512(512);
    auto mgrid = [](int M_, int Nout_) { return dim3((Nout_ + TBN - 1) / TBN, (M_ + TBM - 1) / TBM); };

    // --- merged fp32->f16 conversion: weights only (data converted in pgemm32) ---
    {
        CvtSegs cs;
        const float* srcs[6] = { W_pp, enh_w1, enh_w2, W_proc, W_t, W_g };
        _Float16* dsts[6]    = { Wpph, w1h, w2h, Wproch, Wth, Wgh };
        int sizes[6] = { D * DIN, 3 * D * D, 3 * D * D, D * D, D * D, D * D };
        int c = 0;
        cs.cum4[0] = 0;
        for (int s = 0; s < 6; s++) {
            cs.src[s] = srcs[s]; cs.dst[s] = dsts[s];
            c += sizes[s] / 4;
            cs.cum4[s + 1] = c;
        }
        cvtall_k<<<dim3(2048), blk, 0, stream>>>(cs);
    }

    // P = leaky(data @ W_pp^T + b_pp) -> f16 (fp32 A read direct), Psq4 partials
    pgemm32<<<mgrid(N, D), blk512, 0, stream>>>(data, Wpph, b_pp, Ph, Psq4, N, DIN, D);
    // C0 = leaky(protos @ W_cp^T + b_cp) -> fp32, then f16 set via cvtC2
    dot_k<1, false><<<dim3(128 * 512 / 4), blk, 0, stream>>>(protos, W_cp, b_cp, Ca, 128, DIN);
    cvtC2_k<<<dim3(32), blk, 0, stream>>>(Ca, Ch, CTh, Csq2, 128);

    float* C = Ca;
    float* Cn = Cb;
    int Kin = 128;
    for (int i = 0; i < 3; i++) {
        int Kout = Kin >> 1;
        // A = softmax(-dist/denom) fused with S = P@C^T
        if (i == 0)
            simgemm<<<dim3(1, N / SBM), blk, 0, stream>>>(Ph, Ch, Psq4, Csq2, sscale, Ah, N, D);
        else if (i == 1)
            simgemm_s<64><<<dim3(1, N / 256), blk, 0, stream>>>(Ph, Ch, Psq4, Csq2, sscale, Ah, N, D);
        else
            simgemm_s<32><<<dim3(1, N / 256), blk, 0, stream>>>(Ph, Ch, Psq4, Csq2, sscale, Ah, N, D);
        // P = LN(P + A@C) fused
        ctxln_k<<<dim3(1, N / 128), blk512, 0, stream>>>(Ah, CTh, ln_g + (size_t)i * D, ln_b + (size_t)i * D, Ph, N, Kin);
        // enhancer MLP: P += w2 @ relu(w1 @ P + b1) + b2   (enh2 emits Psq4 for next iter)
        mgemm<0, 2, false><<<mgrid(N, D), blk512, 0, stream>>>(Ph, w1h + (size_t)i * D * D, enh_b1 + (size_t)i * D, TMPh, nullptr, N, D, D);
        if (i < 2)
            mgemm<1, 0, true><<<mgrid(N, D), blk512, 0, stream>>>(TMPh, w2h + (size_t)i * D * D, enh_b2 + (size_t)i * D, Ph, Psq4, N, D, D);
        else
            mgemm<1, 0, false><<<mgrid(N, D), blk512, 0, stream>>>(TMPh, w2h + (size_t)i * D * D, enh_b2 + (size_t)i * D, Ph, nullptr, N, D, D);
        // ProtoReducer; red2 emits next iteration's f16 C set + Csq2
        red1_k<<<dim3(2, Kin), blk, 0, stream>>>(C, red_w1[i], red_b1[i], H1, Kin);
        red2_k<<<dim3(2, Kout), blk, 0, stream>>>(H1, red_w2[i], red_b2[i], Cn, Ch, CTh, Csq2, Kin, Kout);
        float* t = C; C = Cn; Cn = t;
        Kin = Kout;
    }

    // Z(main) = LN(relu(P @ W_proc^T + b_proc)) fused
    procln_k<<<dim3(1, N / 128), blk512, 0, stream>>>(Ph, Wproch, b_proc, g_an, b_an, Zh, N);
    // Z(tail, 16 C rows)
    dot_k<2, true><<<dim3(16 * 512 / 4), blk, 0, stream>>>(C, W_proc, b_proc, Ztail, 16, D);
    ln_k<<<dim3(4), blk, 0, stream>>>(Ztail, nullptr, g_an, b_an, Zh + (size_t)N * D, 16);

    // scores: per-col-block partials into scr4 (no memset, no atomics)
    gatgemm<<<mgrid(N + 16, D), blk512, 0, stream>>>(Zh, Wth, Wgh, b_t, b_g, W_s, scr4, N + 16, D, D);

    // attention pooling
    pool_k<<<dim3(1), dim3(1024), 0, stream>>>((const float4*)scr4, scr, scal, N + 16);
    int cs2 = (N + 16 + NCHUNK - 1) / NCHUNK;
    bagp_k<<<dim3(2, NCHUNK), blk, 0, stream>>>(Zh, scr, PB, N + 16, cs2);
    bagf_k<<<dim3(2), blk, 0, stream>>>(PB, scal, bag, NCHUNK);

    // classifier head
    h_k<<<dim3(128), blk, 0, stream>>>(bag, W_h, b_h, hb);
    logit_k<<<dim3(1), dim3(128), 0, stream>>>(hb, W_c, b_c, out);
}

// Round 18
// 754.839 us; speedup vs baseline: 1.5663x; 1.0038x over previous
//
#include <hip/hip_runtime.h>
#include <math.h>

typedef _Float16 f16x8 __attribute__((ext_vector_type(8)));
typedef _Float16 f16x4 __attribute__((ext_vector_type(4)));
typedef float f32x4 __attribute__((ext_vector_type(4)));

#define TBM 256
#define TBN 128
#define TBK 32

#define AS1 __attribute__((address_space(1)))
#define AS3 __attribute__((address_space(3)))

__device__ __forceinline__ void gll16(const _Float16* g, _Float16* l)
{
    __builtin_amdgcn_global_load_lds((const AS1 unsigned int*)g,
                                     (AS3 unsigned int*)l, 16, 0, 0);
}

// bijective XCD chunking (m204)
__device__ __forceinline__ int xcd_swz(int d, int nwg)
{
    int q = nwg >> 3, r = nwg & 7;
    int x = d & 7, idx = d >> 3;
    int base = x < r ? x * (q + 1) : r * (q + 1) + (x - r) * q;
    return base + idx;
}

// ---- fast transcendentals ----
__device__ __forceinline__ float fsigmoid(float x)
{
    return __builtin_amdgcn_rcpf(1.f + __expf(-x));
}
__device__ __forceinline__ float ftanh(float x)
{
    float ax = fabsf(x);
    float e = __expf(-2.f * ax);
    float t = (1.f - e) * __builtin_amdgcn_rcpf(1.f + e);
    return copysignf(t, x);
}

// ---------------- merged fp32->f16 converter (weights only, 1 launch) ----------------
struct CvtSegs {
    const float* src[6];
    _Float16* dst[6];
    int cum4[7];
};

__global__ __launch_bounds__(256)
void cvtall_k(CvtSegs a)
{
    int total = a.cum4[6];
    for (int i = blockIdx.x * 256 + threadIdx.x; i < total; i += gridDim.x * 256) {
        int s = 0;
        while (i >= a.cum4[s + 1]) s++;
        int loc = (i - a.cum4[s]) * 4;
        float4 v = *(const float4*)(a.src[s] + loc);
        f16x4 h = { (_Float16)v.x, (_Float16)v.y, (_Float16)v.z, (_Float16)v.w };
        *(f16x4*)(a.dst[s] + loc) = h;
    }
}

// ---------------- wave-per-output dot kernel (small-M fp32 GEMMs) ----------------
template<int ACT, bool F16OUT>
__global__ __launch_bounds__(256)
void dot_k(const float* __restrict__ X, const float* __restrict__ W,
           const float* __restrict__ bias, void* __restrict__ Yv,
           int M, int K)
{
    int gw = (blockIdx.x * 256 + threadIdx.x) >> 6;
    int lane = threadIdx.x & 63;
    if (gw >= M * 512) return;
    int r = gw >> 9, n = gw & 511;
    const float* xr = X + (size_t)r * K;
    const float* wr = W + (size_t)n * K;
    float d = 0.f;
    for (int t = 0; t < K; t += 256) {
        float4 a = *(const float4*)(xr + t + lane * 4);
        float4 b = *(const float4*)(wr + t + lane * 4);
        d += a.x * b.x + a.y * b.y + a.z * b.z + a.w * b.w;
    }
#pragma unroll
    for (int o = 32; o; o >>= 1) d += __shfl_xor(d, o);
    if (lane == 0) {
        float v = d + bias[n];
        if (ACT == 1) v = v > 0.f ? v : 0.01f * v;
        else if (ACT == 2) v = fmaxf(v, 0.f);
        if (F16OUT) ((_Float16*)Yv)[(size_t)r * 512 + n] = (_Float16)v;
        else        ((float*)Yv)[(size_t)r * 512 + n] = v;
    }
}

// C [Kin,512] fp32 -> Ch, CTh f16 + Csq2; one wave per row
__global__ __launch_bounds__(256)
void cvtC2_k(const float* __restrict__ C, _Float16* __restrict__ Ch,
             _Float16* __restrict__ CTh, float* __restrict__ Csq2, int Kin)
{
    int w = threadIdx.x >> 6, lane = threadIdx.x & 63;
    int row = blockIdx.x * 4 + w;
    if (row >= Kin) return;
    float4 a = *(const float4*)(C + (size_t)row * 512 + lane * 8);
    float4 b = *(const float4*)(C + (size_t)row * 512 + lane * 8 + 4);
    f16x8 h;
    h[0] = (_Float16)a.x; h[1] = (_Float16)a.y; h[2] = (_Float16)a.z; h[3] = (_Float16)a.w;
    h[4] = (_Float16)b.x; h[5] = (_Float16)b.y; h[6] = (_Float16)b.z; h[7] = (_Float16)b.w;
    *(f16x8*)(Ch + (size_t)row * 512 + lane * 8) = h;
    float s = 0.f;
#pragma unroll
    for (int q = 0; q < 8; q++) {
        float f = (float)h[q];
        s += f * f;
        CTh[(size_t)(lane * 8 + q) * Kin + row] = h[q];
    }
#pragma unroll
    for (int o = 32; o; o >>= 1) s += __shfl_xor(s, o);
    if (lane == 0) { Csq2[row * 2] = s; Csq2[row * 2 + 1] = 0.f; }
}

// ---------------- P-projection GEMM: fp32 A read directly, converted during reg-staging ----------------
__global__ __launch_bounds__(512)
void pgemm32(const float* __restrict__ A32, const _Float16* __restrict__ B,
             const float* __restrict__ bias, _Float16* __restrict__ Yh,
             float* __restrict__ Psq4, int M, int K, int Nout)
{
    __shared__ _Float16 As[2][TBM * TBK];
    __shared__ _Float16 Bs[2][TBN * TBK];
    const int tid = threadIdx.x;
    const int lane = tid & 63;
    const int wid = tid >> 6;
    const int wr = wid >> 1, wc = wid & 1;

    int bid = xcd_swz(blockIdx.y * gridDim.x + blockIdx.x, gridDim.x * gridDim.y);
    const int m0 = (bid / gridDim.x) * TBM;
    const int n0 = (bid % gridDim.x) * TBN;

    f32x4 acc[4][4] = {};
    const int nt = K / TBK;

    const int lrow = lane >> 2;
    const int lk = (lane & 3) * 8;

    auto stage = [&](int t, int buf) {
        const int k0 = t * TBK;
#pragma unroll
        for (int q = 0; q < 2; q++) {
            int c = wid * 2 + q;
            int r = c * 16 + lrow;
            int am = min(m0 + r, M - 1);
            const float* src = A32 + (size_t)am * K + k0 + lk;
            float4 a0 = *(const float4*)src;
            float4 a1 = *(const float4*)(src + 4);
            f16x8 h;
            h[0] = (_Float16)a0.x; h[1] = (_Float16)a0.y; h[2] = (_Float16)a0.z; h[3] = (_Float16)a0.w;
            h[4] = (_Float16)a1.x; h[5] = (_Float16)a1.y; h[6] = (_Float16)a1.z; h[7] = (_Float16)a1.w;
            *(f16x8*)(&As[buf][c * 512 + lane * 8]) = h;
        }
        {
            int c = wid;
            int r = c * 16 + lrow;
            int bn = min(n0 + r, Nout - 1);
            gll16(B + (size_t)bn * K + k0 + lk, &Bs[buf][c * 512]);
        }
    };

    stage(0, 0);
    __syncthreads();
    for (int t = 0; t < nt; ++t) {
        const int cur = t & 1;
        if (t + 1 < nt) stage(t + 1, cur ^ 1);
        f16x8 af[4], bf[4];
#pragma unroll
        for (int mi = 0; mi < 4; mi++)
            af[mi] = *(const f16x8*)(&As[cur][(wr * 64 + mi * 16 + (lane & 15)) * TBK + (lane >> 4) * 8]);
#pragma unroll
        for (int nj = 0; nj < 4; nj++)
            bf[nj] = *(const f16x8*)(&Bs[cur][(wc * 64 + nj * 16 + (lane & 15)) * TBK + (lane >> 4) * 8]);
#pragma unroll
        for (int mi = 0; mi < 4; mi++)
#pragma unroll
            for (int nj = 0; nj < 4; nj++)
                acc[mi][nj] = __builtin_amdgcn_mfma_f32_16x16x32_f16(af[mi], bf[nj], acc[mi][nj], 0, 0, 0);
        __syncthreads();
    }

    _Float16* eb = &As[0][0];
    const int g = lane >> 4;
#pragma unroll
    for (int p = 0; p < 2; p++) {
        if (p) __syncthreads();
        if ((wr >> 1) == p) {
#pragma unroll
            for (int nj = 0; nj < 4; nj++) {
                int col = wc * 64 + nj * 16 + (lane & 15);
                float bv = bias[n0 + col];
#pragma unroll
                for (int mi = 0; mi < 4; mi++)
#pragma unroll
                    for (int r = 0; r < 4; r++) {
                        int lr = (wr & 1) * 64 + mi * 16 + g * 4 + r;
                        float v = acc[mi][nj][r] + bv;
                        v = v > 0.f ? v : 0.01f * v;
                        eb[lr * 128 + col] = (_Float16)v;
                    }
            }
        }
        __syncthreads();
        int t4 = tid * 4;
        int lr = t4 >> 4;
        int cbase = (t4 & 15) * 8;
        int m = m0 + p * 128 + lr;
        float sq = 0.f;
        if (m < M) {
#pragma unroll
            for (int q = 0; q < 4; q++) {
                int c0 = cbase + q * 8;
                f16x8 hv = *(f16x8*)(eb + lr * 128 + c0);
                *(f16x8*)(Yh + (size_t)m * Nout + n0 + c0) = hv;
#pragma unroll
                for (int e = 0; e < 8; e++) { float f = (float)hv[e]; sq += f * f; }
            }
        }
        sq += __shfl_xor(sq, 1);
        sq += __shfl_xor(sq, 2);
        if ((lane & 3) == 0 && m < M) Psq4[(size_t)m * 4 + (n0 >> 7)] = sq;
    }
}

// ---------------- enh1: TMPh = relu(A@W^T + bias), 128x512 tile, 8 waves ----------------
__global__ __launch_bounds__(512)
void enh1_k(const _Float16* __restrict__ A, const _Float16* __restrict__ W,
            const float* __restrict__ bias, _Float16* __restrict__ Y, int M)
{
    __shared__ _Float16 As[2][128 * TBK];
    __shared__ _Float16 Bs[2][512 * TBK];
    const int tid = threadIdx.x;
    const int lane = tid & 63;
    const int wid = tid >> 6;
    const int wr = wid >> 2, wc = wid & 3;
    const int m0 = blockIdx.y * 128;
    const int K = 512;

    f32x4 acc[4][8] = {};
    const int nt = K / TBK;
    const int lrow = lane >> 2;
    const int lk = (lane & 3) * 8;

    auto stage = [&](int t, int buf) {
        const int k0 = t * TBK;
        {
            int r = wid * 16 + lrow;
            gll16(A + (size_t)(m0 + r) * K + k0 + lk, &As[buf][wid * 512]);
        }
#pragma unroll
        for (int q = 0; q < 4; q++) {
            int c = wid * 4 + q;
            int n = c * 16 + lrow;
            gll16(W + (size_t)n * K + k0 + lk, &Bs[buf][c * 512]);
        }
    };

    stage(0, 0);
    __syncthreads();
    for (int t = 0; t < nt; ++t) {
        const int cur = t & 1;
        if (t + 1 < nt) stage(t + 1, cur ^ 1);
        f16x8 af[4], bf[8];
#pragma unroll
        for (int mi = 0; mi < 4; mi++)
            af[mi] = *(const f16x8*)(&As[cur][(wr * 64 + mi * 16 + (lane & 15)) * TBK + (lane >> 4) * 8]);
#pragma unroll
        for (int nj = 0; nj < 8; nj++)
            bf[nj] = *(const f16x8*)(&Bs[cur][(wc * 128 + nj * 16 + (lane & 15)) * TBK + (lane >> 4) * 8]);
#pragma unroll
        for (int mi = 0; mi < 4; mi++)
#pragma unroll
            for (int nj = 0; nj < 8; nj++)
                acc[mi][nj] = __builtin_amdgcn_mfma_f32_16x16x32_f16(af[mi], bf[nj], acc[mi][nj], 0, 0, 0);
        __syncthreads();
    }

    _Float16* eb = &Bs[0][0];
    const int gq = lane >> 4;
#pragma unroll
    for (int p = 0; p < 2; p++) {
        if (p) __syncthreads();
        if (wr == p) {
#pragma unroll
            for (int nj = 0; nj < 8; nj++) {
                int col = wc * 128 + nj * 16 + (lane & 15);
                float bv = bias[col];
#pragma unroll
                for (int mi = 0; mi < 4; mi++)
#pragma unroll
                    for (int r = 0; r < 4; r++) {
                        int lr = mi * 16 + gq * 4 + r;
                        eb[lr * 512 + col] = (_Float16)fmaxf(acc[mi][nj][r] + bv, 0.f);
                    }
            }
        }
        __syncthreads();
#pragma unroll
        for (int rr = 0; rr < 8; rr++) {
            int lr = wid * 8 + rr;
            int m = m0 + p * 64 + lr;
            f16x8 hv = *(f16x8*)(eb + lr * 512 + lane * 8);
            *(f16x8*)(Y + (size_t)m * 512 + lane * 8) = hv;
        }
    }
}

// ---------------- enh2: Ph += (A@W^T + bias), 128x512 tile; optional full-row Psq4 ----------------
template<bool SQ>
__global__ __launch_bounds__(512)
void enh2_k(const _Float16* __restrict__ A, const _Float16* __restrict__ W,
            const float* __restrict__ bias, _Float16* __restrict__ Ph,
            float* __restrict__ Psq4, int M)
{
    __shared__ _Float16 As[2][128 * TBK];
    __shared__ _Float16 Bs[2][512 * TBK];
    const int tid = threadIdx.x;
    const int lane = tid & 63;
    const int wid = tid >> 6;
    const int wr = wid >> 2, wc = wid & 3;
    const int m0 = blockIdx.y * 128;
    const int K = 512;

    f32x4 acc[4][8] = {};
    const int nt = K / TBK;
    const int lrow = lane >> 2;
    const int lk = (lane & 3) * 8;

    auto stage = [&](int t, int buf) {
        const int k0 = t * TBK;
        {
            int r = wid * 16 + lrow;
            gll16(A + (size_t)(m0 + r) * K + k0 + lk, &As[buf][wid * 512]);
        }
#pragma unroll
        for (int q = 0; q < 4; q++) {
            int c = wid * 4 + q;
            int n = c * 16 + lrow;
            gll16(W + (size_t)n * K + k0 + lk, &Bs[buf][c * 512]);
        }
    };

    stage(0, 0);
    __syncthreads();
    for (int t = 0; t < nt; ++t) {
        const int cur = t & 1;
        if (t + 1 < nt) stage(t + 1, cur ^ 1);
        f16x8 af[4], bf[8];
#pragma unroll
        for (int mi = 0; mi < 4; mi++)
            af[mi] = *(const f16x8*)(&As[cur][(wr * 64 + mi * 16 + (lane & 15)) * TBK + (lane >> 4) * 8]);
#pragma unroll
        for (int nj = 0; nj < 8; nj++)
            bf[nj] = *(const f16x8*)(&Bs[cur][(wc * 128 + nj * 16 + (lane & 15)) * TBK + (lane >> 4) * 8]);
#pragma unroll
        for (int mi = 0; mi < 4; mi++)
#pragma unroll
            for (int nj = 0; nj < 8; nj++)
                acc[mi][nj] = __builtin_amdgcn_mfma_f32_16x16x32_f16(af[mi], bf[nj], acc[mi][nj], 0, 0, 0);
        __syncthreads();
    }

    _Float16* eb = &Bs[0][0];
    const int gq = lane >> 4;
#pragma unroll
    for (int p = 0; p < 2; p++) {
        if (p) __syncthreads();
        if (wr == p) {
#pragma unroll
            for (int nj = 0; nj < 8; nj++) {
                int col = wc * 128 + nj * 16 + (lane & 15);
                float bv = bias[col];
#pragma unroll
                for (int mi = 0; mi < 4; mi++)
#pragma unroll
                    for (int r = 0; r < 4; r++) {
                        int lr = mi * 16 + gq * 4 + r;
                        eb[lr * 512 + col] = (_Float16)(acc[mi][nj][r] + bv);
                    }
            }
        }
        __syncthreads();
#pragma unroll
        for (int rr = 0; rr < 8; rr++) {
            int lr = wid * 8 + rr;
            int m = m0 + p * 64 + lr;
            f16x8 cv = *(f16x8*)(eb + lr * 512 + lane * 8);
            f16x8 pv = *(const f16x8*)(Ph + (size_t)m * 512 + lane * 8);
            f16x8 o8;
            float sq = 0.f;
#pragma unroll
            for (int q = 0; q < 8; q++) {
                float s = (float)pv[q] + (float)cv[q];
                o8[q] = (_Float16)s;
                if (SQ) { float f = (float)o8[q]; sq += f * f; }
            }
            *(f16x8*)(Ph + (size_t)m * 512 + lane * 8) = o8;
            if (SQ) {
#pragma unroll
                for (int o = 32; o; o >>= 1) sq += __shfl_xor(sq, o);
                if (lane == 0) {
                    float4 w4 = { sq, 0.f, 0.f, 0.f };
                    *(float4*)(Psq4 + (size_t)m * 4) = w4;
                }
            }
        }
    }
}

// ---------------- fused ctx GEMM + LN(P+ctx) -> Ph ----------------
__global__ __launch_bounds__(512)
void ctxln_k(const _Float16* __restrict__ A, const _Float16* __restrict__ CT,
             const float* __restrict__ g, const float* __restrict__ b,
             _Float16* __restrict__ Ph, int M, int Kin)
{
    __shared__ _Float16 As[2][128 * TBK];
    __shared__ _Float16 Bs[2][512 * TBK];
    const int tid = threadIdx.x;
    const int lane = tid & 63;
    const int wid = tid >> 6;
    const int wr = wid >> 2, wc = wid & 3;
    const int m0 = blockIdx.y * 128;

    f32x4 acc[4][8] = {};
    const int nt = Kin / TBK;
    const int lrow = lane >> 2;
    const int lk = (lane & 3) * 8;

    auto stage = [&](int t, int buf) {
        const int k0 = t * TBK;
        {
            int r = wid * 16 + lrow;
            gll16(A + (size_t)(m0 + r) * Kin + k0 + lk, &As[buf][wid * 512]);
        }
#pragma unroll
        for (int q = 0; q < 4; q++) {
            int c = wid * 4 + q;
            int n = c * 16 + lrow;
            gll16(CT + (size_t)n * Kin + k0 + lk, &Bs[buf][c * 512]);
        }
    };

    stage(0, 0);
    __syncthreads();
    for (int t = 0; t < nt; ++t) {
        const int cur = t & 1;
        if (t + 1 < nt) stage(t + 1, cur ^ 1);
        f16x8 af[4], bf[8];
#pragma unroll
        for (int mi = 0; mi < 4; mi++)
            af[mi] = *(const f16x8*)(&As[cur][(wr * 64 + mi * 16 + (lane & 15)) * TBK + (lane >> 4) * 8]);
#pragma unroll
        for (int nj = 0; nj < 8; nj++)
            bf[nj] = *(const f16x8*)(&Bs[cur][(wc * 128 + nj * 16 + (lane & 15)) * TBK + (lane >> 4) * 8]);
#pragma unroll
        for (int mi = 0; mi < 4; mi++)
#pragma unroll
            for (int nj = 0; nj < 8; nj++)
                acc[mi][nj] = __builtin_amdgcn_mfma_f32_16x16x32_f16(af[mi], bf[nj], acc[mi][nj], 0, 0, 0);
        __syncthreads();
    }

    _Float16* eb = &Bs[0][0];
    const int gq = lane >> 4;
#pragma unroll
    for (int p = 0; p < 2; p++) {
        if (p) __syncthreads();
        if (wr == p) {
#pragma unroll
            for (int nj = 0; nj < 8; nj++) {
                int col = wc * 128 + nj * 16 + (lane & 15);
#pragma unroll
                for (int mi = 0; mi < 4; mi++)
#pragma unroll
                    for (int r = 0; r < 4; r++) {
                        int lr = mi * 16 + gq * 4 + r;
                        eb[lr * 512 + col] = (_Float16)acc[mi][nj][r];
                    }
            }
        }
        __syncthreads();
#pragma unroll
        for (int rr = 0; rr < 8; rr++) {
            int lr = wid * 8 + rr;
            int m = m0 + p * 64 + lr;
            f16x8 cv = *(f16x8*)(eb + lr * 512 + lane * 8);
            f16x8 pv = *(const f16x8*)(Ph + (size_t)m * 512 + lane * 8);
            float v[8];
            float s = 0.f, ss = 0.f;
#pragma unroll
            for (int q = 0; q < 8; q++) {
                v[q] = (float)pv[q] + (float)cv[q];
                s += v[q]; ss += v[q] * v[q];
            }
#pragma unroll
            for (int o = 32; o; o >>= 1) { s += __shfl_xor(s, o); ss += __shfl_xor(ss, o); }
            float mean = s * (1.f / 512.f);
            float var = ss * (1.f / 512.f) - mean * mean;
            float inv = 1.f / sqrtf(var + 1e-5f);
            int d0 = lane * 8;
            f16x8 o8;
#pragma unroll
            for (int q = 0; q < 8; q++)
                o8[q] = (_Float16)((v[q] - mean) * inv * g[d0 + q] + b[d0 + q]);
            *(f16x8*)(Ph + (size_t)m * 512 + d0) = o8;
        }
    }
}

// ---------------- fused proc GEMM + relu + LN -> Zh ----------------
__global__ __launch_bounds__(512)
void procln_k(const _Float16* __restrict__ A, const _Float16* __restrict__ W,
              const float* __restrict__ bias, const float* __restrict__ g,
              const float* __restrict__ b, _Float16* __restrict__ Zh, int M)
{
    __shared__ _Float16 As[2][128 * TBK];
    __shared__ _Float16 Bs[2][512 * TBK];
    const int tid = threadIdx.x;
    const int lane = tid & 63;
    const int wid = tid >> 6;
    const int wr = wid >> 2, wc = wid & 3;
    const int m0 = blockIdx.y * 128;
    const int K = 512;

    f32x4 acc[4][8] = {};
    const int nt = K / TBK;
    const int lrow = lane >> 2;
    const int lk = (lane & 3) * 8;

    auto stage = [&](int t, int buf) {
        const int k0 = t * TBK;
        {
            int r = wid * 16 + lrow;
            gll16(A + (size_t)(m0 + r) * K + k0 + lk, &As[buf][wid * 512]);
        }
#pragma unroll
        for (int q = 0; q < 4; q++) {
            int c = wid * 4 + q;
            int n = c * 16 + lrow;
            gll16(W + (size_t)n * K + k0 + lk, &Bs[buf][c * 512]);
        }
    };

    stage(0, 0);
    __syncthreads();
    for (int t = 0; t < nt; ++t) {
        const int cur = t & 1;
        if (t + 1 < nt) stage(t + 1, cur ^ 1);
        f16x8 af[4], bf[8];
#pragma unroll
        for (int mi = 0; mi < 4; mi++)
            af[mi] = *(const f16x8*)(&As[cur][(wr * 64 + mi * 16 + (lane & 15)) * TBK + (lane >> 4) * 8]);
#pragma unroll
        for (int nj = 0; nj < 8; nj++)
            bf[nj] = *(const f16x8*)(&Bs[cur][(wc * 128 + nj * 16 + (lane & 15)) * TBK + (lane >> 4) * 8]);
#pragma unroll
        for (int mi = 0; mi < 4; mi++)
#pragma unroll
            for (int nj = 0; nj < 8; nj++)
                acc[mi][nj] = __builtin_amdgcn_mfma_f32_16x16x32_f16(af[mi], bf[nj], acc[mi][nj], 0, 0, 0);
        __syncthreads();
    }

    _Float16* eb = &Bs[0][0];
    const int gq = lane >> 4;
#pragma unroll
    for (int p = 0; p < 2; p++) {
        if (p) __syncthreads();
        if (wr == p) {
#pragma unroll
            for (int nj = 0; nj < 8; nj++) {
                int col = wc * 128 + nj * 16 + (lane & 15);
                float bv = bias[col];
#pragma unroll
                for (int mi = 0; mi < 4; mi++)
#pragma unroll
                    for (int r = 0; r < 4; r++) {
                        int lr = mi * 16 + gq * 4 + r;
                        eb[lr * 512 + col] = (_Float16)fmaxf(acc[mi][nj][r] + bv, 0.f);
                    }
            }
        }
        __syncthreads();
#pragma unroll
        for (int rr = 0; rr < 8; rr++) {
            int lr = wid * 8 + rr;
            int m = m0 + p * 64 + lr;
            f16x8 cv = *(f16x8*)(eb + lr * 512 + lane * 8);
            float v[8];
            float s = 0.f, ss = 0.f;
#pragma unroll
            for (int q = 0; q < 8; q++) {
                v[q] = (float)cv[q];
                s += v[q]; ss += v[q] * v[q];
            }
#pragma unroll
            for (int o = 32; o; o >>= 1) { s += __shfl_xor(s, o); ss += __shfl_xor(ss, o); }
            float mean = s * (1.f / 512.f);
            float var = ss * (1.f / 512.f) - mean * mean;
            float inv = 1.f / sqrtf(var + 1e-5f);
            int d0 = lane * 8;
            f16x8 o8;
#pragma unroll
            for (int q = 0; q < 8; q++)
                o8[q] = (_Float16)((v[q] - mean) * inv * g[d0 + q] + b[d0 + q]);
            *(f16x8*)(Zh + (size_t)m * 512 + d0) = o8;
        }
    }
}

// ---------------- fused gate + attention-score GEMM (per-col-block partials) ----------------
__global__ __launch_bounds__(512)
void gatgemm(const _Float16* __restrict__ A, const _Float16* __restrict__ B1,
             const _Float16* __restrict__ B2, const float* __restrict__ c1,
             const float* __restrict__ c2, const float* __restrict__ Ws,
             float* __restrict__ scr4, int M, int K, int Nout)
{
    __shared__ _Float16 As[2][TBM * TBK];
    __shared__ _Float16 B1s[2][TBN * TBK];
    __shared__ _Float16 B2s[2][TBN * TBK];
    const int tid = threadIdx.x;
    const int lane = tid & 63;
    const int wid = tid >> 6;
    const int wr = wid >> 1, wc = wid & 1;

    int bid = xcd_swz(blockIdx.y * gridDim.x + blockIdx.x, gridDim.x * gridDim.y);
    const int m0 = (bid / gridDim.x) * TBM;
    const int n0 = (bid % gridDim.x) * TBN;

    f32x4 acc1[4][4] = {};
    f32x4 acc2[4][4] = {};
    const int nt = K / TBK;

    const int lrow = lane >> 2;
    const int lk = (lane & 3) * 8;

    auto stage = [&](int t, int buf) {
        const int k0 = t * TBK;
#pragma unroll
        for (int q = 0; q < 2; q++) {
            int c = wid * 2 + q;
            int r = c * 16 + lrow;
            int am = min(m0 + r, M - 1);
            gll16(A + (size_t)am * K + k0 + lk, &As[buf][c * 512]);
        }
        {
            int c = wid;
            int r = c * 16 + lrow;
            int bn = min(n0 + r, Nout - 1);
            gll16(B1 + (size_t)bn * K + k0 + lk, &B1s[buf][c * 512]);
            gll16(B2 + (size_t)bn * K + k0 + lk, &B2s[buf][c * 512]);
        }
    };

    stage(0, 0);
    __syncthreads();
    for (int t = 0; t < nt; ++t) {
        const int cur = t & 1;
        if (t + 1 < nt) stage(t + 1, cur ^ 1);
        f16x8 af[4], bf1[4], bf2[4];
#pragma unroll
        for (int mi = 0; mi < 4; mi++)
            af[mi] = *(const f16x8*)(&As[cur][(wr * 64 + mi * 16 + (lane & 15)) * TBK + (lane >> 4) * 8]);
#pragma unroll
        for (int nj = 0; nj < 4; nj++) {
            int ro = (wc * 64 + nj * 16 + (lane & 15)) * TBK + (lane >> 4) * 8;
            bf1[nj] = *(const f16x8*)(&B1s[cur][ro]);
            bf2[nj] = *(const f16x8*)(&B2s[cur][ro]);
        }
#pragma unroll
        for (int mi = 0; mi < 4; mi++)
#pragma unroll
            for (int nj = 0; nj < 4; nj++) {
                acc1[mi][nj] = __builtin_amdgcn_mfma_f32_16x16x32_f16(af[mi], bf1[nj], acc1[mi][nj], 0, 0, 0);
                acc2[mi][nj] = __builtin_amdgcn_mfma_f32_16x16x32_f16(af[mi], bf2[nj], acc2[mi][nj], 0, 0, 0);
            }
        __syncthreads();
    }

    const int g = lane >> 4;
    float wsv[4];
#pragma unroll
    for (int nj = 0; nj < 4; nj++)
        wsv[nj] = Ws[n0 + wc * 64 + nj * 16 + (lane & 15)];
#pragma unroll
    for (int mi = 0; mi < 4; mi++) {
#pragma unroll
        for (int r = 0; r < 4; r++) {
            float p = 0.f;
#pragma unroll
            for (int nj = 0; nj < 4; nj++) {
                int col = n0 + wc * 64 + nj * 16 + (lane & 15);
                float t1 = ftanh(acc1[mi][nj][r] + c1[col]);
                float g1 = fsigmoid(acc2[mi][nj][r] + c2[col]);
                p += t1 * g1 * wsv[nj];
            }
#pragma unroll
            for (int o = 1; o < 16; o <<= 1) p += __shfl_xor(p, o);
            if ((lane & 15) == 0) {
                int m = m0 + wr * 64 + mi * 16 + g * 4 + r;
                if (m < M) scr4[(size_t)m * 4 + (n0 >> 7)] = p;
            }
        }
    }
}

// ---------------- fused sim GEMM + row softmax, Kin=128 ----------------
#define SBM 128
__global__ __launch_bounds__(256)
void simgemm(const _Float16* __restrict__ A, const _Float16* __restrict__ B,
             const float* __restrict__ Psq4, const float* __restrict__ Csq2,
             const float* __restrict__ sscale, _Float16* __restrict__ Ah,
             int M, int K)
{
    const int Kin = 128;
    __shared__ _Float16 As[2][SBM * TBK];
    __shared__ _Float16 Bs[2][SBM * TBK];
    __shared__ float redmx[2][SBM];
    __shared__ float redsm[2][SBM];
    const int tid = threadIdx.x;
    const int lane = tid & 63;
    const int wid = tid >> 6;
    const int wr = wid >> 1, wc = wid & 1;
    const int m0 = blockIdx.y * SBM;

    f32x4 acc[4][4] = {};
    const int nt = K / TBK;
    const int lrow = lane >> 2;
    const int lk = (lane & 3) * 8;

    auto stage = [&](int t, int buf) {
        const int k0 = t * TBK;
#pragma unroll
        for (int q = 0; q < 2; q++) {
            int c = wid * 2 + q;
            int r = c * 16 + lrow;
            gll16(A + (size_t)(m0 + r) * K + k0 + lk, &As[buf][c * 512]);
            gll16(B + (size_t)r * K + k0 + lk, &Bs[buf][c * 512]);
        }
    };

    stage(0, 0);
    __syncthreads();
    for (int t = 0; t < nt; ++t) {
        const int cur = t & 1;
        if (t + 1 < nt) stage(t + 1, cur ^ 1);
        f16x8 af[4], bf[4];
#pragma unroll
        for (int mi = 0; mi < 4; mi++)
            af[mi] = *(const f16x8*)(&As[cur][(wr * 64 + mi * 16 + (lane & 15)) * TBK + (lane >> 4) * 8]);
#pragma unroll
        for (int nj = 0; nj < 4; nj++)
            bf[nj] = *(const f16x8*)(&Bs[cur][(wc * 64 + nj * 16 + (lane & 15)) * TBK + (lane >> 4) * 8]);
#pragma unroll
        for (int mi = 0; mi < 4; mi++)
#pragma unroll
            for (int nj = 0; nj < 4; nj++)
                acc[mi][nj] = __builtin_amdgcn_mfma_f32_16x16x32_f16(af[mi], bf[nj], acc[mi][nj], 0, 0, 0);
        __syncthreads();
    }

    const float denom = fmaxf(1e-6f, sscale[0]);
    const int colbase = wc * 64 + (lane & 15);
    const int g = lane >> 4;
    float cc[4];
#pragma unroll
    for (int nj = 0; nj < 4; nj++) {
        int n = colbase + nj * 16;
        cc[nj] = Csq2[n * 2] + Csq2[n * 2 + 1];
    }

#pragma unroll
    for (int mi = 0; mi < 4; mi++) {
#pragma unroll
        for (int r = 0; r < 4; r++) {
            int row = wr * 64 + mi * 16 + g * 4 + r;
            float4 pq = *(const float4*)(Psq4 + (size_t)(m0 + row) * 4);
            float pp = (pq.x + pq.y) + (pq.z + pq.w);
            float mx = -INFINITY;
#pragma unroll
            for (int nj = 0; nj < 4; nj++) {
                float v = -sqrtf(fmaxf(pp + cc[nj] - 2.f * acc[mi][nj][r], 1e-12f)) / denom;
                acc[mi][nj][r] = v;
                mx = fmaxf(mx, v);
            }
#pragma unroll
            for (int o = 1; o < 16; o <<= 1) mx = fmaxf(mx, __shfl_xor(mx, o));
            if ((lane & 15) == 0) redmx[wc][row] = mx;
        }
    }
    __syncthreads();

#pragma unroll
    for (int mi = 0; mi < 4; mi++) {
#pragma unroll
        for (int r = 0; r < 4; r++) {
            int row = wr * 64 + mi * 16 + g * 4 + r;
            float mx = fmaxf(redmx[0][row], redmx[1][row]);
            float s = 0.f;
#pragma unroll
            for (int nj = 0; nj < 4; nj++) {
                float e = __expf(acc[mi][nj][r] - mx);
                acc[mi][nj][r] = e;
                s += e;
            }
#pragma unroll
            for (int o = 1; o < 16; o <<= 1) s += __shfl_xor(s, o);
            if ((lane & 15) == 0) redsm[wc][row] = s;
        }
    }
    __syncthreads();

#pragma unroll
    for (int mi = 0; mi < 4; mi++) {
#pragma unroll
        for (int r = 0; r < 4; r++) {
            int row = wr * 64 + mi * 16 + g * 4 + r;
            float inv = __builtin_amdgcn_rcpf(redsm[0][row] + redsm[1][row]);
            int m = m0 + row;
#pragma unroll
            for (int nj = 0; nj < 4; nj++)
                Ah[(size_t)m * Kin + colbase + nj * 16] = (_Float16)(acc[mi][nj][r] * inv);
        }
    }
}

// ---------------- fused sim GEMM + row softmax, KIN<=64 ----------------
template<int KIN>
__global__ __launch_bounds__(256)
void simgemm_s(const _Float16* __restrict__ A, const _Float16* __restrict__ B,
               const float* __restrict__ Psq4, const float* __restrict__ Csq2,
               const float* __restrict__ sscale, _Float16* __restrict__ Ah,
               int M, int K)
{
    constexpr int NB = KIN / 16;
    __shared__ _Float16 As[2][256 * TBK];
    __shared__ _Float16 Bs[2][KIN * TBK];
    const int tid = threadIdx.x;
    const int lane = tid & 63;
    const int wid = tid >> 6;
    const int m0 = blockIdx.y * 256;

    f32x4 acc[4][NB] = {};
    const int nt = K / TBK;
    const int lrow = lane >> 2;
    const int lk = (lane & 3) * 8;

    auto stage = [&](int t, int buf) {
        const int k0 = t * TBK;
#pragma unroll
        for (int q = 0; q < 4; q++) {
            int c = wid * 4 + q;
            int r = c * 16 + lrow;
            gll16(A + (size_t)(m0 + r) * K + k0 + lk, &As[buf][c * 512]);
        }
        if (wid < NB) {
            int r = wid * 16 + lrow;
            gll16(B + (size_t)r * K + k0 + lk, &Bs[buf][wid * 512]);
        }
    };

    stage(0, 0);
    __syncthreads();
    for (int t = 0; t < nt; ++t) {
        const int cur = t & 1;
        if (t + 1 < nt) stage(t + 1, cur ^ 1);
        f16x8 af[4], bf[NB];
#pragma unroll
        for (int mi = 0; mi < 4; mi++)
            af[mi] = *(const f16x8*)(&As[cur][(wid * 64 + mi * 16 + (lane & 15)) * TBK + (lane >> 4) * 8]);
#pragma unroll
        for (int nj = 0; nj < NB; nj++)
            bf[nj] = *(const f16x8*)(&Bs[cur][(nj * 16 + (lane & 15)) * TBK + (lane >> 4) * 8]);
#pragma unroll
        for (int mi = 0; mi < 4; mi++)
#pragma unroll
            for (int nj = 0; nj < NB; nj++)
                acc[mi][nj] = __builtin_amdgcn_mfma_f32_16x16x32_f16(af[mi], bf[nj], acc[mi][nj], 0, 0, 0);
        __syncthreads();
    }

    const float denom = fmaxf(1e-6f, sscale[0]);
    const int g = lane >> 4;
    float cc[NB];
#pragma unroll
    for (int nj = 0; nj < NB; nj++) {
        int n = nj * 16 + (lane & 15);
        cc[nj] = Csq2[n * 2] + Csq2[n * 2 + 1];
    }

#pragma unroll
    for (int mi = 0; mi < 4; mi++) {
#pragma unroll
        for (int r = 0; r < 4; r++) {
            int m = m0 + wid * 64 + mi * 16 + g * 4 + r;
            float4 pq = *(const float4*)(Psq4 + (size_t)m * 4);
            float pp = (pq.x + pq.y) + (pq.z + pq.w);
            float vv[NB];
            float mx = -INFINITY;
#pragma unroll
            for (int nj = 0; nj < NB; nj++) {
                float v = -sqrtf(fmaxf(pp + cc[nj] - 2.f * acc[mi][nj][r], 1e-12f)) / denom;
                vv[nj] = v;
                mx = fmaxf(mx, v);
            }
#pragma unroll
            for (int o = 1; o < 16; o <<= 1) mx = fmaxf(mx, __shfl_xor(mx, o));
            float s = 0.f;
#pragma unroll
            for (int nj = 0; nj < NB; nj++) { float e = __expf(vv[nj] - mx); vv[nj] = e; s += e; }
#pragma unroll
            for (int o = 1; o < 16; o <<= 1) s += __shfl_xor(s, o);
            float inv = __builtin_amdgcn_rcpf(s);
#pragma unroll
            for (int nj = 0; nj < NB; nj++)
                Ah[(size_t)m * KIN + nj * 16 + (lane & 15)] = (_Float16)(vv[nj] * inv);
        }
    }
}

// ---------------- small kernels ----------------
__global__ __launch_bounds__(256)
void ln_k(const _Float16* __restrict__ X, const _Float16* __restrict__ R,
          const float* __restrict__ g, const float* __restrict__ b,
          _Float16* __restrict__ Yh, int M)
{
    int wid = threadIdx.x >> 6, lane = threadIdx.x & 63;
    int row = blockIdx.x * 4 + wid;
    if (row >= M) return;
    f16x8 a = *(const f16x8*)(X + (size_t)row * 512 + lane * 8);
    float v[8];
#pragma unroll
    for (int q = 0; q < 8; q++) v[q] = (float)a[q];
    if (R) {
        f16x8 c = *(const f16x8*)(R + (size_t)row * 512 + lane * 8);
#pragma unroll
        for (int q = 0; q < 8; q++) v[q] += (float)c[q];
    }
    float s = 0.f, ss = 0.f;
#pragma unroll
    for (int q = 0; q < 8; q++) { s += v[q]; ss += v[q] * v[q]; }
#pragma unroll
    for (int o = 32; o; o >>= 1) { s += __shfl_xor(s, o); ss += __shfl_xor(ss, o); }
    float mean = s * (1.f / 512.f);
    float var = ss * (1.f / 512.f) - mean * mean;
    float inv = 1.f / sqrtf(var + 1e-5f);
    int d0 = lane * 8;
    f16x8 o8;
#pragma unroll
    for (int q = 0; q < 8; q++)
        o8[q] = (_Float16)((v[q] - mean) * inv * g[d0 + q] + b[d0 + q]);
    *(f16x8*)(Yh + (size_t)row * 512 + d0) = o8;
}

__global__ __launch_bounds__(256)
void red1_k(const float* __restrict__ C, const float* __restrict__ w1,
            const float* __restrict__ b1, float* __restrict__ H1, int Kin)
{
    int d = blockIdx.x * 256 + threadIdx.x;
    int j = blockIdx.y;
    float acc = b1[j];
    for (int k = 0; k < Kin; k++) acc = fmaf(C[(size_t)k * 512 + d], w1[(size_t)j * Kin + k], acc);
    H1[(size_t)j * 512 + d] = fmaxf(acc, 0.f);
}

__global__ __launch_bounds__(256)
void red2_k(const float* __restrict__ H1, const float* __restrict__ w2,
            const float* __restrict__ b2, float* __restrict__ Cn,
            _Float16* __restrict__ Chn, _Float16* __restrict__ CThn,
            float* __restrict__ Csq2, int Kin, int Kout)
{
    __shared__ float sm[4];
    int d = blockIdx.x * 256 + threadIdx.x;
    int j2 = blockIdx.y;
    float acc = b2[j2];
    for (int j = 0; j < Kin; j++) acc = fmaf(H1[(size_t)j * 512 + d], w2[(size_t)j2 * Kin + j], acc);
    Cn[(size_t)j2 * 512 + d] = acc;
    _Float16 h = (_Float16)acc;
    Chn[(size_t)j2 * 512 + d] = h;
    CThn[(size_t)d * Kout + j2] = h;
    float f = (float)h;
    float sq = f * f;
#pragma unroll
    for (int o = 32; o; o >>= 1) sq += __shfl_xor(sq, o);
    if ((threadIdx.x & 63) == 0) sm[threadIdx.x >> 6] = sq;
    __syncthreads();
    if (threadIdx.x == 0)
        Csq2[j2 * 2 + blockIdx.x] = (sm[0] + sm[1]) + (sm[2] + sm[3]);
}

__global__ __launch_bounds__(1024)
void pool_k(const float4* __restrict__ s4, float* __restrict__ s,
            float* __restrict__ scal, int M)
{
    __shared__ float sm[16];
    int tid = threadIdx.x, lane = tid & 63, wid = tid >> 6;
    float mx = -INFINITY;
    for (int i = tid; i < M; i += 1024) {
        float4 a = s4[i];
        float v = (a.x + a.y) + (a.z + a.w);
        s[i] = v;
        mx = fmaxf(mx, v);
    }
#pragma unroll
    for (int o = 32; o; o >>= 1) mx = fmaxf(mx, __shfl_xor(mx, o));
    if (lane == 0) sm[wid] = mx;
    __syncthreads();
    if (wid == 0) {
        float v = (lane < 16) ? sm[lane] : -INFINITY;
#pragma unroll
        for (int o = 8; o; o >>= 1) v = fmaxf(v, __shfl_xor(v, o));
        if (lane == 0) sm[0] = v;
    }
    __syncthreads();
    float gmax = sm[0];
    __syncthreads();
    float sum = 0.f;
    for (int i = tid; i < M; i += 1024) {
        float e = __expf(s[i] - gmax);
        s[i] = e;
        sum += e;
    }
#pragma unroll
    for (int o = 32; o; o >>= 1) sum += __shfl_xor(sum, o);
    if (lane == 0) sm[wid] = sum;
    __syncthreads();
    if (tid == 0) {
        float t = 0.f;
        for (int w = 0; w < 16; w++) t += sm[w];
        scal[0] = t;
    }
}

__global__ __launch_bounds__(256)
void bagp_k(const _Float16* __restrict__ Z, const float* __restrict__ w,
            float* __restrict__ PB, int M, int cs)
{
    int d = blockIdx.x * 256 + threadIdx.x;
    int chunk = blockIdx.y;
    int i0 = chunk * cs;
    int i1 = min(M, i0 + cs);
    float acc = 0.f;
    for (int i = i0; i < i1; i++) acc = fmaf(w[i], (float)Z[(size_t)i * 512 + d], acc);
    PB[(size_t)chunk * 512 + d] = acc;
}

__global__ __launch_bounds__(256)
void bagf_k(const float* __restrict__ PB, const float* __restrict__ scal,
            float* __restrict__ bag, int nchunk)
{
    int d = blockIdx.x * 256 + threadIdx.x;
    float acc = 0.f;
    for (int c = 0; c < nchunk; c++) acc += PB[(size_t)c * 512 + d];
    bag[d] = acc / scal[0];
}

__global__ __launch_bounds__(256)
void h_k(const float* __restrict__ bag, const float* __restrict__ Wh,
         const float* __restrict__ bh, float* __restrict__ h)
{
    int wid = threadIdx.x >> 6, lane = threadIdx.x & 63;
    int j = blockIdx.x * 4 + wid;
    const float* wr = Wh + (size_t)j * 512;
    float d = 0.f;
#pragma unroll
    for (int t = 0; t < 2; t++) {
        float4 a = *(const float4*)(wr + t * 256 + lane * 4);
        float4 bv = *(const float4*)(bag + t * 256 + lane * 4);
        d += a.x * bv.x + a.y * bv.y + a.z * bv.z + a.w * bv.w;
    }
#pragma unroll
    for (int o = 32; o; o >>= 1) d += __shfl_xor(d, o);
    if (lane == 0) h[j] = fmaxf(d + bh[j], 0.f);
}

__global__ __launch_bounds__(128)
void logit_k(const float* __restrict__ h, const float* __restrict__ Wc,
             const float* __restrict__ bc, float* __restrict__ out)
{
    int wid = threadIdx.x >> 6, lane = threadIdx.x & 63;
    const float* wr = Wc + (size_t)wid * 512;
    float d = 0.f;
#pragma unroll
    for (int t = 0; t < 2; t++) {
        float4 a = *(const float4*)(wr + t * 256 + lane * 4);
        float4 hv = *(const float4*)(h + t * 256 + lane * 4);
        d += a.x * hv.x + a.y * hv.y + a.z * hv.z + a.w * hv.w;
    }
#pragma unroll
    for (int o = 32; o; o >>= 1) d += __shfl_xor(d, o);
    if (lane == 0) out[wid] = d + bc[wid];
}

extern "C" void kernel_launch(void* const* d_in, const int* in_sizes, int n_in,
                              void* d_out, int out_size, void* d_ws, size_t ws_size,
                              hipStream_t stream)
{
    const float* data    = (const float*)d_in[0];
    const float* protos  = (const float*)d_in[1];
    const float* W_pp    = (const float*)d_in[2];
    const float* b_pp    = (const float*)d_in[3];
    const float* W_cp    = (const float*)d_in[4];
    const float* b_cp    = (const float*)d_in[5];
    const float* sscale  = (const float*)d_in[6];
    const float* enh_w1  = (const float*)d_in[7];
    const float* enh_b1  = (const float*)d_in[8];
    const float* enh_w2  = (const float*)d_in[9];
    const float* enh_b2  = (const float*)d_in[10];
    const float* ln_g    = (const float*)d_in[11];
    const float* ln_b    = (const float*)d_in[12];
    const float* red_w1[3] = {(const float*)d_in[13], (const float*)d_in[17], (const float*)d_in[21]};
    const float* red_b1[3] = {(const float*)d_in[14], (const float*)d_in[18], (const float*)d_in[22]};
    const float* red_w2[3] = {(const float*)d_in[15], (const float*)d_in[19], (const float*)d_in[23]};
    const float* red_b2[3] = {(const float*)d_in[16], (const float*)d_in[20], (const float*)d_in[24]};
    const float* W_proc  = (const float*)d_in[25];
    const float* b_proc  = (const float*)d_in[26];
    const float* g_an    = (const float*)d_in[27];
    const float* b_an    = (const float*)d_in[28];
    const float* W_t     = (const float*)d_in[29];
    const float* b_t     = (const float*)d_in[30];
    const float* W_g     = (const float*)d_in[31];
    const float* b_g     = (const float*)d_in[32];
    const float* W_s     = (const float*)d_in[33];
    const float* b_s     = (const float*)d_in[34];  // unused: softmax shift-invariant
    const float* W_h     = (const float*)d_in[35];
    const float* b_h     = (const float*)d_in[36];
    const float* W_c     = (const float*)d_in[37];
    const float* b_c     = (const float*)d_in[38];
    float* out = (float*)d_out;
    (void)b_s;

    constexpr int N = 32768, DIN = 768, D = 512;
    constexpr int NCHUNK = 256;
    char* w = (char*)d_ws;
    auto alloc = [&](size_t bytes) -> char* {
        char* p = w; w += (bytes + 255) & ~(size_t)255; return p;
    };
    _Float16* Ph     = (_Float16*)alloc((size_t)N * D * 2);
    _Float16* TMPh   = (_Float16*)alloc((size_t)N * D * 2);
    _Float16* Zh     = (_Float16*)alloc((size_t)(N + 16) * D * 2);
    _Float16* Ztail  = (_Float16*)alloc((size_t)16 * D * 2);
    _Float16* Ah     = (_Float16*)alloc((size_t)N * 128 * 2);
    _Float16* Ch     = (_Float16*)alloc(128 * D * 2);
    _Float16* CTh    = (_Float16*)alloc(128 * D * 2);
    _Float16* Wpph   = (_Float16*)alloc((size_t)D * DIN * 2);
    _Float16* w1h    = (_Float16*)alloc((size_t)3 * D * D * 2);
    _Float16* w2h    = (_Float16*)alloc((size_t)3 * D * D * 2);
    _Float16* Wproch = (_Float16*)alloc((size_t)D * D * 2);
    _Float16* Wth    = (_Float16*)alloc((size_t)D * D * 2);
    _Float16* Wgh    = (_Float16*)alloc((size_t)D * D * 2);
    float*    Psq4   = (float*)alloc((size_t)N * 4 * 4);
    float*    Csq2   = (float*)alloc(128 * 2 * 4);
    float*    Ca     = (float*)alloc(128 * D * 4);
    float*    Cb     = (float*)alloc(128 * D * 4);
    float*    H1     = (float*)alloc(128 * D * 4);
    float*    scr4   = (float*)alloc((size_t)(N + 16) * 4 * 4);
    float*    scr    = (float*)alloc((size_t)(N + 16) * 4);
    float*    PB     = (float*)alloc((size_t)NCHUNK * D * 4);
    float*    bag    = (float*)alloc(D * 4);
    float*    hb     = (float*)alloc(D * 4);
    float*    scal   = (float*)alloc(8 * 4);

    dim3 blk(256);
    dim3 blk512(512);
    auto mgrid = [](int M_, int Nout_) { return dim3((Nout_ + TBN - 1) / TBN, (M_ + TBM - 1) / TBM); };

    // --- merged fp32->f16 conversion: weights only ---
    {
        CvtSegs cs;
        const float* srcs[6] = { W_pp, enh_w1, enh_w2, W_proc, W_t, W_g };
        _Float16* dsts[6]    = { Wpph, w1h, w2h, Wproch, Wth, Wgh };
        int sizes[6] = { D * DIN, 3 * D * D, 3 * D * D, D * D, D * D, D * D };
        int c = 0;
        cs.cum4[0] = 0;
        for (int s = 0; s < 6; s++) {
            cs.src[s] = srcs[s]; cs.dst[s] = dsts[s];
            c += sizes[s] / 4;
            cs.cum4[s + 1] = c;
        }
        cvtall_k<<<dim3(2048), blk, 0, stream>>>(cs);
    }

    // P = leaky(data @ W_pp^T + b_pp) -> f16 (fp32 A read direct), Psq4 partials
    pgemm32<<<mgrid(N, D), blk512, 0, stream>>>(data, Wpph, b_pp, Ph, Psq4, N, DIN, D);
    // C0 = leaky(protos @ W_cp^T + b_cp) -> fp32, then f16 set via cvtC2
    dot_k<1, false><<<dim3(128 * 512 / 4), blk, 0, stream>>>(protos, W_cp, b_cp, Ca, 128, DIN);
    cvtC2_k<<<dim3(32), blk, 0, stream>>>(Ca, Ch, CTh, Csq2, 128);

    float* C = Ca;
    float* Cn = Cb;
    int Kin = 128;
    for (int i = 0; i < 3; i++) {
        int Kout = Kin >> 1;
        // A = softmax(-dist/denom) fused with S = P@C^T
        if (i == 0)
            simgemm<<<dim3(1, N / SBM), blk, 0, stream>>>(Ph, Ch, Psq4, Csq2, sscale, Ah, N, D);
        else if (i == 1)
            simgemm_s<64><<<dim3(1, N / 256), blk, 0, stream>>>(Ph, Ch, Psq4, Csq2, sscale, Ah, N, D);
        else
            simgemm_s<32><<<dim3(1, N / 256), blk, 0, stream>>>(Ph, Ch, Psq4, Csq2, sscale, Ah, N, D);
        // P = LN(P + A@C) fused
        ctxln_k<<<dim3(1, N / 128), blk512, 0, stream>>>(Ah, CTh, ln_g + (size_t)i * D, ln_b + (size_t)i * D, Ph, N, Kin);
        // enhancer MLP (128x512 tiles): TMPh = relu(P@w1^T+b1); P += TMPh@w2^T+b2
        enh1_k<<<dim3(1, N / 128), blk512, 0, stream>>>(Ph, w1h + (size_t)i * D * D, enh_b1 + (size_t)i * D, TMPh, N);
        if (i < 2)
            enh2_k<true><<<dim3(1, N / 128), blk512, 0, stream>>>(TMPh, w2h + (size_t)i * D * D, enh_b2 + (size_t)i * D, Ph, Psq4, N);
        else
            enh2_k<false><<<dim3(1, N / 128), blk512, 0, stream>>>(TMPh, w2h + (size_t)i * D * D, enh_b2 + (size_t)i * D, Ph, nullptr, N);
        // ProtoReducer; red2 emits next iteration's f16 C set + Csq2
        red1_k<<<dim3(2, Kin), blk, 0, stream>>>(C, red_w1[i], red_b1[i], H1, Kin);
        red2_k<<<dim3(2, Kout), blk, 0, stream>>>(H1, red_w2[i], red_b2[i], Cn, Ch, CTh, Csq2, Kin, Kout);
        float* t = C; C = Cn; Cn = t;
        Kin = Kout;
    }

    // Z(main) = LN(relu(P @ W_proc^T + b_proc)) fused
    procln_k<<<dim3(1, N / 128), blk512, 0, stream>>>(Ph, Wproch, b_proc, g_an, b_an, Zh, N);
    // Z(tail, 16 C rows)
    dot_k<2, true><<<dim3(16 * 512 / 4), blk, 0, stream>>>(C, W_proc, b_proc, Ztail, 16, D);
    ln_k<<<dim3(4), blk, 0, stream>>>(Ztail, nullptr, g_an, b_an, Zh + (size_t)N * D, 16);

    // scores: per-col-block partials into scr4
    gatgemm<<<mgrid(N + 16, D), blk512, 0, stream>>>(Zh, Wth, Wgh, b_t, b_g, W_s, scr4, N + 16, D, D);

    // attention pooling
    pool_k<<<dim3(1), dim3(1024), 0, stream>>>((const float4*)scr4, scr, scal, N + 16);
    int cs2 = (N + 16 + NCHUNK - 1) / NCHUNK;
    bagp_k<<<dim3(2, NCHUNK), blk, 0, stream>>>(Zh, scr, PB, N + 16, cs2);
    bagf_k<<<dim3(2), blk, 0, stream>>>(PB, scal, bag, NCHUNK);

    // classifier head
    h_k<<<dim3(128), blk, 0, stream>>>(bag, W_h, b_h, hb);
    logit_k<<<dim3(1), dim3(128), 0, stream>>>(hb, W_c, b_c, out);
}